// Round 3
// baseline (8853.168 us; speedup 1.0000x reference)
//
#include <hip/hip_runtime.h>
#include <cstdint>
#include <cstddef>

namespace {

constexpr int kNB   = 8;
constexpr int kN    = 4096;
constexpr int kS    = 1024;   // NPOINT
constexpr int kK    = 32;     // NSAMPLE
constexpr int kInCh = 64;
constexpr int kC0   = 67;     // 3 + 64
constexpr int kC0P  = 68;     // padded (zero col at c'=3)
constexpr int kC1   = 64;
constexpr int kC3   = 128;
constexpr int kRows = kNB * kS * kK;  // 262144
constexpr int kTileR = 128;
constexpr int kGemmBlocks = kRows / kTileR;  // 2048

// ---------------- Farthest point sampling -----------------------------------
// ONE WAVE per batch; 64 points per lane in registers; zero barriers in the
// 1023-step serial loop. Bit-exact vs numpy: d = ((dx*dx+dy*dy)+dz*dz) with
// RN ops (no FMA), argmax = first occurrence of max (adjacent-pairing tree
// keeps index ranges ordered so strict '>' is exact; butterfly ties broken by
// explicit min-index compare).
__global__ __launch_bounds__(64) void fps_kernel(const float* __restrict__ xyz,
                                                 float* __restrict__ newxyz) {
  __shared__ float sx[kN], sy[kN], sz[kN];
  const int lane = threadIdx.x;   // 0..63
  const int b = blockIdx.x;
  const float* xb = xyz + (size_t)b * kN * 3;
  float px[64], py[64], pz[64], dist[64];
#pragma unroll
  for (int t = 0; t < 64; ++t) {
    const int i = t * 64 + lane;
    const float x = xb[i * 3 + 0];
    const float y = xb[i * 3 + 1];
    const float z = xb[i * 3 + 2];
    px[t] = x; py[t] = y; pz[t] = z; dist[t] = 1e10f;
    sx[i] = x; sy[i] = y; sz[i] = z;
  }
  float cx = __shfl(px[0], 0, 64);
  float cy = __shfl(py[0], 0, 64);
  float cz = __shfl(pz[0], 0, 64);
  float* ob = newxyz + (size_t)b * kS * 3;
  if (lane == 0) { ob[0] = cx; ob[1] = cy; ob[2] = cz; }
  for (int j = 1; j < kS; ++j) {
    // Update all 64 distances (register-resident, independent -> full ILP).
#pragma unroll
    for (int t = 0; t < 64; ++t) {
      const float dx = __fsub_rn(px[t], cx);
      const float dy = __fsub_rn(py[t], cy);
      const float dz = __fsub_rn(pz[t], cz);
      const float d0 = __fadd_rn(__fadd_rn(__fmul_rn(dx, dx), __fmul_rn(dy, dy)),
                                 __fmul_rn(dz, dz));
      dist[t] = fminf(dist[t], d0);
    }
    // Per-lane leftmost-max tree with ADJACENT pairing: at every level the
    // left node's index range lies entirely below the right node's, so
    // "replace only if strictly greater" yields the first max exactly.
    float tv[32]; int tt[32];
#pragma unroll
    for (int k = 0; k < 32; ++k) {
      const bool g = dist[2 * k + 1] > dist[2 * k];
      tv[k] = g ? dist[2 * k + 1] : dist[2 * k];
      tt[k] = g ? (2 * k + 1) : (2 * k);
    }
#pragma unroll
    for (int s = 16; s >= 1; s >>= 1) {
#pragma unroll
      for (int k = 0; k < s; ++k) {
        const bool g = tv[2 * k + 1] > tv[2 * k];
        tv[k] = g ? tv[2 * k + 1] : tv[2 * k];
        tt[k] = g ? tt[2 * k + 1] : tt[2 * k];
      }
    }
    float bv = tv[0];
    int   bi = tt[0] * 64 + lane;   // global index; per-lane set ascending in t
    // Cross-lane butterfly with exact min-index tie-break.
#pragma unroll
    for (int off = 1; off < 64; off <<= 1) {
      const float ov = __shfl_xor(bv, off, 64);
      const int   oi = __shfl_xor(bi, off, 64);
      if (ov > bv || (ov == bv && oi < bi)) { bv = ov; bi = oi; }
    }
    cx = sx[bi]; cy = sy[bi]; cz = sz[bi];
    if (lane == 0) { ob[j * 3 + 0] = cx; ob[j * 3 + 1] = cy; ob[j * 3 + 2] = cz; }
  }
}

// ---------------- Ball query -------------------------------------------------
// One wave per query point; first-32 in-radius indices in ascending order,
// padded with the first index. Distance uses the reference's expanded form and
// the compare is done in double (python float radius*radius).
__global__ __launch_bounds__(256) void ballq_kernel(const float* __restrict__ xyz,
                                                    const float* __restrict__ newxyz,
                                                    int* __restrict__ gidx) {
  const int tid  = threadIdx.x;
  const int lane = tid & 63;
  const int gq   = blockIdx.x * 4 + (tid >> 6);
  const int b    = gq >> 10;
  const float* xb = xyz + (size_t)b * kN * 3;
  const float qx = newxyz[gq * 3 + 0];
  const float qy = newxyz[gq * 3 + 1];
  const float qz = newxyz[gq * 3 + 2];
  const float s2 = __fadd_rn(__fadd_rn(__fmul_rn(qx, qx), __fmul_rn(qy, qy)),
                             __fmul_rn(qz, qz));
  const double r2 = 0.2 * 0.2;
  int taken = 0;
  int first = 0;
  bool hasfirst = false;
  int* g = gidx + (size_t)gq * kK;
  for (int base = 0; base < kN; base += 64) {
    const int n = base + lane;
    const float fx = xb[n * 3 + 0], fy = xb[n * 3 + 1], fz = xb[n * 3 + 2];
    const float p2 = __fadd_rn(__fadd_rn(__fmul_rn(fx, fx), __fmul_rn(fy, fy)),
                               __fmul_rn(fz, fz));
    const float dt = __fadd_rn(__fadd_rn(__fmul_rn(qx, fx), __fmul_rn(qy, fy)),
                               __fmul_rn(qz, fz));
    const float d = __fadd_rn(__fadd_rn(__fmul_rn(-2.0f, dt), s2), p2);
    const bool in = !((double)d > r2);
    const unsigned long long m = __ballot(in);
    if (!hasfirst && m != 0ull) { first = base + __builtin_ctzll(m); hasfirst = true; }
    if (in) {
      const int pos = taken + (int)__popcll(m & ((1ull << lane) - 1ull));
      if (pos < kK) g[pos] = n;
    }
    taken += (int)__popcll(m);
    if (taken >= kK) break;
  }
  for (int p = taken + lane; p < kK; p += 64) g[p] = first;
}

// ---------------- GEMM core (shared pattern) ---------------------------------
// Block: 256 threads, tile 128 rows x 64 cols. Thread (tr = tid&15, tc = tid>>4)
// computes rows {tr+16i} x cols {tc*4+j}, acc[8][4].

template <int KDIM>
__device__ __forceinline__ void gemm_compute(const float xs[kTileR][kC0P],
                                             const float wl[kC1][kC0P],
                                             int tr, int tc, float acc[8][4]) {
#pragma unroll
  for (int i = 0; i < 8; ++i)
#pragma unroll
    for (int j = 0; j < 4; ++j) acc[i][j] = 0.0f;
#pragma unroll 4
  for (int c = 0; c < KDIM; c += 4) {
    const float4 wv0 = *(const float4*)&wl[tc * 4 + 0][c];
    const float4 wv1 = *(const float4*)&wl[tc * 4 + 1][c];
    const float4 wv2 = *(const float4*)&wl[tc * 4 + 2][c];
    const float4 wv3 = *(const float4*)&wl[tc * 4 + 3][c];
#pragma unroll
    for (int i = 0; i < 8; ++i) {
      const float4 xv = *(const float4*)&xs[tr + 16 * i][c];
      acc[i][0] = fmaf(xv.x, wv0.x, acc[i][0]);
      acc[i][0] = fmaf(xv.y, wv0.y, acc[i][0]);
      acc[i][0] = fmaf(xv.z, wv0.z, acc[i][0]);
      acc[i][0] = fmaf(xv.w, wv0.w, acc[i][0]);
      acc[i][1] = fmaf(xv.x, wv1.x, acc[i][1]);
      acc[i][1] = fmaf(xv.y, wv1.y, acc[i][1]);
      acc[i][1] = fmaf(xv.z, wv1.z, acc[i][1]);
      acc[i][1] = fmaf(xv.w, wv1.w, acc[i][1]);
      acc[i][2] = fmaf(xv.x, wv2.x, acc[i][2]);
      acc[i][2] = fmaf(xv.y, wv2.y, acc[i][2]);
      acc[i][2] = fmaf(xv.z, wv2.z, acc[i][2]);
      acc[i][2] = fmaf(xv.w, wv2.w, acc[i][2]);
      acc[i][3] = fmaf(xv.x, wv3.x, acc[i][3]);
      acc[i][3] = fmaf(xv.y, wv3.y, acc[i][3]);
      acc[i][3] = fmaf(xv.z, wv3.z, acc[i][3]);
      acc[i][3] = fmaf(xv.w, wv3.w, acc[i][3]);
    }
  }
}

// Epilogue: add bias, write y, and per-channel {sum, sumsq} partials.
__device__ __forceinline__ void gemm_store_stats(float acc[8][4], const float* __restrict__ bias,
                                                 float* __restrict__ y,
                                                 float* __restrict__ psum, float* __restrict__ psq,
                                                 int R0, int tr, int tc, int bid) {
  float bb[4];
#pragma unroll
  for (int j = 0; j < 4; ++j) bb[j] = bias[tc * 4 + j];
  float sum[4] = {0, 0, 0, 0}, sq[4] = {0, 0, 0, 0};
#pragma unroll
  for (int i = 0; i < 8; ++i) {
    float v[4];
#pragma unroll
    for (int j = 0; j < 4; ++j) {
      const float t = acc[i][j] + bb[j];
      v[j] = t;
      sum[j] += t;
      sq[j] = fmaf(t, t, sq[j]);
    }
    *(float4*)&y[((size_t)(R0 + tr + 16 * i)) * kC1 + tc * 4] =
        make_float4(v[0], v[1], v[2], v[3]);
  }
#pragma unroll
  for (int off = 1; off < 16; off <<= 1) {
#pragma unroll
    for (int j = 0; j < 4; ++j) {
      sum[j] += __shfl_xor(sum[j], off, 64);
      sq[j]  += __shfl_xor(sq[j], off, 64);
    }
  }
  if (tr == 0) {
    *(float4*)&psum[(size_t)bid * kC1 + tc * 4] = make_float4(sum[0], sum[1], sum[2], sum[3]);
    *(float4*)&psq[(size_t)bid * kC1 + tc * 4]  = make_float4(sq[0], sq[1], sq[2], sq[3]);
  }
}

// ---------------- Layer 1: fused gather + GEMM(K=67->68, N=64) ---------------
__global__ __launch_bounds__(256) void gemm1_kernel(
    const float* __restrict__ xyz, const float* __restrict__ points,
    const float* __restrict__ newxyz, const int* __restrict__ gidx,
    const float* __restrict__ W, const float* __restrict__ bias,
    float* __restrict__ y, float* __restrict__ psum, float* __restrict__ psq) {
  __shared__ float xs[kTileR][kC0P];
  __shared__ float wl[kC1][kC0P];
  __shared__ int   gl[kTileR];
  __shared__ float nx[4][3];
  const int tid = threadIdx.x;
  const int R0  = blockIdx.x * kTileR;
  const int b   = R0 >> 15;          // 32768 rows per batch
  const int G0  = R0 >> 5;           // global group id base (4 groups per tile)
  if (tid < kTileR) gl[tid] = gidx[R0 + tid];
  if (tid >= 128 && tid < 140) {
    const int q = (tid - 128) / 3, c = (tid - 128) % 3;
    nx[q][c] = newxyz[(size_t)(G0 + q) * 3 + c];
  }
  // Stage W reordered: c'=0..2 -> W[:,0..2], c'=3 -> 0, c'>=4 -> W[:,c'-1]
  for (int i = tid; i < kC1 * kC0P; i += 256) {
    const int o = i / kC0P, c = i % kC0P;
    float v;
    if (c < 3)       v = W[o * kC0 + c];
    else if (c == 3) v = 0.0f;
    else             v = W[o * kC0 + (c - 1)];
    wl[o][c] = v;
  }
  __syncthreads();
  // Gather-stage xs: [dx,dy,dz,0, p0..p63]
  for (int i = tid; i < kTileR * 17; i += 256) {
    const int r = i / 17, q = i % 17;
    const int n = gl[r];
    if (q == 0) {
      const float* xp = xyz + ((size_t)(b * kN + n)) * 3;
      const int sq4 = r >> 5;
      xs[r][0] = __fsub_rn(xp[0], nx[sq4][0]);
      xs[r][1] = __fsub_rn(xp[1], nx[sq4][1]);
      xs[r][2] = __fsub_rn(xp[2], nx[sq4][2]);
      xs[r][3] = 0.0f;
    } else {
      const float4 p = *(const float4*)(points + ((size_t)(b * kN + n)) * kInCh + (q - 1) * 4);
      *(float4*)&xs[r][q * 4] = p;
    }
  }
  __syncthreads();
  const int tr = tid & 15, tc = tid >> 4;
  float acc[8][4];
  gemm_compute<kC0P>(xs, wl, tr, tc, acc);
  gemm_store_stats(acc, bias, y, psum, psq, R0, tr, tc, blockIdx.x);
}

// ---------------- Layer 2: GEMM(K=64, N=64), BN1+ReLU fused on input --------
__global__ __launch_bounds__(256) void gemm2_kernel(
    const float* __restrict__ x, const float* __restrict__ W, const float* __restrict__ bias,
    const float* __restrict__ a, const float* __restrict__ sft,
    float* __restrict__ y, float* __restrict__ psum, float* __restrict__ psq) {
  __shared__ float xs[kTileR][kC0P];
  __shared__ float wl[kC1][kC0P];
  const int tid = threadIdx.x;
  const int R0  = blockIdx.x * kTileR;
  for (int i = tid; i < kTileR * 16; i += 256) {
    const int r = i >> 4, cq = i & 15;
    float4 v = *(const float4*)&x[((size_t)(R0 + r)) * kC1 + cq * 4];
    const float4 av = *(const float4*)&a[cq * 4];
    const float4 sv = *(const float4*)&sft[cq * 4];
    v.x = fmaxf(fmaf(av.x, v.x, sv.x), 0.0f);
    v.y = fmaxf(fmaf(av.y, v.y, sv.y), 0.0f);
    v.z = fmaxf(fmaf(av.z, v.z, sv.z), 0.0f);
    v.w = fmaxf(fmaf(av.w, v.w, sv.w), 0.0f);
    *(float4*)&xs[r][cq * 4] = v;
  }
  for (int i = tid; i < kC1 * 16; i += 256) {
    const int o = i >> 4, cq = i & 15;
    *(float4*)&wl[o][cq * 4] = *(const float4*)&W[(size_t)o * kC1 + cq * 4];
  }
  __syncthreads();
  const int tr = tid & 15, tc = tid >> 4;
  float acc[8][4];
  gemm_compute<kC1>(xs, wl, tr, tc, acc);
  gemm_store_stats(acc, bias, y, psum, psq, R0, tr, tc, blockIdx.x);
}

// ---------------- Layer 3 pass A: stats only (no y3 store) -------------------
__global__ __launch_bounds__(256) void gemm3a_kernel(
    const float* __restrict__ x, const float* __restrict__ W, const float* __restrict__ bias,
    const float* __restrict__ a, const float* __restrict__ sft,
    float* __restrict__ psum, float* __restrict__ psq) {
  __shared__ float xs[kTileR][kC0P];
  __shared__ float wl[kC1][kC0P];
  const int tid = threadIdx.x;
  const int R0  = blockIdx.x * kTileR;
  for (int i = tid; i < kTileR * 16; i += 256) {
    const int r = i >> 4, cq = i & 15;
    float4 v = *(const float4*)&x[((size_t)(R0 + r)) * kC1 + cq * 4];
    const float4 av = *(const float4*)&a[cq * 4];
    const float4 sv = *(const float4*)&sft[cq * 4];
    v.x = fmaxf(fmaf(av.x, v.x, sv.x), 0.0f);
    v.y = fmaxf(fmaf(av.y, v.y, sv.y), 0.0f);
    v.z = fmaxf(fmaf(av.z, v.z, sv.z), 0.0f);
    v.w = fmaxf(fmaf(av.w, v.w, sv.w), 0.0f);
    *(float4*)&xs[r][cq * 4] = v;
  }
  const int tr = tid & 15, tc = tid >> 4;
  for (int cp = 0; cp < 2; ++cp) {
    __syncthreads();
    for (int i = tid; i < kC1 * 16; i += 256) {
      const int o = i >> 4, cq = i & 15;
      *(float4*)&wl[o][cq * 4] = *(const float4*)&W[((size_t)(cp * 64 + o)) * kC1 + cq * 4];
    }
    __syncthreads();
    float acc[8][4];
    gemm_compute<kC1>(xs, wl, tr, tc, acc);
    float bb[4];
#pragma unroll
    for (int j = 0; j < 4; ++j) bb[j] = bias[cp * 64 + tc * 4 + j];
    float sum[4] = {0, 0, 0, 0}, sq[4] = {0, 0, 0, 0};
#pragma unroll
    for (int i = 0; i < 8; ++i)
#pragma unroll
      for (int j = 0; j < 4; ++j) {
        const float t = acc[i][j] + bb[j];
        sum[j] += t;
        sq[j] = fmaf(t, t, sq[j]);
      }
#pragma unroll
    for (int off = 1; off < 16; off <<= 1) {
#pragma unroll
      for (int j = 0; j < 4; ++j) {
        sum[j] += __shfl_xor(sum[j], off, 64);
        sq[j]  += __shfl_xor(sq[j], off, 64);
      }
    }
    if (tr == 0) {
      *(float4*)&psum[(size_t)blockIdx.x * kC3 + cp * 64 + tc * 4] =
          make_float4(sum[0], sum[1], sum[2], sum[3]);
      *(float4*)&psq[(size_t)blockIdx.x * kC3 + cp * 64 + tc * 4] =
          make_float4(sq[0], sq[1], sq[2], sq[3]);
    }
  }
}

// ---------------- Layer 3 pass B: recompute + BN3 + ReLU + max over k -------
__global__ __launch_bounds__(256) void gemm3b_kernel(
    const float* __restrict__ x, const float* __restrict__ W, const float* __restrict__ bias,
    const float* __restrict__ a2, const float* __restrict__ s2,
    const float* __restrict__ a3, const float* __restrict__ s3,
    float* __restrict__ outp) {
  __shared__ float xs[kTileR][kC0P];
  __shared__ float wl[kC1][kC0P];
  const int tid = threadIdx.x;
  const int R0  = blockIdx.x * kTileR;
  const int G0  = R0 >> 5;
  for (int i = tid; i < kTileR * 16; i += 256) {
    const int r = i >> 4, cq = i & 15;
    float4 v = *(const float4*)&x[((size_t)(R0 + r)) * kC1 + cq * 4];
    const float4 av = *(const float4*)&a2[cq * 4];
    const float4 sv = *(const float4*)&s2[cq * 4];
    v.x = fmaxf(fmaf(av.x, v.x, sv.x), 0.0f);
    v.y = fmaxf(fmaf(av.y, v.y, sv.y), 0.0f);
    v.z = fmaxf(fmaf(av.z, v.z, sv.z), 0.0f);
    v.w = fmaxf(fmaf(av.w, v.w, sv.w), 0.0f);
    *(float4*)&xs[r][cq * 4] = v;
  }
  const int tr = tid & 15, tc = tid >> 4;
  for (int cp = 0; cp < 2; ++cp) {
    __syncthreads();
    for (int i = tid; i < kC1 * 16; i += 256) {
      const int o = i >> 4, cq = i & 15;
      *(float4*)&wl[o][cq * 4] = *(const float4*)&W[((size_t)(cp * 64 + o)) * kC1 + cq * 4];
    }
    __syncthreads();
    float acc[8][4];
    gemm_compute<kC1>(xs, wl, tr, tc, acc);
    float bb[4], av3[4], sv3[4];
#pragma unroll
    for (int j = 0; j < 4; ++j) {
      const int col = cp * 64 + tc * 4 + j;
      bb[j]  = bias[col];
      av3[j] = a3[col];
      sv3[j] = s3[col];
    }
    float mm[4][4];
#pragma unroll
    for (int i = 0; i < 8; ++i) {
      const int s4 = i >> 1;
#pragma unroll
      for (int j = 0; j < 4; ++j) {
        const float t = acc[i][j] + bb[j];
        const float v = fmaxf(fmaf(av3[j], t, sv3[j]), 0.0f);
        mm[s4][j] = (i & 1) ? fmaxf(mm[s4][j], v) : v;
      }
    }
#pragma unroll
    for (int off = 1; off < 16; off <<= 1)
#pragma unroll
      for (int s4 = 0; s4 < 4; ++s4)
#pragma unroll
        for (int j = 0; j < 4; ++j)
          mm[s4][j] = fmaxf(mm[s4][j], __shfl_xor(mm[s4][j], off, 64));
    if (tr == 0) {
#pragma unroll
      for (int s4 = 0; s4 < 4; ++s4) {
        *(float4*)&outp[(size_t)(G0 + s4) * kC3 + cp * 64 + tc * 4] =
            make_float4(mm[s4][0], mm[s4][1], mm[s4][2], mm[s4][3]);
      }
    }
  }
}

// ---------------- BN stats finalize ------------------------------------------
__global__ void finalize_kernel(const float* __restrict__ psum, const float* __restrict__ psq,
                                const float* __restrict__ g, const float* __restrict__ be,
                                float* __restrict__ a, float* __restrict__ s,
                                int nch, int nblocks) {
  const int c = threadIdx.x;
  if (c >= nch) return;
  float sum = 0.f, sq = 0.f;
  for (int i = 0; i < nblocks; ++i) {
    sum += psum[(size_t)i * nch + c];
    sq  += psq[(size_t)i * nch + c];
  }
  const float inv = 1.0f / (float)kRows;
  const float mu  = sum * inv;
  const float var = sq * inv - mu * mu;
  const float rs  = 1.0f / sqrtf(var + 1e-5f);
  const float av  = g[c] * rs;
  a[c] = av;
  s[c] = be[c] - av * mu;
}

}  // namespace

extern "C" void kernel_launch(void* const* d_in, const int* in_sizes, int n_in,
                              void* d_out, int out_size, void* d_ws, size_t ws_size,
                              hipStream_t stream) {
  const float* xyz    = (const float*)d_in[0];
  const float* points = (const float*)d_in[1];
  const float* W0  = (const float*)d_in[2];
  const float* b0  = (const float*)d_in[3];
  const float* g0  = (const float*)d_in[4];
  const float* be0 = (const float*)d_in[5];
  const float* W1  = (const float*)d_in[6];
  const float* b1  = (const float*)d_in[7];
  const float* g1  = (const float*)d_in[8];
  const float* be1 = (const float*)d_in[9];
  const float* W2  = (const float*)d_in[10];
  const float* b2  = (const float*)d_in[11];
  const float* g2  = (const float*)d_in[12];
  const float* be2 = (const float*)d_in[13];

  float* out      = (float*)d_out;
  float* newxyz   = out;            // 8*1024*3 = 24576 floats
  float* newpts   = out + 24576;    // 8*1024*128

  char* wsb = (char*)d_ws;
  int*   gidx = (int*)wsb;                              // 1 MiB
  float* a1 = (float*)(wsb + (1u << 20));
  float* s1 = a1 + 128;
  float* a2 = s1 + 128;
  float* s2 = a2 + 128;
  float* a3 = s2 + 128;
  float* s3 = a3 + 128;
  float* psum = (float*)(wsb + 2u * (1u << 20));        // 1 MiB
  float* psq  = (float*)(wsb + 3u * (1u << 20));        // 1 MiB
  float* y1 = (float*)(wsb + 4u * (1u << 20));          // 64 MiB
  float* y2 = (float*)(wsb + 68u * (1u << 20));         // 64 MiB

  fps_kernel<<<kNB, 64, 0, stream>>>(xyz, newxyz);
  ballq_kernel<<<(kNB * kS) / 4, 256, 0, stream>>>(xyz, newxyz, gidx);
  gemm1_kernel<<<kGemmBlocks, 256, 0, stream>>>(xyz, points, newxyz, gidx, W0, b0, y1, psum, psq);
  finalize_kernel<<<1, 64, 0, stream>>>(psum, psq, g0, be0, a1, s1, 64, kGemmBlocks);
  gemm2_kernel<<<kGemmBlocks, 256, 0, stream>>>(y1, W1, b1, a1, s1, y2, psum, psq);
  finalize_kernel<<<1, 64, 0, stream>>>(psum, psq, g1, be1, a2, s2, 64, kGemmBlocks);
  gemm3a_kernel<<<kGemmBlocks, 256, 0, stream>>>(y2, W2, b2, a2, s2, psum, psq);
  finalize_kernel<<<1, 128, 0, stream>>>(psum, psq, g2, be2, a3, s3, 128, kGemmBlocks);
  gemm3b_kernel<<<kGemmBlocks, 256, 0, stream>>>(y2, W2, b2, a2, s2, a3, s3, newpts);
}

// Round 4
// 7377.927 us; speedup vs baseline: 1.2000x; 1.2000x over previous
//
#include <hip/hip_runtime.h>
#include <cstdint>
#include <cstddef>

namespace {

constexpr int kNB   = 8;
constexpr int kN    = 4096;
constexpr int kS    = 1024;   // NPOINT
constexpr int kK    = 32;     // NSAMPLE
constexpr int kInCh = 64;
constexpr int kC0   = 67;     // 3 + 64
constexpr int kC0P  = 68;     // padded (zero col at c'=3)
constexpr int kC1   = 64;
constexpr int kC3   = 128;
constexpr int kRows = kNB * kS * kK;  // 262144
constexpr int kTileR = 128;
constexpr int kGemmBlocks = kRows / kTileR;  // 2048

// ---------------- Farthest point sampling -----------------------------------
// ONE WAVE per batch; 64 points per lane in registers; zero barriers in the
// 1023-step serial loop. __launch_bounds__(64, 1) is ESSENTIAL: it lets the
// allocator use up to 512 VGPRs/lane so px/py/pz/dist[64] (+ tree temps) stay
// in registers. (Round-2 lesson: without it the compiler capped at 168 VGPRs
// and spilled the arrays to scratch -> 7 us/step.)
// Bit-exact vs numpy: d = ((dx*dx+dy*dy)+dz*dz) with RN ops (no FMA), argmax =
// first occurrence of max (adjacent-pairing tree keeps index ranges ordered so
// strict '>' is exact; butterfly ties broken by explicit min-index compare).
__global__ __launch_bounds__(64, 1) void fps_kernel(const float* __restrict__ xyz,
                                                    float* __restrict__ newxyz) {
  __shared__ float sx[kN], sy[kN], sz[kN];
  const int lane = threadIdx.x;   // 0..63
  const int b = blockIdx.x;
  const float* xb = xyz + (size_t)b * kN * 3;
  float px[64], py[64], pz[64], dist[64];
#pragma unroll
  for (int t = 0; t < 64; ++t) {
    const int i = t * 64 + lane;
    const float x = xb[i * 3 + 0];
    const float y = xb[i * 3 + 1];
    const float z = xb[i * 3 + 2];
    px[t] = x; py[t] = y; pz[t] = z; dist[t] = 1e10f;
    sx[i] = x; sy[i] = y; sz[i] = z;
  }
  float cx = __shfl(px[0], 0, 64);
  float cy = __shfl(py[0], 0, 64);
  float cz = __shfl(pz[0], 0, 64);
  float* ob = newxyz + (size_t)b * kS * 3;
  if (lane == 0) { ob[0] = cx; ob[1] = cy; ob[2] = cz; }
  for (int j = 1; j < kS; ++j) {
    // Update all 64 distances (register-resident, independent -> full ILP).
#pragma unroll
    for (int t = 0; t < 64; ++t) {
      const float dx = __fsub_rn(px[t], cx);
      const float dy = __fsub_rn(py[t], cy);
      const float dz = __fsub_rn(pz[t], cz);
      const float d0 = __fadd_rn(__fadd_rn(__fmul_rn(dx, dx), __fmul_rn(dy, dy)),
                                 __fmul_rn(dz, dz));
      dist[t] = fminf(dist[t], d0);
    }
    // Per-lane leftmost-max tree with ADJACENT pairing: at every level the
    // left node's index range lies entirely below the right node's, so
    // "replace only if strictly greater" yields the first max exactly.
    float tv[32]; int tt[32];
#pragma unroll
    for (int k = 0; k < 32; ++k) {
      const bool g = dist[2 * k + 1] > dist[2 * k];
      tv[k] = g ? dist[2 * k + 1] : dist[2 * k];
      tt[k] = g ? (2 * k + 1) : (2 * k);
    }
#pragma unroll
    for (int s = 16; s >= 1; s >>= 1) {
#pragma unroll
      for (int k = 0; k < s; ++k) {
        const bool g = tv[2 * k + 1] > tv[2 * k];
        tv[k] = g ? tv[2 * k + 1] : tv[2 * k];
        tt[k] = g ? tt[2 * k + 1] : tt[2 * k];
      }
    }
    float bv = tv[0];
    int   bi = tt[0] * 64 + lane;   // global index; per-lane set ascending in t
    // Cross-lane butterfly with exact min-index tie-break.
#pragma unroll
    for (int off = 1; off < 64; off <<= 1) {
      const float ov = __shfl_xor(bv, off, 64);
      const int   oi = __shfl_xor(bi, off, 64);
      if (ov > bv || (ov == bv && oi < bi)) { bv = ov; bi = oi; }
    }
    cx = sx[bi]; cy = sy[bi]; cz = sz[bi];
    if (lane == 0) { ob[j * 3 + 0] = cx; ob[j * 3 + 1] = cy; ob[j * 3 + 2] = cz; }
  }
}

// ---------------- Ball query -------------------------------------------------
// One wave per query point; first-32 in-radius indices in ascending order,
// padded with the first index. Distance uses the reference's expanded form and
// the compare is done in double (python float radius*radius).
__global__ __launch_bounds__(256) void ballq_kernel(const float* __restrict__ xyz,
                                                    const float* __restrict__ newxyz,
                                                    int* __restrict__ gidx) {
  const int tid  = threadIdx.x;
  const int lane = tid & 63;
  const int gq   = blockIdx.x * 4 + (tid >> 6);
  const int b    = gq >> 10;
  const float* xb = xyz + (size_t)b * kN * 3;
  const float qx = newxyz[gq * 3 + 0];
  const float qy = newxyz[gq * 3 + 1];
  const float qz = newxyz[gq * 3 + 2];
  const float s2 = __fadd_rn(__fadd_rn(__fmul_rn(qx, qx), __fmul_rn(qy, qy)),
                             __fmul_rn(qz, qz));
  const double r2 = 0.2 * 0.2;
  int taken = 0;
  int first = 0;
  bool hasfirst = false;
  int* g = gidx + (size_t)gq * kK;
  for (int base = 0; base < kN; base += 64) {
    const int n = base + lane;
    const float fx = xb[n * 3 + 0], fy = xb[n * 3 + 1], fz = xb[n * 3 + 2];
    const float p2 = __fadd_rn(__fadd_rn(__fmul_rn(fx, fx), __fmul_rn(fy, fy)),
                               __fmul_rn(fz, fz));
    const float dt = __fadd_rn(__fadd_rn(__fmul_rn(qx, fx), __fmul_rn(qy, fy)),
                               __fmul_rn(qz, fz));
    const float d = __fadd_rn(__fadd_rn(__fmul_rn(-2.0f, dt), s2), p2);
    const bool in = !((double)d > r2);
    const unsigned long long m = __ballot(in);
    if (!hasfirst && m != 0ull) { first = base + __builtin_ctzll(m); hasfirst = true; }
    if (in) {
      const int pos = taken + (int)__popcll(m & ((1ull << lane) - 1ull));
      if (pos < kK) g[pos] = n;
    }
    taken += (int)__popcll(m);
    if (taken >= kK) break;
  }
  for (int p = taken + lane; p < kK; p += 64) g[p] = first;
}

// ---------------- GEMM core (shared pattern) ---------------------------------
// Block: 256 threads, tile 128 rows x 64 cols. Thread (tr = tid&15, tc = tid>>4)
// computes rows {tr+16i} x cols {tc*4+j}, acc[8][4].

template <int KDIM>
__device__ __forceinline__ void gemm_compute(const float xs[kTileR][kC0P],
                                             const float wl[kC1][kC0P],
                                             int tr, int tc, float acc[8][4]) {
#pragma unroll
  for (int i = 0; i < 8; ++i)
#pragma unroll
    for (int j = 0; j < 4; ++j) acc[i][j] = 0.0f;
#pragma unroll 4
  for (int c = 0; c < KDIM; c += 4) {
    const float4 wv0 = *(const float4*)&wl[tc * 4 + 0][c];
    const float4 wv1 = *(const float4*)&wl[tc * 4 + 1][c];
    const float4 wv2 = *(const float4*)&wl[tc * 4 + 2][c];
    const float4 wv3 = *(const float4*)&wl[tc * 4 + 3][c];
#pragma unroll
    for (int i = 0; i < 8; ++i) {
      const float4 xv = *(const float4*)&xs[tr + 16 * i][c];
      acc[i][0] = fmaf(xv.x, wv0.x, acc[i][0]);
      acc[i][0] = fmaf(xv.y, wv0.y, acc[i][0]);
      acc[i][0] = fmaf(xv.z, wv0.z, acc[i][0]);
      acc[i][0] = fmaf(xv.w, wv0.w, acc[i][0]);
      acc[i][1] = fmaf(xv.x, wv1.x, acc[i][1]);
      acc[i][1] = fmaf(xv.y, wv1.y, acc[i][1]);
      acc[i][1] = fmaf(xv.z, wv1.z, acc[i][1]);
      acc[i][1] = fmaf(xv.w, wv1.w, acc[i][1]);
      acc[i][2] = fmaf(xv.x, wv2.x, acc[i][2]);
      acc[i][2] = fmaf(xv.y, wv2.y, acc[i][2]);
      acc[i][2] = fmaf(xv.z, wv2.z, acc[i][2]);
      acc[i][2] = fmaf(xv.w, wv2.w, acc[i][2]);
      acc[i][3] = fmaf(xv.x, wv3.x, acc[i][3]);
      acc[i][3] = fmaf(xv.y, wv3.y, acc[i][3]);
      acc[i][3] = fmaf(xv.z, wv3.z, acc[i][3]);
      acc[i][3] = fmaf(xv.w, wv3.w, acc[i][3]);
    }
  }
}

// Epilogue: add bias, write y, and per-channel {sum, sumsq} partials.
__device__ __forceinline__ void gemm_store_stats(float acc[8][4], const float* __restrict__ bias,
                                                 float* __restrict__ y,
                                                 float* __restrict__ psum, float* __restrict__ psq,
                                                 int R0, int tr, int tc, int bid) {
  float bb[4];
#pragma unroll
  for (int j = 0; j < 4; ++j) bb[j] = bias[tc * 4 + j];
  float sum[4] = {0, 0, 0, 0}, sq[4] = {0, 0, 0, 0};
#pragma unroll
  for (int i = 0; i < 8; ++i) {
    float v[4];
#pragma unroll
    for (int j = 0; j < 4; ++j) {
      const float t = acc[i][j] + bb[j];
      v[j] = t;
      sum[j] += t;
      sq[j] = fmaf(t, t, sq[j]);
    }
    *(float4*)&y[((size_t)(R0 + tr + 16 * i)) * kC1 + tc * 4] =
        make_float4(v[0], v[1], v[2], v[3]);
  }
#pragma unroll
  for (int off = 1; off < 16; off <<= 1) {
#pragma unroll
    for (int j = 0; j < 4; ++j) {
      sum[j] += __shfl_xor(sum[j], off, 64);
      sq[j]  += __shfl_xor(sq[j], off, 64);
    }
  }
  if (tr == 0) {
    *(float4*)&psum[(size_t)bid * kC1 + tc * 4] = make_float4(sum[0], sum[1], sum[2], sum[3]);
    *(float4*)&psq[(size_t)bid * kC1 + tc * 4]  = make_float4(sq[0], sq[1], sq[2], sq[3]);
  }
}

// ---------------- Layer 1: fused gather + GEMM(K=67->68, N=64) ---------------
__global__ __launch_bounds__(256) void gemm1_kernel(
    const float* __restrict__ xyz, const float* __restrict__ points,
    const float* __restrict__ newxyz, const int* __restrict__ gidx,
    const float* __restrict__ W, const float* __restrict__ bias,
    float* __restrict__ y, float* __restrict__ psum, float* __restrict__ psq) {
  __shared__ float xs[kTileR][kC0P];
  __shared__ float wl[kC1][kC0P];
  __shared__ int   gl[kTileR];
  __shared__ float nx[4][3];
  const int tid = threadIdx.x;
  const int R0  = blockIdx.x * kTileR;
  const int b   = R0 >> 15;          // 32768 rows per batch
  const int G0  = R0 >> 5;           // global group id base (4 groups per tile)
  if (tid < kTileR) gl[tid] = gidx[R0 + tid];
  if (tid >= 128 && tid < 140) {
    const int q = (tid - 128) / 3, c = (tid - 128) % 3;
    nx[q][c] = newxyz[(size_t)(G0 + q) * 3 + c];
  }
  // Stage W reordered: c'=0..2 -> W[:,0..2], c'=3 -> 0, c'>=4 -> W[:,c'-1]
  for (int i = tid; i < kC1 * kC0P; i += 256) {
    const int o = i / kC0P, c = i % kC0P;
    float v;
    if (c < 3)       v = W[o * kC0 + c];
    else if (c == 3) v = 0.0f;
    else             v = W[o * kC0 + (c - 1)];
    wl[o][c] = v;
  }
  __syncthreads();
  // Gather-stage xs: [dx,dy,dz,0, p0..p63]
  for (int i = tid; i < kTileR * 17; i += 256) {
    const int r = i / 17, q = i % 17;
    const int n = gl[r];
    if (q == 0) {
      const float* xp = xyz + ((size_t)(b * kN + n)) * 3;
      const int sq4 = r >> 5;
      xs[r][0] = __fsub_rn(xp[0], nx[sq4][0]);
      xs[r][1] = __fsub_rn(xp[1], nx[sq4][1]);
      xs[r][2] = __fsub_rn(xp[2], nx[sq4][2]);
      xs[r][3] = 0.0f;
    } else {
      const float4 p = *(const float4*)(points + ((size_t)(b * kN + n)) * kInCh + (q - 1) * 4);
      *(float4*)&xs[r][q * 4] = p;
    }
  }
  __syncthreads();
  const int tr = tid & 15, tc = tid >> 4;
  float acc[8][4];
  gemm_compute<kC0P>(xs, wl, tr, tc, acc);
  gemm_store_stats(acc, bias, y, psum, psq, R0, tr, tc, blockIdx.x);
}

// ---------------- Layer 2: GEMM(K=64, N=64), BN1+ReLU fused on input --------
__global__ __launch_bounds__(256) void gemm2_kernel(
    const float* __restrict__ x, const float* __restrict__ W, const float* __restrict__ bias,
    const float* __restrict__ a, const float* __restrict__ sft,
    float* __restrict__ y, float* __restrict__ psum, float* __restrict__ psq) {
  __shared__ float xs[kTileR][kC0P];
  __shared__ float wl[kC1][kC0P];
  const int tid = threadIdx.x;
  const int R0  = blockIdx.x * kTileR;
  for (int i = tid; i < kTileR * 16; i += 256) {
    const int r = i >> 4, cq = i & 15;
    float4 v = *(const float4*)&x[((size_t)(R0 + r)) * kC1 + cq * 4];
    const float4 av = *(const float4*)&a[cq * 4];
    const float4 sv = *(const float4*)&sft[cq * 4];
    v.x = fmaxf(fmaf(av.x, v.x, sv.x), 0.0f);
    v.y = fmaxf(fmaf(av.y, v.y, sv.y), 0.0f);
    v.z = fmaxf(fmaf(av.z, v.z, sv.z), 0.0f);
    v.w = fmaxf(fmaf(av.w, v.w, sv.w), 0.0f);
    *(float4*)&xs[r][cq * 4] = v;
  }
  for (int i = tid; i < kC1 * 16; i += 256) {
    const int o = i >> 4, cq = i & 15;
    *(float4*)&wl[o][cq * 4] = *(const float4*)&W[(size_t)o * kC1 + cq * 4];
  }
  __syncthreads();
  const int tr = tid & 15, tc = tid >> 4;
  float acc[8][4];
  gemm_compute<kC1>(xs, wl, tr, tc, acc);
  gemm_store_stats(acc, bias, y, psum, psq, R0, tr, tc, blockIdx.x);
}

// ---------------- Layer 3 pass A: stats only (no y3 store) -------------------
__global__ __launch_bounds__(256) void gemm3a_kernel(
    const float* __restrict__ x, const float* __restrict__ W, const float* __restrict__ bias,
    const float* __restrict__ a, const float* __restrict__ sft,
    float* __restrict__ psum, float* __restrict__ psq) {
  __shared__ float xs[kTileR][kC0P];
  __shared__ float wl[kC1][kC0P];
  const int tid = threadIdx.x;
  const int R0  = blockIdx.x * kTileR;
  for (int i = tid; i < kTileR * 16; i += 256) {
    const int r = i >> 4, cq = i & 15;
    float4 v = *(const float4*)&x[((size_t)(R0 + r)) * kC1 + cq * 4];
    const float4 av = *(const float4*)&a[cq * 4];
    const float4 sv = *(const float4*)&sft[cq * 4];
    v.x = fmaxf(fmaf(av.x, v.x, sv.x), 0.0f);
    v.y = fmaxf(fmaf(av.y, v.y, sv.y), 0.0f);
    v.z = fmaxf(fmaf(av.z, v.z, sv.z), 0.0f);
    v.w = fmaxf(fmaf(av.w, v.w, sv.w), 0.0f);
    *(float4*)&xs[r][cq * 4] = v;
  }
  const int tr = tid & 15, tc = tid >> 4;
  for (int cp = 0; cp < 2; ++cp) {
    __syncthreads();
    for (int i = tid; i < kC1 * 16; i += 256) {
      const int o = i >> 4, cq = i & 15;
      *(float4*)&wl[o][cq * 4] = *(const float4*)&W[((size_t)(cp * 64 + o)) * kC1 + cq * 4];
    }
    __syncthreads();
    float acc[8][4];
    gemm_compute<kC1>(xs, wl, tr, tc, acc);
    float bb[4];
#pragma unroll
    for (int j = 0; j < 4; ++j) bb[j] = bias[cp * 64 + tc * 4 + j];
    float sum[4] = {0, 0, 0, 0}, sq[4] = {0, 0, 0, 0};
#pragma unroll
    for (int i = 0; i < 8; ++i)
#pragma unroll
      for (int j = 0; j < 4; ++j) {
        const float t = acc[i][j] + bb[j];
        sum[j] += t;
        sq[j] = fmaf(t, t, sq[j]);
      }
#pragma unroll
    for (int off = 1; off < 16; off <<= 1) {
#pragma unroll
      for (int j = 0; j < 4; ++j) {
        sum[j] += __shfl_xor(sum[j], off, 64);
        sq[j]  += __shfl_xor(sq[j], off, 64);
      }
    }
    if (tr == 0) {
      *(float4*)&psum[(size_t)blockIdx.x * kC3 + cp * 64 + tc * 4] =
          make_float4(sum[0], sum[1], sum[2], sum[3]);
      *(float4*)&psq[(size_t)blockIdx.x * kC3 + cp * 64 + tc * 4] =
          make_float4(sq[0], sq[1], sq[2], sq[3]);
    }
  }
}

// ---------------- Layer 3 pass B: recompute + BN3 + ReLU + max over k -------
__global__ __launch_bounds__(256) void gemm3b_kernel(
    const float* __restrict__ x, const float* __restrict__ W, const float* __restrict__ bias,
    const float* __restrict__ a2, const float* __restrict__ s2,
    const float* __restrict__ a3, const float* __restrict__ s3,
    float* __restrict__ outp) {
  __shared__ float xs[kTileR][kC0P];
  __shared__ float wl[kC1][kC0P];
  const int tid = threadIdx.x;
  const int R0  = blockIdx.x * kTileR;
  const int G0  = R0 >> 5;
  for (int i = tid; i < kTileR * 16; i += 256) {
    const int r = i >> 4, cq = i & 15;
    float4 v = *(const float4*)&x[((size_t)(R0 + r)) * kC1 + cq * 4];
    const float4 av = *(const float4*)&a2[cq * 4];
    const float4 sv = *(const float4*)&s2[cq * 4];
    v.x = fmaxf(fmaf(av.x, v.x, sv.x), 0.0f);
    v.y = fmaxf(fmaf(av.y, v.y, sv.y), 0.0f);
    v.z = fmaxf(fmaf(av.z, v.z, sv.z), 0.0f);
    v.w = fmaxf(fmaf(av.w, v.w, sv.w), 0.0f);
    *(float4*)&xs[r][cq * 4] = v;
  }
  const int tr = tid & 15, tc = tid >> 4;
  for (int cp = 0; cp < 2; ++cp) {
    __syncthreads();
    for (int i = tid; i < kC1 * 16; i += 256) {
      const int o = i >> 4, cq = i & 15;
      *(float4*)&wl[o][cq * 4] = *(const float4*)&W[((size_t)(cp * 64 + o)) * kC1 + cq * 4];
    }
    __syncthreads();
    float acc[8][4];
    gemm_compute<kC1>(xs, wl, tr, tc, acc);
    float bb[4], av3[4], sv3[4];
#pragma unroll
    for (int j = 0; j < 4; ++j) {
      const int col = cp * 64 + tc * 4 + j;
      bb[j]  = bias[col];
      av3[j] = a3[col];
      sv3[j] = s3[col];
    }
    float mm[4][4];
#pragma unroll
    for (int i = 0; i < 8; ++i) {
      const int s4 = i >> 1;
#pragma unroll
      for (int j = 0; j < 4; ++j) {
        const float t = acc[i][j] + bb[j];
        const float v = fmaxf(fmaf(av3[j], t, sv3[j]), 0.0f);
        mm[s4][j] = (i & 1) ? fmaxf(mm[s4][j], v) : v;
      }
    }
#pragma unroll
    for (int off = 1; off < 16; off <<= 1)
#pragma unroll
      for (int s4 = 0; s4 < 4; ++s4)
#pragma unroll
        for (int j = 0; j < 4; ++j)
          mm[s4][j] = fmaxf(mm[s4][j], __shfl_xor(mm[s4][j], off, 64));
    if (tr == 0) {
#pragma unroll
      for (int s4 = 0; s4 < 4; ++s4) {
        *(float4*)&outp[(size_t)(G0 + s4) * kC3 + cp * 64 + tc * 4] =
            make_float4(mm[s4][0], mm[s4][1], mm[s4][2], mm[s4][3]);
      }
    }
  }
}

// ---------------- BN stats finalize (parallel) -------------------------------
// One block per channel; 256 threads reduce the 2048 per-block partials.
__global__ __launch_bounds__(256) void finalize_kernel(
    const float* __restrict__ psum, const float* __restrict__ psq,
    const float* __restrict__ g, const float* __restrict__ be,
    float* __restrict__ a, float* __restrict__ s, int nch) {
  __shared__ float red[2][4];
  const int c   = blockIdx.x;
  const int tid = threadIdx.x;
  const int lane = tid & 63, wid = tid >> 6;
  float sum = 0.f, sq = 0.f;
  for (int i = tid; i < kGemmBlocks; i += 256) {
    sum += psum[(size_t)i * nch + c];
    sq  += psq[(size_t)i * nch + c];
  }
#pragma unroll
  for (int off = 1; off < 64; off <<= 1) {
    sum += __shfl_xor(sum, off, 64);
    sq  += __shfl_xor(sq, off, 64);
  }
  if (lane == 0) { red[0][wid] = sum; red[1][wid] = sq; }
  __syncthreads();
  if (tid == 0) {
    const float tsum = red[0][0] + red[0][1] + red[0][2] + red[0][3];
    const float tsq  = red[1][0] + red[1][1] + red[1][2] + red[1][3];
    const float inv = 1.0f / (float)kRows;
    const float mu  = tsum * inv;
    const float var = tsq * inv - mu * mu;
    const float rs  = 1.0f / sqrtf(var + 1e-5f);
    const float av  = g[c] * rs;
    a[c] = av;
    s[c] = be[c] - av * mu;
  }
}

}  // namespace

extern "C" void kernel_launch(void* const* d_in, const int* in_sizes, int n_in,
                              void* d_out, int out_size, void* d_ws, size_t ws_size,
                              hipStream_t stream) {
  const float* xyz    = (const float*)d_in[0];
  const float* points = (const float*)d_in[1];
  const float* W0  = (const float*)d_in[2];
  const float* b0  = (const float*)d_in[3];
  const float* g0  = (const float*)d_in[4];
  const float* be0 = (const float*)d_in[5];
  const float* W1  = (const float*)d_in[6];
  const float* b1  = (const float*)d_in[7];
  const float* g1  = (const float*)d_in[8];
  const float* be1 = (const float*)d_in[9];
  const float* W2  = (const float*)d_in[10];
  const float* b2  = (const float*)d_in[11];
  const float* g2  = (const float*)d_in[12];
  const float* be2 = (const float*)d_in[13];

  float* out      = (float*)d_out;
  float* newxyz   = out;            // 8*1024*3 = 24576 floats
  float* newpts   = out + 24576;    // 8*1024*128

  char* wsb = (char*)d_ws;
  int*   gidx = (int*)wsb;                              // 1 MiB
  float* a1 = (float*)(wsb + (1u << 20));
  float* s1 = a1 + 128;
  float* a2 = s1 + 128;
  float* s2 = a2 + 128;
  float* a3 = s2 + 128;
  float* s3 = a3 + 128;
  float* psum = (float*)(wsb + 2u * (1u << 20));        // 1 MiB
  float* psq  = (float*)(wsb + 3u * (1u << 20));        // 1 MiB
  float* y1 = (float*)(wsb + 4u * (1u << 20));          // 64 MiB
  float* y2 = (float*)(wsb + 68u * (1u << 20));         // 64 MiB

  fps_kernel<<<kNB, 64, 0, stream>>>(xyz, newxyz);
  ballq_kernel<<<(kNB * kS) / 4, 256, 0, stream>>>(xyz, newxyz, gidx);
  gemm1_kernel<<<kGemmBlocks, 256, 0, stream>>>(xyz, points, newxyz, gidx, W0, b0, y1, psum, psq);
  finalize_kernel<<<64, 256, 0, stream>>>(psum, psq, g0, be0, a1, s1, 64);
  gemm2_kernel<<<kGemmBlocks, 256, 0, stream>>>(y1, W1, b1, a1, s1, y2, psum, psq);
  finalize_kernel<<<64, 256, 0, stream>>>(psum, psq, g1, be1, a2, s2, 64);
  gemm3a_kernel<<<kGemmBlocks, 256, 0, stream>>>(y2, W2, b2, a2, s2, psum, psq);
  finalize_kernel<<<128, 256, 0, stream>>>(psum, psq, g2, be2, a3, s3, 128);
  gemm3b_kernel<<<kGemmBlocks, 256, 0, stream>>>(y2, W2, b2, a2, s2, a3, s3, newpts);
}

// Round 5
// 7371.633 us; speedup vs baseline: 1.2010x; 1.0009x over previous
//
#include <hip/hip_runtime.h>
#include <cstdint>
#include <cstddef>

namespace {

constexpr int kNB   = 8;
constexpr int kN    = 4096;
constexpr int kS    = 1024;   // NPOINT
constexpr int kK    = 32;     // NSAMPLE
constexpr int kInCh = 64;
constexpr int kC0   = 67;     // 3 + 64
constexpr int kC0P  = 68;     // padded (zero col at c'=3)
constexpr int kC1   = 64;
constexpr int kC3   = 128;
constexpr int kRows = kNB * kS * kK;  // 262144
constexpr int kTileR = 128;
constexpr int kGemmBlocks = kRows / kTileR;  // 2048

// ---------------- Farthest point sampling -----------------------------------
// ONE WAVE per batch; zero barriers in the 1023-step loop.
// Register budget lesson (rounds 2-3): px/py/pz/dist[64] = 256 floats/lane ==
// the ENTIRE addressable VGPR file -> unavoidable spill (VGPR_Count 168,
// scratch traffic, 7 us/step). Fix: only dist[64] in registers; coords live in
// LDS as float4[4096] (64 KiB) and are re-read each step via ds_read_b128
// (~12 cyc throughput, overlapped with the VALU update).
// Bit-exact vs numpy: d = ((dx*dx+dy*dy)+dz*dz) with RN ops, no FMA
// (fp contract(off)); argmax = first occurrence (adjacent-pairing tree keeps
// index ranges ordered so strict '>' is exact; butterfly ties broken by
// min-index compare).
__global__ __launch_bounds__(64, 1) void fps_kernel(const float* __restrict__ xyz,
                                                    float* __restrict__ newxyz) {
  __shared__ float4 sp[kN];   // 64 KiB
  const int lane = threadIdx.x;   // 0..63
  const int b = blockIdx.x;
  const float* xb = xyz + (size_t)b * kN * 3;
  float dist[64];
#pragma unroll
  for (int t = 0; t < 64; ++t) {
    const int i = t * 64 + lane;
    sp[i] = make_float4(xb[i * 3 + 0], xb[i * 3 + 1], xb[i * 3 + 2], 0.0f);
    dist[t] = 1e10f;
  }
  __syncthreads();   // once; single wave
  float4 c4 = sp[0];   // broadcast
  float cx = c4.x, cy = c4.y, cz = c4.z;
  float* ob = newxyz + (size_t)b * kS * 3;
  if (lane == 0) { ob[0] = cx; ob[1] = cy; ob[2] = cz; }
  for (int j = 1; j < kS; ++j) {
    // Fused update + tree level 0 (adjacent pairing).
    float tv[32]; int tt[32];
#pragma unroll
    for (int k = 0; k < 32; ++k) {
      const float4 p0 = sp[(2 * k) * 64 + lane];
      const float4 p1 = sp[(2 * k + 1) * 64 + lane];
      float nd0, nd1;
      {
#pragma clang fp contract(off)
        const float dx0 = p0.x - cx, dy0 = p0.y - cy, dz0 = p0.z - cz;
        const float d0 = ((dx0 * dx0 + dy0 * dy0) + dz0 * dz0);
        const float dx1 = p1.x - cx, dy1 = p1.y - cy, dz1 = p1.z - cz;
        const float d1 = ((dx1 * dx1 + dy1 * dy1) + dz1 * dz1);
        nd0 = fminf(dist[2 * k], d0);
        nd1 = fminf(dist[2 * k + 1], d1);
      }
      dist[2 * k] = nd0;
      dist[2 * k + 1] = nd1;
      const bool g = nd1 > nd0;
      tv[k] = g ? nd1 : nd0;
      tt[k] = g ? (2 * k + 1) : (2 * k);
    }
    // Tree levels 16..1 (register-only; leftmost-max preserved by strict '>').
#pragma unroll
    for (int s = 16; s >= 1; s >>= 1) {
#pragma unroll
      for (int k = 0; k < s; ++k) {
        const bool g = tv[2 * k + 1] > tv[2 * k];
        tv[k] = g ? tv[2 * k + 1] : tv[2 * k];
        tt[k] = g ? tt[2 * k + 1] : tt[2 * k];
      }
    }
    float bv = tv[0];
    int   bi = tt[0] * 64 + lane;   // global index; per-lane set ascending in t
    // Cross-lane butterfly with exact min-index tie-break.
#pragma unroll
    for (int off = 1; off < 64; off <<= 1) {
      const float ov = __shfl_xor(bv, off, 64);
      const int   oi = __shfl_xor(bi, off, 64);
      if (ov > bv || (ov == bv && oi < bi)) { bv = ov; bi = oi; }
    }
    c4 = sp[bi];   // broadcast b128 read
    cx = c4.x; cy = c4.y; cz = c4.z;
    if (lane == 0) { ob[j * 3 + 0] = cx; ob[j * 3 + 1] = cy; ob[j * 3 + 2] = cz; }
  }
}

// ---------------- Ball query -------------------------------------------------
// One wave per query point; first-32 in-radius indices in ascending order,
// padded with the first index. Distance uses the reference's expanded form and
// the compare is done in double (python float radius*radius).
__global__ __launch_bounds__(256) void ballq_kernel(const float* __restrict__ xyz,
                                                    const float* __restrict__ newxyz,
                                                    int* __restrict__ gidx) {
  const int tid  = threadIdx.x;
  const int lane = tid & 63;
  const int gq   = blockIdx.x * 4 + (tid >> 6);
  const int b    = gq >> 10;
  const float* xb = xyz + (size_t)b * kN * 3;
  const float qx = newxyz[gq * 3 + 0];
  const float qy = newxyz[gq * 3 + 1];
  const float qz = newxyz[gq * 3 + 2];
  const float s2 = __fadd_rn(__fadd_rn(__fmul_rn(qx, qx), __fmul_rn(qy, qy)),
                             __fmul_rn(qz, qz));
  const double r2 = 0.2 * 0.2;
  int taken = 0;
  int first = 0;
  bool hasfirst = false;
  int* g = gidx + (size_t)gq * kK;
  for (int base = 0; base < kN; base += 64) {
    const int n = base + lane;
    const float fx = xb[n * 3 + 0], fy = xb[n * 3 + 1], fz = xb[n * 3 + 2];
    const float p2 = __fadd_rn(__fadd_rn(__fmul_rn(fx, fx), __fmul_rn(fy, fy)),
                               __fmul_rn(fz, fz));
    const float dt = __fadd_rn(__fadd_rn(__fmul_rn(qx, fx), __fmul_rn(qy, fy)),
                               __fmul_rn(qz, fz));
    const float d = __fadd_rn(__fadd_rn(__fmul_rn(-2.0f, dt), s2), p2);
    const bool in = !((double)d > r2);
    const unsigned long long m = __ballot(in);
    if (!hasfirst && m != 0ull) { first = base + __builtin_ctzll(m); hasfirst = true; }
    if (in) {
      const int pos = taken + (int)__popcll(m & ((1ull << lane) - 1ull));
      if (pos < kK) g[pos] = n;
    }
    taken += (int)__popcll(m);
    if (taken >= kK) break;
  }
  for (int p = taken + lane; p < kK; p += 64) g[p] = first;
}

// ---------------- GEMM core (shared pattern) ---------------------------------
// Block: 256 threads, tile 128 rows x 64 cols. Thread (tr = tid&15, tc = tid>>4)
// computes rows {tr+16i} x cols {tc*4+j}, acc[8][4].

template <int KDIM>
__device__ __forceinline__ void gemm_compute(const float xs[kTileR][kC0P],
                                             const float wl[kC1][kC0P],
                                             int tr, int tc, float acc[8][4]) {
#pragma unroll
  for (int i = 0; i < 8; ++i)
#pragma unroll
    for (int j = 0; j < 4; ++j) acc[i][j] = 0.0f;
#pragma unroll 4
  for (int c = 0; c < KDIM; c += 4) {
    const float4 wv0 = *(const float4*)&wl[tc * 4 + 0][c];
    const float4 wv1 = *(const float4*)&wl[tc * 4 + 1][c];
    const float4 wv2 = *(const float4*)&wl[tc * 4 + 2][c];
    const float4 wv3 = *(const float4*)&wl[tc * 4 + 3][c];
#pragma unroll
    for (int i = 0; i < 8; ++i) {
      const float4 xv = *(const float4*)&xs[tr + 16 * i][c];
      acc[i][0] = fmaf(xv.x, wv0.x, acc[i][0]);
      acc[i][0] = fmaf(xv.y, wv0.y, acc[i][0]);
      acc[i][0] = fmaf(xv.z, wv0.z, acc[i][0]);
      acc[i][0] = fmaf(xv.w, wv0.w, acc[i][0]);
      acc[i][1] = fmaf(xv.x, wv1.x, acc[i][1]);
      acc[i][1] = fmaf(xv.y, wv1.y, acc[i][1]);
      acc[i][1] = fmaf(xv.z, wv1.z, acc[i][1]);
      acc[i][1] = fmaf(xv.w, wv1.w, acc[i][1]);
      acc[i][2] = fmaf(xv.x, wv2.x, acc[i][2]);
      acc[i][2] = fmaf(xv.y, wv2.y, acc[i][2]);
      acc[i][2] = fmaf(xv.z, wv2.z, acc[i][2]);
      acc[i][2] = fmaf(xv.w, wv2.w, acc[i][2]);
      acc[i][3] = fmaf(xv.x, wv3.x, acc[i][3]);
      acc[i][3] = fmaf(xv.y, wv3.y, acc[i][3]);
      acc[i][3] = fmaf(xv.z, wv3.z, acc[i][3]);
      acc[i][3] = fmaf(xv.w, wv3.w, acc[i][3]);
    }
  }
}

// Epilogue: add bias, write y, and per-channel {sum, sumsq} partials.
__device__ __forceinline__ void gemm_store_stats(float acc[8][4], const float* __restrict__ bias,
                                                 float* __restrict__ y,
                                                 float* __restrict__ psum, float* __restrict__ psq,
                                                 int R0, int tr, int tc, int bid) {
  float bb[4];
#pragma unroll
  for (int j = 0; j < 4; ++j) bb[j] = bias[tc * 4 + j];
  float sum[4] = {0, 0, 0, 0}, sq[4] = {0, 0, 0, 0};
#pragma unroll
  for (int i = 0; i < 8; ++i) {
    float v[4];
#pragma unroll
    for (int j = 0; j < 4; ++j) {
      const float t = acc[i][j] + bb[j];
      v[j] = t;
      sum[j] += t;
      sq[j] = fmaf(t, t, sq[j]);
    }
    *(float4*)&y[((size_t)(R0 + tr + 16 * i)) * kC1 + tc * 4] =
        make_float4(v[0], v[1], v[2], v[3]);
  }
#pragma unroll
  for (int off = 1; off < 16; off <<= 1) {
#pragma unroll
    for (int j = 0; j < 4; ++j) {
      sum[j] += __shfl_xor(sum[j], off, 64);
      sq[j]  += __shfl_xor(sq[j], off, 64);
    }
  }
  if (tr == 0) {
    *(float4*)&psum[(size_t)bid * kC1 + tc * 4] = make_float4(sum[0], sum[1], sum[2], sum[3]);
    *(float4*)&psq[(size_t)bid * kC1 + tc * 4]  = make_float4(sq[0], sq[1], sq[2], sq[3]);
  }
}

// ---------------- Layer 1: fused gather + GEMM(K=67->68, N=64) ---------------
__global__ __launch_bounds__(256) void gemm1_kernel(
    const float* __restrict__ xyz, const float* __restrict__ points,
    const float* __restrict__ newxyz, const int* __restrict__ gidx,
    const float* __restrict__ W, const float* __restrict__ bias,
    float* __restrict__ y, float* __restrict__ psum, float* __restrict__ psq) {
  __shared__ float xs[kTileR][kC0P];
  __shared__ float wl[kC1][kC0P];
  __shared__ int   gl[kTileR];
  __shared__ float nx[4][3];
  const int tid = threadIdx.x;
  const int R0  = blockIdx.x * kTileR;
  const int b   = R0 >> 15;          // 32768 rows per batch
  const int G0  = R0 >> 5;           // global group id base (4 groups per tile)
  if (tid < kTileR) gl[tid] = gidx[R0 + tid];
  if (tid >= 128 && tid < 140) {
    const int q = (tid - 128) / 3, c = (tid - 128) % 3;
    nx[q][c] = newxyz[(size_t)(G0 + q) * 3 + c];
  }
  // Stage W reordered: c'=0..2 -> W[:,0..2], c'=3 -> 0, c'>=4 -> W[:,c'-1]
  for (int i = tid; i < kC1 * kC0P; i += 256) {
    const int o = i / kC0P, c = i % kC0P;
    float v;
    if (c < 3)       v = W[o * kC0 + c];
    else if (c == 3) v = 0.0f;
    else             v = W[o * kC0 + (c - 1)];
    wl[o][c] = v;
  }
  __syncthreads();
  // Gather-stage xs: [dx,dy,dz,0, p0..p63]
  for (int i = tid; i < kTileR * 17; i += 256) {
    const int r = i / 17, q = i % 17;
    const int n = gl[r];
    if (q == 0) {
      const float* xp = xyz + ((size_t)(b * kN + n)) * 3;
      const int sq4 = r >> 5;
      xs[r][0] = __fsub_rn(xp[0], nx[sq4][0]);
      xs[r][1] = __fsub_rn(xp[1], nx[sq4][1]);
      xs[r][2] = __fsub_rn(xp[2], nx[sq4][2]);
      xs[r][3] = 0.0f;
    } else {
      const float4 p = *(const float4*)(points + ((size_t)(b * kN + n)) * kInCh + (q - 1) * 4);
      *(float4*)&xs[r][q * 4] = p;
    }
  }
  __syncthreads();
  const int tr = tid & 15, tc = tid >> 4;
  float acc[8][4];
  gemm_compute<kC0P>(xs, wl, tr, tc, acc);
  gemm_store_stats(acc, bias, y, psum, psq, R0, tr, tc, blockIdx.x);
}

// ---------------- Layer 2: GEMM(K=64, N=64), BN1+ReLU fused on input --------
__global__ __launch_bounds__(256) void gemm2_kernel(
    const float* __restrict__ x, const float* __restrict__ W, const float* __restrict__ bias,
    const float* __restrict__ a, const float* __restrict__ sft,
    float* __restrict__ y, float* __restrict__ psum, float* __restrict__ psq) {
  __shared__ float xs[kTileR][kC0P];
  __shared__ float wl[kC1][kC0P];
  const int tid = threadIdx.x;
  const int R0  = blockIdx.x * kTileR;
  for (int i = tid; i < kTileR * 16; i += 256) {
    const int r = i >> 4, cq = i & 15;
    float4 v = *(const float4*)&x[((size_t)(R0 + r)) * kC1 + cq * 4];
    const float4 av = *(const float4*)&a[cq * 4];
    const float4 sv = *(const float4*)&sft[cq * 4];
    v.x = fmaxf(fmaf(av.x, v.x, sv.x), 0.0f);
    v.y = fmaxf(fmaf(av.y, v.y, sv.y), 0.0f);
    v.z = fmaxf(fmaf(av.z, v.z, sv.z), 0.0f);
    v.w = fmaxf(fmaf(av.w, v.w, sv.w), 0.0f);
    *(float4*)&xs[r][cq * 4] = v;
  }
  for (int i = tid; i < kC1 * 16; i += 256) {
    const int o = i >> 4, cq = i & 15;
    *(float4*)&wl[o][cq * 4] = *(const float4*)&W[(size_t)o * kC1 + cq * 4];
  }
  __syncthreads();
  const int tr = tid & 15, tc = tid >> 4;
  float acc[8][4];
  gemm_compute<kC1>(xs, wl, tr, tc, acc);
  gemm_store_stats(acc, bias, y, psum, psq, R0, tr, tc, blockIdx.x);
}

// ---------------- Layer 3 pass A: stats only (no y3 store) -------------------
__global__ __launch_bounds__(256) void gemm3a_kernel(
    const float* __restrict__ x, const float* __restrict__ W, const float* __restrict__ bias,
    const float* __restrict__ a, const float* __restrict__ sft,
    float* __restrict__ psum, float* __restrict__ psq) {
  __shared__ float xs[kTileR][kC0P];
  __shared__ float wl[kC1][kC0P];
  const int tid = threadIdx.x;
  const int R0  = blockIdx.x * kTileR;
  for (int i = tid; i < kTileR * 16; i += 256) {
    const int r = i >> 4, cq = i & 15;
    float4 v = *(const float4*)&x[((size_t)(R0 + r)) * kC1 + cq * 4];
    const float4 av = *(const float4*)&a[cq * 4];
    const float4 sv = *(const float4*)&sft[cq * 4];
    v.x = fmaxf(fmaf(av.x, v.x, sv.x), 0.0f);
    v.y = fmaxf(fmaf(av.y, v.y, sv.y), 0.0f);
    v.z = fmaxf(fmaf(av.z, v.z, sv.z), 0.0f);
    v.w = fmaxf(fmaf(av.w, v.w, sv.w), 0.0f);
    *(float4*)&xs[r][cq * 4] = v;
  }
  const int tr = tid & 15, tc = tid >> 4;
  for (int cp = 0; cp < 2; ++cp) {
    __syncthreads();
    for (int i = tid; i < kC1 * 16; i += 256) {
      const int o = i >> 4, cq = i & 15;
      *(float4*)&wl[o][cq * 4] = *(const float4*)&W[((size_t)(cp * 64 + o)) * kC1 + cq * 4];
    }
    __syncthreads();
    float acc[8][4];
    gemm_compute<kC1>(xs, wl, tr, tc, acc);
    float bb[4];
#pragma unroll
    for (int j = 0; j < 4; ++j) bb[j] = bias[cp * 64 + tc * 4 + j];
    float sum[4] = {0, 0, 0, 0}, sq[4] = {0, 0, 0, 0};
#pragma unroll
    for (int i = 0; i < 8; ++i)
#pragma unroll
      for (int j = 0; j < 4; ++j) {
        const float t = acc[i][j] + bb[j];
        sum[j] += t;
        sq[j] = fmaf(t, t, sq[j]);
      }
#pragma unroll
    for (int off = 1; off < 16; off <<= 1) {
#pragma unroll
      for (int j = 0; j < 4; ++j) {
        sum[j] += __shfl_xor(sum[j], off, 64);
        sq[j]  += __shfl_xor(sq[j], off, 64);
      }
    }
    if (tr == 0) {
      *(float4*)&psum[(size_t)blockIdx.x * kC3 + cp * 64 + tc * 4] =
          make_float4(sum[0], sum[1], sum[2], sum[3]);
      *(float4*)&psq[(size_t)blockIdx.x * kC3 + cp * 64 + tc * 4] =
          make_float4(sq[0], sq[1], sq[2], sq[3]);
    }
  }
}

// ---------------- Layer 3 pass B: recompute + BN3 + ReLU + max over k -------
__global__ __launch_bounds__(256) void gemm3b_kernel(
    const float* __restrict__ x, const float* __restrict__ W, const float* __restrict__ bias,
    const float* __restrict__ a2, const float* __restrict__ s2,
    const float* __restrict__ a3, const float* __restrict__ s3,
    float* __restrict__ outp) {
  __shared__ float xs[kTileR][kC0P];
  __shared__ float wl[kC1][kC0P];
  const int tid = threadIdx.x;
  const int R0  = blockIdx.x * kTileR;
  const int G0  = R0 >> 5;
  for (int i = tid; i < kTileR * 16; i += 256) {
    const int r = i >> 4, cq = i & 15;
    float4 v = *(const float4*)&x[((size_t)(R0 + r)) * kC1 + cq * 4];
    const float4 av = *(const float4*)&a2[cq * 4];
    const float4 sv = *(const float4*)&s2[cq * 4];
    v.x = fmaxf(fmaf(av.x, v.x, sv.x), 0.0f);
    v.y = fmaxf(fmaf(av.y, v.y, sv.y), 0.0f);
    v.z = fmaxf(fmaf(av.z, v.z, sv.z), 0.0f);
    v.w = fmaxf(fmaf(av.w, v.w, sv.w), 0.0f);
    *(float4*)&xs[r][cq * 4] = v;
  }
  const int tr = tid & 15, tc = tid >> 4;
  for (int cp = 0; cp < 2; ++cp) {
    __syncthreads();
    for (int i = tid; i < kC1 * 16; i += 256) {
      const int o = i >> 4, cq = i & 15;
      *(float4*)&wl[o][cq * 4] = *(const float4*)&W[((size_t)(cp * 64 + o)) * kC1 + cq * 4];
    }
    __syncthreads();
    float acc[8][4];
    gemm_compute<kC1>(xs, wl, tr, tc, acc);
    float bb[4], av3[4], sv3[4];
#pragma unroll
    for (int j = 0; j < 4; ++j) {
      const int col = cp * 64 + tc * 4 + j;
      bb[j]  = bias[col];
      av3[j] = a3[col];
      sv3[j] = s3[col];
    }
    float mm[4][4];
#pragma unroll
    for (int i = 0; i < 8; ++i) {
      const int s4 = i >> 1;
#pragma unroll
      for (int j = 0; j < 4; ++j) {
        const float t = acc[i][j] + bb[j];
        const float v = fmaxf(fmaf(av3[j], t, sv3[j]), 0.0f);
        mm[s4][j] = (i & 1) ? fmaxf(mm[s4][j], v) : v;
      }
    }
#pragma unroll
    for (int off = 1; off < 16; off <<= 1)
#pragma unroll
      for (int s4 = 0; s4 < 4; ++s4)
#pragma unroll
        for (int j = 0; j < 4; ++j)
          mm[s4][j] = fmaxf(mm[s4][j], __shfl_xor(mm[s4][j], off, 64));
    if (tr == 0) {
#pragma unroll
      for (int s4 = 0; s4 < 4; ++s4) {
        *(float4*)&outp[(size_t)(G0 + s4) * kC3 + cp * 64 + tc * 4] =
            make_float4(mm[s4][0], mm[s4][1], mm[s4][2], mm[s4][3]);
      }
    }
  }
}

// ---------------- BN stats finalize (parallel) -------------------------------
// One block per channel; 256 threads reduce the 2048 per-block partials.
__global__ __launch_bounds__(256) void finalize_kernel(
    const float* __restrict__ psum, const float* __restrict__ psq,
    const float* __restrict__ g, const float* __restrict__ be,
    float* __restrict__ a, float* __restrict__ s, int nch) {
  __shared__ float red[2][4];
  const int c   = blockIdx.x;
  const int tid = threadIdx.x;
  const int lane = tid & 63, wid = tid >> 6;
  float sum = 0.f, sq = 0.f;
  for (int i = tid; i < kGemmBlocks; i += 256) {
    sum += psum[(size_t)i * nch + c];
    sq  += psq[(size_t)i * nch + c];
  }
#pragma unroll
  for (int off = 1; off < 64; off <<= 1) {
    sum += __shfl_xor(sum, off, 64);
    sq  += __shfl_xor(sq, off, 64);
  }
  if (lane == 0) { red[0][wid] = sum; red[1][wid] = sq; }
  __syncthreads();
  if (tid == 0) {
    const float tsum = red[0][0] + red[0][1] + red[0][2] + red[0][3];
    const float tsq  = red[1][0] + red[1][1] + red[1][2] + red[1][3];
    const float inv = 1.0f / (float)kRows;
    const float mu  = tsum * inv;
    const float var = tsq * inv - mu * mu;
    const float rs  = 1.0f / sqrtf(var + 1e-5f);
    const float av  = g[c] * rs;
    a[c] = av;
    s[c] = be[c] - av * mu;
  }
}

}  // namespace

extern "C" void kernel_launch(void* const* d_in, const int* in_sizes, int n_in,
                              void* d_out, int out_size, void* d_ws, size_t ws_size,
                              hipStream_t stream) {
  const float* xyz    = (const float*)d_in[0];
  const float* points = (const float*)d_in[1];
  const float* W0  = (const float*)d_in[2];
  const float* b0  = (const float*)d_in[3];
  const float* g0  = (const float*)d_in[4];
  const float* be0 = (const float*)d_in[5];
  const float* W1  = (const float*)d_in[6];
  const float* b1  = (const float*)d_in[7];
  const float* g1  = (const float*)d_in[8];
  const float* be1 = (const float*)d_in[9];
  const float* W2  = (const float*)d_in[10];
  const float* b2  = (const float*)d_in[11];
  const float* g2  = (const float*)d_in[12];
  const float* be2 = (const float*)d_in[13];

  float* out      = (float*)d_out;
  float* newxyz   = out;            // 8*1024*3 = 24576 floats
  float* newpts   = out + 24576;    // 8*1024*128

  char* wsb = (char*)d_ws;
  int*   gidx = (int*)wsb;                              // 1 MiB
  float* a1 = (float*)(wsb + (1u << 20));
  float* s1 = a1 + 128;
  float* a2 = s1 + 128;
  float* s2 = a2 + 128;
  float* a3 = s2 + 128;
  float* s3 = a3 + 128;
  float* psum = (float*)(wsb + 2u * (1u << 20));        // 1 MiB
  float* psq  = (float*)(wsb + 3u * (1u << 20));        // 1 MiB
  float* y1 = (float*)(wsb + 4u * (1u << 20));          // 64 MiB
  float* y2 = (float*)(wsb + 68u * (1u << 20));         // 64 MiB

  fps_kernel<<<kNB, 64, 0, stream>>>(xyz, newxyz);
  ballq_kernel<<<(kNB * kS) / 4, 256, 0, stream>>>(xyz, newxyz, gidx);
  gemm1_kernel<<<kGemmBlocks, 256, 0, stream>>>(xyz, points, newxyz, gidx, W0, b0, y1, psum, psq);
  finalize_kernel<<<64, 256, 0, stream>>>(psum, psq, g0, be0, a1, s1, 64);
  gemm2_kernel<<<kGemmBlocks, 256, 0, stream>>>(y1, W1, b1, a1, s1, y2, psum, psq);
  finalize_kernel<<<64, 256, 0, stream>>>(psum, psq, g1, be1, a2, s2, 64);
  gemm3a_kernel<<<kGemmBlocks, 256, 0, stream>>>(y2, W2, b2, a2, s2, psum, psq);
  finalize_kernel<<<128, 256, 0, stream>>>(psum, psq, g2, be2, a3, s3, 128);
  gemm3b_kernel<<<kGemmBlocks, 256, 0, stream>>>(y2, W2, b2, a2, s2, a3, s3, newpts);
}

// Round 6
// 4231.364 us; speedup vs baseline: 2.0923x; 1.7421x over previous
//
#include <hip/hip_runtime.h>
#include <cstdint>
#include <cstddef>

namespace {

constexpr int kNB   = 8;
constexpr int kN    = 4096;
constexpr int kS    = 1024;   // NPOINT
constexpr int kK    = 32;     // NSAMPLE
constexpr int kInCh = 64;
constexpr int kC0   = 67;     // 3 + 64
constexpr int kC0P  = 68;     // padded (zero col at c'=3)
constexpr int kC1   = 64;
constexpr int kC3   = 128;
constexpr int kRows = kNB * kS * kK;  // 262144
constexpr int kTileR = 128;
constexpr int kGemmBlocks = kRows / kTileR;  // 2048

// ---------------- Farthest point sampling -----------------------------------
// Empirical record (r0-r5): 1024-thread/4pt/2-barrier structure = 2.05 us/step;
// 8 waves = 3.1; 1 wave = 6.9 (spill or not). Lesson: maximize lanes on the
// update, keep per-lane work tiny; exposed latency ~130 cyc per point-update.
// This version: SAME structure, but TWO batches per block (A/B interleaved) so
// the two independent serial chains overlap their latencies; 2 barriers serve
// both batches. Per-batch arithmetic is bit-identical to numpy:
// d = ((dx*dx+dy*dy)+dz*dz) with RN ops (no FMA), argmax = first max
// (per-thread ascending-t scan; butterfly + scan tie-break by min index).
__global__ __launch_bounds__(1024) void fps_kernel(const float* __restrict__ xyz,
                                                   float* __restrict__ newxyz) {
  __shared__ float sxA[kN], syA[kN], szA[kN];
  __shared__ float sxB[kN], syB[kN], szB[kN];
  __shared__ float red_vA[16], red_vB[16];
  __shared__ int   red_iA[16], red_iB[16];
  const int tid = threadIdx.x;
  const int bA = blockIdx.x * 2;
  const int bB = bA + 1;
  const float* xbA = xyz + (size_t)bA * kN * 3;
  const float* xbB = xyz + (size_t)bB * kN * 3;
  for (int i = tid; i < kN; i += 1024) {
    sxA[i] = xbA[i * 3 + 0]; syA[i] = xbA[i * 3 + 1]; szA[i] = xbA[i * 3 + 2];
    sxB[i] = xbB[i * 3 + 0]; syB[i] = xbB[i * 3 + 1]; szB[i] = xbB[i * 3 + 2];
  }
  __syncthreads();
  float pxA[4], pyA[4], pzA[4], dA[4];
  float pxB[4], pyB[4], pzB[4], dB[4];
#pragma unroll
  for (int t = 0; t < 4; ++t) {
    const int i = tid + 1024 * t;
    pxA[t] = sxA[i]; pyA[t] = syA[i]; pzA[t] = szA[i]; dA[t] = 1e10f;
    pxB[t] = sxB[i]; pyB[t] = syB[i]; pzB[t] = szB[i]; dB[t] = 1e10f;
  }
  float cxA = sxA[0], cyA = syA[0], czA = szA[0];
  float cxB = sxB[0], cyB = syB[0], czB = szB[0];
  float* obA = newxyz + (size_t)bA * kS * 3;
  float* obB = newxyz + (size_t)bB * kS * 3;
  if (tid == 0) {
    obA[0] = cxA; obA[1] = cyA; obA[2] = czA;
    obB[0] = cxB; obB[1] = cyB; obB[2] = czB;
  }
  const int lane = tid & 63;
  const int wid  = tid >> 6;
  for (int j = 1; j < kS; ++j) {
    float bvA = -1.0f; int biA = 0;
    float bvB = -1.0f; int biB = 0;
#pragma unroll
    for (int t = 0; t < 4; ++t) {
      {
        const float dx = __fsub_rn(pxA[t], cxA);
        const float dy = __fsub_rn(pyA[t], cyA);
        const float dz = __fsub_rn(pzA[t], czA);
        const float d0 = __fadd_rn(__fadd_rn(__fmul_rn(dx, dx), __fmul_rn(dy, dy)),
                                   __fmul_rn(dz, dz));
        const float d = fminf(dA[t], d0);
        dA[t] = d;
        if (d > bvA) { bvA = d; biA = tid + 1024 * t; }  // ascending -> first max
      }
      {
        const float dx = __fsub_rn(pxB[t], cxB);
        const float dy = __fsub_rn(pyB[t], cyB);
        const float dz = __fsub_rn(pzB[t], czB);
        const float d0 = __fadd_rn(__fadd_rn(__fmul_rn(dx, dx), __fmul_rn(dy, dy)),
                                   __fmul_rn(dz, dz));
        const float d = fminf(dB[t], d0);
        dB[t] = d;
        if (d > bvB) { bvB = d; biB = tid + 1024 * t; }
      }
    }
#pragma unroll
    for (int off = 1; off < 64; off <<= 1) {
      const float ovA = __shfl_xor(bvA, off, 64);
      const int   oiA = __shfl_xor(biA, off, 64);
      const float ovB = __shfl_xor(bvB, off, 64);
      const int   oiB = __shfl_xor(biB, off, 64);
      if (ovA > bvA || (ovA == bvA && oiA < biA)) { bvA = ovA; biA = oiA; }
      if (ovB > bvB || (ovB == bvB && oiB < biB)) { bvB = ovB; biB = oiB; }
    }
    __syncthreads();   // previous iteration's red reads done
    if (lane == 0) {
      red_vA[wid] = bvA; red_iA[wid] = biA;
      red_vB[wid] = bvB; red_iB[wid] = biB;
    }
    __syncthreads();
    float fvA = red_vA[0]; int fiA = red_iA[0];
    float fvB = red_vB[0]; int fiB = red_iB[0];
#pragma unroll
    for (int w = 1; w < 16; ++w) {
      const float vA = red_vA[w]; const int iA2 = red_iA[w];
      if (vA > fvA || (vA == fvA && iA2 < fiA)) { fvA = vA; fiA = iA2; }
      const float vB = red_vB[w]; const int iB2 = red_iB[w];
      if (vB > fvB || (vB == fvB && iB2 < fiB)) { fvB = vB; fiB = iB2; }
    }
    cxA = sxA[fiA]; cyA = syA[fiA]; czA = szA[fiA];
    cxB = sxB[fiB]; cyB = syB[fiB]; czB = szB[fiB];
    if (tid == 0) {
      obA[j * 3 + 0] = cxA; obA[j * 3 + 1] = cyA; obA[j * 3 + 2] = czA;
      obB[j * 3 + 0] = cxB; obB[j * 3 + 1] = cyB; obB[j * 3 + 2] = czB;
    }
  }
}

// ---------------- Ball query -------------------------------------------------
// One wave per query point; first-32 in-radius indices in ascending order,
// padded with the first index. Distance uses the reference's expanded form and
// the compare is done in double (python float radius*radius).
__global__ __launch_bounds__(256) void ballq_kernel(const float* __restrict__ xyz,
                                                    const float* __restrict__ newxyz,
                                                    int* __restrict__ gidx) {
  const int tid  = threadIdx.x;
  const int lane = tid & 63;
  const int gq   = blockIdx.x * 4 + (tid >> 6);
  const int b    = gq >> 10;
  const float* xb = xyz + (size_t)b * kN * 3;
  const float qx = newxyz[gq * 3 + 0];
  const float qy = newxyz[gq * 3 + 1];
  const float qz = newxyz[gq * 3 + 2];
  const float s2 = __fadd_rn(__fadd_rn(__fmul_rn(qx, qx), __fmul_rn(qy, qy)),
                             __fmul_rn(qz, qz));
  const double r2 = 0.2 * 0.2;
  int taken = 0;
  int first = 0;
  bool hasfirst = false;
  int* g = gidx + (size_t)gq * kK;
  for (int base = 0; base < kN; base += 64) {
    const int n = base + lane;
    const float fx = xb[n * 3 + 0], fy = xb[n * 3 + 1], fz = xb[n * 3 + 2];
    const float p2 = __fadd_rn(__fadd_rn(__fmul_rn(fx, fx), __fmul_rn(fy, fy)),
                               __fmul_rn(fz, fz));
    const float dt = __fadd_rn(__fadd_rn(__fmul_rn(qx, fx), __fmul_rn(qy, fy)),
                               __fmul_rn(qz, fz));
    const float d = __fadd_rn(__fadd_rn(__fmul_rn(-2.0f, dt), s2), p2);
    const bool in = !((double)d > r2);
    const unsigned long long m = __ballot(in);
    if (!hasfirst && m != 0ull) { first = base + __builtin_ctzll(m); hasfirst = true; }
    if (in) {
      const int pos = taken + (int)__popcll(m & ((1ull << lane) - 1ull));
      if (pos < kK) g[pos] = n;
    }
    taken += (int)__popcll(m);
    if (taken >= kK) break;
  }
  for (int p = taken + lane; p < kK; p += 64) g[p] = first;
}

// ---------------- GEMM core (shared pattern) ---------------------------------
// Block: 256 threads, tile 128 rows x 64 cols. Thread (tr = tid&15, tc = tid>>4)
// computes rows {tr+16i} x cols {tc*4+j}, acc[8][4].

template <int KDIM>
__device__ __forceinline__ void gemm_compute(const float xs[kTileR][kC0P],
                                             const float wl[kC1][kC0P],
                                             int tr, int tc, float acc[8][4]) {
#pragma unroll
  for (int i = 0; i < 8; ++i)
#pragma unroll
    for (int j = 0; j < 4; ++j) acc[i][j] = 0.0f;
#pragma unroll 4
  for (int c = 0; c < KDIM; c += 4) {
    const float4 wv0 = *(const float4*)&wl[tc * 4 + 0][c];
    const float4 wv1 = *(const float4*)&wl[tc * 4 + 1][c];
    const float4 wv2 = *(const float4*)&wl[tc * 4 + 2][c];
    const float4 wv3 = *(const float4*)&wl[tc * 4 + 3][c];
#pragma unroll
    for (int i = 0; i < 8; ++i) {
      const float4 xv = *(const float4*)&xs[tr + 16 * i][c];
      acc[i][0] = fmaf(xv.x, wv0.x, acc[i][0]);
      acc[i][0] = fmaf(xv.y, wv0.y, acc[i][0]);
      acc[i][0] = fmaf(xv.z, wv0.z, acc[i][0]);
      acc[i][0] = fmaf(xv.w, wv0.w, acc[i][0]);
      acc[i][1] = fmaf(xv.x, wv1.x, acc[i][1]);
      acc[i][1] = fmaf(xv.y, wv1.y, acc[i][1]);
      acc[i][1] = fmaf(xv.z, wv1.z, acc[i][1]);
      acc[i][1] = fmaf(xv.w, wv1.w, acc[i][1]);
      acc[i][2] = fmaf(xv.x, wv2.x, acc[i][2]);
      acc[i][2] = fmaf(xv.y, wv2.y, acc[i][2]);
      acc[i][2] = fmaf(xv.z, wv2.z, acc[i][2]);
      acc[i][2] = fmaf(xv.w, wv2.w, acc[i][2]);
      acc[i][3] = fmaf(xv.x, wv3.x, acc[i][3]);
      acc[i][3] = fmaf(xv.y, wv3.y, acc[i][3]);
      acc[i][3] = fmaf(xv.z, wv3.z, acc[i][3]);
      acc[i][3] = fmaf(xv.w, wv3.w, acc[i][3]);
    }
  }
}

// Epilogue: add bias, write y, and per-channel {sum, sumsq} partials.
__device__ __forceinline__ void gemm_store_stats(float acc[8][4], const float* __restrict__ bias,
                                                 float* __restrict__ y,
                                                 float* __restrict__ psum, float* __restrict__ psq,
                                                 int R0, int tr, int tc, int bid) {
  float bb[4];
#pragma unroll
  for (int j = 0; j < 4; ++j) bb[j] = bias[tc * 4 + j];
  float sum[4] = {0, 0, 0, 0}, sq[4] = {0, 0, 0, 0};
#pragma unroll
  for (int i = 0; i < 8; ++i) {
    float v[4];
#pragma unroll
    for (int j = 0; j < 4; ++j) {
      const float t = acc[i][j] + bb[j];
      v[j] = t;
      sum[j] += t;
      sq[j] = fmaf(t, t, sq[j]);
    }
    *(float4*)&y[((size_t)(R0 + tr + 16 * i)) * kC1 + tc * 4] =
        make_float4(v[0], v[1], v[2], v[3]);
  }
#pragma unroll
  for (int off = 1; off < 16; off <<= 1) {
#pragma unroll
    for (int j = 0; j < 4; ++j) {
      sum[j] += __shfl_xor(sum[j], off, 64);
      sq[j]  += __shfl_xor(sq[j], off, 64);
    }
  }
  if (tr == 0) {
    *(float4*)&psum[(size_t)bid * kC1 + tc * 4] = make_float4(sum[0], sum[1], sum[2], sum[3]);
    *(float4*)&psq[(size_t)bid * kC1 + tc * 4]  = make_float4(sq[0], sq[1], sq[2], sq[3]);
  }
}

// ---------------- Layer 1: fused gather + GEMM(K=67->68, N=64) ---------------
__global__ __launch_bounds__(256) void gemm1_kernel(
    const float* __restrict__ xyz, const float* __restrict__ points,
    const float* __restrict__ newxyz, const int* __restrict__ gidx,
    const float* __restrict__ W, const float* __restrict__ bias,
    float* __restrict__ y, float* __restrict__ psum, float* __restrict__ psq) {
  __shared__ float xs[kTileR][kC0P];
  __shared__ float wl[kC1][kC0P];
  __shared__ int   gl[kTileR];
  __shared__ float nx[4][3];
  const int tid = threadIdx.x;
  const int R0  = blockIdx.x * kTileR;
  const int b   = R0 >> 15;          // 32768 rows per batch
  const int G0  = R0 >> 5;           // global group id base (4 groups per tile)
  if (tid < kTileR) gl[tid] = gidx[R0 + tid];
  if (tid >= 128 && tid < 140) {
    const int q = (tid - 128) / 3, c = (tid - 128) % 3;
    nx[q][c] = newxyz[(size_t)(G0 + q) * 3 + c];
  }
  // Stage W reordered: c'=0..2 -> W[:,0..2], c'=3 -> 0, c'>=4 -> W[:,c'-1]
  for (int i = tid; i < kC1 * kC0P; i += 256) {
    const int o = i / kC0P, c = i % kC0P;
    float v;
    if (c < 3)       v = W[o * kC0 + c];
    else if (c == 3) v = 0.0f;
    else             v = W[o * kC0 + (c - 1)];
    wl[o][c] = v;
  }
  __syncthreads();
  // Gather-stage xs: [dx,dy,dz,0, p0..p63]
  for (int i = tid; i < kTileR * 17; i += 256) {
    const int r = i / 17, q = i % 17;
    const int n = gl[r];
    if (q == 0) {
      const float* xp = xyz + ((size_t)(b * kN + n)) * 3;
      const int sq4 = r >> 5;
      xs[r][0] = __fsub_rn(xp[0], nx[sq4][0]);
      xs[r][1] = __fsub_rn(xp[1], nx[sq4][1]);
      xs[r][2] = __fsub_rn(xp[2], nx[sq4][2]);
      xs[r][3] = 0.0f;
    } else {
      const float4 p = *(const float4*)(points + ((size_t)(b * kN + n)) * kInCh + (q - 1) * 4);
      *(float4*)&xs[r][q * 4] = p;
    }
  }
  __syncthreads();
  const int tr = tid & 15, tc = tid >> 4;
  float acc[8][4];
  gemm_compute<kC0P>(xs, wl, tr, tc, acc);
  gemm_store_stats(acc, bias, y, psum, psq, R0, tr, tc, blockIdx.x);
}

// ---------------- Layer 2: GEMM(K=64, N=64), BN1+ReLU fused on input --------
__global__ __launch_bounds__(256) void gemm2_kernel(
    const float* __restrict__ x, const float* __restrict__ W, const float* __restrict__ bias,
    const float* __restrict__ a, const float* __restrict__ sft,
    float* __restrict__ y, float* __restrict__ psum, float* __restrict__ psq) {
  __shared__ float xs[kTileR][kC0P];
  __shared__ float wl[kC1][kC0P];
  const int tid = threadIdx.x;
  const int R0  = blockIdx.x * kTileR;
  for (int i = tid; i < kTileR * 16; i += 256) {
    const int r = i >> 4, cq = i & 15;
    float4 v = *(const float4*)&x[((size_t)(R0 + r)) * kC1 + cq * 4];
    const float4 av = *(const float4*)&a[cq * 4];
    const float4 sv = *(const float4*)&sft[cq * 4];
    v.x = fmaxf(fmaf(av.x, v.x, sv.x), 0.0f);
    v.y = fmaxf(fmaf(av.y, v.y, sv.y), 0.0f);
    v.z = fmaxf(fmaf(av.z, v.z, sv.z), 0.0f);
    v.w = fmaxf(fmaf(av.w, v.w, sv.w), 0.0f);
    *(float4*)&xs[r][cq * 4] = v;
  }
  for (int i = tid; i < kC1 * 16; i += 256) {
    const int o = i >> 4, cq = i & 15;
    *(float4*)&wl[o][cq * 4] = *(const float4*)&W[(size_t)o * kC1 + cq * 4];
  }
  __syncthreads();
  const int tr = tid & 15, tc = tid >> 4;
  float acc[8][4];
  gemm_compute<kC1>(xs, wl, tr, tc, acc);
  gemm_store_stats(acc, bias, y, psum, psq, R0, tr, tc, blockIdx.x);
}

// ---------------- Layer 3 pass A: stats only (no y3 store) -------------------
__global__ __launch_bounds__(256) void gemm3a_kernel(
    const float* __restrict__ x, const float* __restrict__ W, const float* __restrict__ bias,
    const float* __restrict__ a, const float* __restrict__ sft,
    float* __restrict__ psum, float* __restrict__ psq) {
  __shared__ float xs[kTileR][kC0P];
  __shared__ float wl[kC1][kC0P];
  const int tid = threadIdx.x;
  const int R0  = blockIdx.x * kTileR;
  for (int i = tid; i < kTileR * 16; i += 256) {
    const int r = i >> 4, cq = i & 15;
    float4 v = *(const float4*)&x[((size_t)(R0 + r)) * kC1 + cq * 4];
    const float4 av = *(const float4*)&a[cq * 4];
    const float4 sv = *(const float4*)&sft[cq * 4];
    v.x = fmaxf(fmaf(av.x, v.x, sv.x), 0.0f);
    v.y = fmaxf(fmaf(av.y, v.y, sv.y), 0.0f);
    v.z = fmaxf(fmaf(av.z, v.z, sv.z), 0.0f);
    v.w = fmaxf(fmaf(av.w, v.w, sv.w), 0.0f);
    *(float4*)&xs[r][cq * 4] = v;
  }
  const int tr = tid & 15, tc = tid >> 4;
  for (int cp = 0; cp < 2; ++cp) {
    __syncthreads();
    for (int i = tid; i < kC1 * 16; i += 256) {
      const int o = i >> 4, cq = i & 15;
      *(float4*)&wl[o][cq * 4] = *(const float4*)&W[((size_t)(cp * 64 + o)) * kC1 + cq * 4];
    }
    __syncthreads();
    float acc[8][4];
    gemm_compute<kC1>(xs, wl, tr, tc, acc);
    float bb[4];
#pragma unroll
    for (int j = 0; j < 4; ++j) bb[j] = bias[cp * 64 + tc * 4 + j];
    float sum[4] = {0, 0, 0, 0}, sq[4] = {0, 0, 0, 0};
#pragma unroll
    for (int i = 0; i < 8; ++i)
#pragma unroll
      for (int j = 0; j < 4; ++j) {
        const float t = acc[i][j] + bb[j];
        sum[j] += t;
        sq[j] = fmaf(t, t, sq[j]);
      }
#pragma unroll
    for (int off = 1; off < 16; off <<= 1) {
#pragma unroll
      for (int j = 0; j < 4; ++j) {
        sum[j] += __shfl_xor(sum[j], off, 64);
        sq[j]  += __shfl_xor(sq[j], off, 64);
      }
    }
    if (tr == 0) {
      *(float4*)&psum[(size_t)blockIdx.x * kC3 + cp * 64 + tc * 4] =
          make_float4(sum[0], sum[1], sum[2], sum[3]);
      *(float4*)&psq[(size_t)blockIdx.x * kC3 + cp * 64 + tc * 4] =
          make_float4(sq[0], sq[1], sq[2], sq[3]);
    }
  }
}

// ---------------- Layer 3 pass B: recompute + BN3 + ReLU + max over k -------
__global__ __launch_bounds__(256) void gemm3b_kernel(
    const float* __restrict__ x, const float* __restrict__ W, const float* __restrict__ bias,
    const float* __restrict__ a2, const float* __restrict__ s2,
    const float* __restrict__ a3, const float* __restrict__ s3,
    float* __restrict__ outp) {
  __shared__ float xs[kTileR][kC0P];
  __shared__ float wl[kC1][kC0P];
  const int tid = threadIdx.x;
  const int R0  = blockIdx.x * kTileR;
  const int G0  = R0 >> 5;
  for (int i = tid; i < kTileR * 16; i += 256) {
    const int r = i >> 4, cq = i & 15;
    float4 v = *(const float4*)&x[((size_t)(R0 + r)) * kC1 + cq * 4];
    const float4 av = *(const float4*)&a2[cq * 4];
    const float4 sv = *(const float4*)&s2[cq * 4];
    v.x = fmaxf(fmaf(av.x, v.x, sv.x), 0.0f);
    v.y = fmaxf(fmaf(av.y, v.y, sv.y), 0.0f);
    v.z = fmaxf(fmaf(av.z, v.z, sv.z), 0.0f);
    v.w = fmaxf(fmaf(av.w, v.w, sv.w), 0.0f);
    *(float4*)&xs[r][cq * 4] = v;
  }
  const int tr = tid & 15, tc = tid >> 4;
  for (int cp = 0; cp < 2; ++cp) {
    __syncthreads();
    for (int i = tid; i < kC1 * 16; i += 256) {
      const int o = i >> 4, cq = i & 15;
      *(float4*)&wl[o][cq * 4] = *(const float4*)&W[((size_t)(cp * 64 + o)) * kC1 + cq * 4];
    }
    __syncthreads();
    float acc[8][4];
    gemm_compute<kC1>(xs, wl, tr, tc, acc);
    float bb[4], av3[4], sv3[4];
#pragma unroll
    for (int j = 0; j < 4; ++j) {
      const int col = cp * 64 + tc * 4 + j;
      bb[j]  = bias[col];
      av3[j] = a3[col];
      sv3[j] = s3[col];
    }
    float mm[4][4];
#pragma unroll
    for (int i = 0; i < 8; ++i) {
      const int s4 = i >> 1;
#pragma unroll
      for (int j = 0; j < 4; ++j) {
        const float t = acc[i][j] + bb[j];
        const float v = fmaxf(fmaf(av3[j], t, sv3[j]), 0.0f);
        mm[s4][j] = (i & 1) ? fmaxf(mm[s4][j], v) : v;
      }
    }
#pragma unroll
    for (int off = 1; off < 16; off <<= 1)
#pragma unroll
      for (int s4 = 0; s4 < 4; ++s4)
#pragma unroll
        for (int j = 0; j < 4; ++j)
          mm[s4][j] = fmaxf(mm[s4][j], __shfl_xor(mm[s4][j], off, 64));
    if (tr == 0) {
#pragma unroll
      for (int s4 = 0; s4 < 4; ++s4) {
        *(float4*)&outp[(size_t)(G0 + s4) * kC3 + cp * 64 + tc * 4] =
            make_float4(mm[s4][0], mm[s4][1], mm[s4][2], mm[s4][3]);
      }
    }
  }
}

// ---------------- BN stats finalize (parallel) -------------------------------
// One block per channel; 256 threads reduce the 2048 per-block partials.
__global__ __launch_bounds__(256) void finalize_kernel(
    const float* __restrict__ psum, const float* __restrict__ psq,
    const float* __restrict__ g, const float* __restrict__ be,
    float* __restrict__ a, float* __restrict__ s, int nch) {
  __shared__ float red[2][4];
  const int c   = blockIdx.x;
  const int tid = threadIdx.x;
  const int lane = tid & 63, wid = tid >> 6;
  float sum = 0.f, sq = 0.f;
  for (int i = tid; i < kGemmBlocks; i += 256) {
    sum += psum[(size_t)i * nch + c];
    sq  += psq[(size_t)i * nch + c];
  }
#pragma unroll
  for (int off = 1; off < 64; off <<= 1) {
    sum += __shfl_xor(sum, off, 64);
    sq  += __shfl_xor(sq, off, 64);
  }
  if (lane == 0) { red[0][wid] = sum; red[1][wid] = sq; }
  __syncthreads();
  if (tid == 0) {
    const float tsum = red[0][0] + red[0][1] + red[0][2] + red[0][3];
    const float tsq  = red[1][0] + red[1][1] + red[1][2] + red[1][3];
    const float inv = 1.0f / (float)kRows;
    const float mu  = tsum * inv;
    const float var = tsq * inv - mu * mu;
    const float rs  = 1.0f / sqrtf(var + 1e-5f);
    const float av  = g[c] * rs;
    a[c] = av;
    s[c] = be[c] - av * mu;
  }
}

}  // namespace

extern "C" void kernel_launch(void* const* d_in, const int* in_sizes, int n_in,
                              void* d_out, int out_size, void* d_ws, size_t ws_size,
                              hipStream_t stream) {
  const float* xyz    = (const float*)d_in[0];
  const float* points = (const float*)d_in[1];
  const float* W0  = (const float*)d_in[2];
  const float* b0  = (const float*)d_in[3];
  const float* g0  = (const float*)d_in[4];
  const float* be0 = (const float*)d_in[5];
  const float* W1  = (const float*)d_in[6];
  const float* b1  = (const float*)d_in[7];
  const float* g1  = (const float*)d_in[8];
  const float* be1 = (const float*)d_in[9];
  const float* W2  = (const float*)d_in[10];
  const float* b2  = (const float*)d_in[11];
  const float* g2  = (const float*)d_in[12];
  const float* be2 = (const float*)d_in[13];

  float* out      = (float*)d_out;
  float* newxyz   = out;            // 8*1024*3 = 24576 floats
  float* newpts   = out + 24576;    // 8*1024*128

  char* wsb = (char*)d_ws;
  int*   gidx = (int*)wsb;                              // 1 MiB
  float* a1 = (float*)(wsb + (1u << 20));
  float* s1 = a1 + 128;
  float* a2 = s1 + 128;
  float* s2 = a2 + 128;
  float* a3 = s2 + 128;
  float* s3 = a3 + 128;
  float* psum = (float*)(wsb + 2u * (1u << 20));        // 1 MiB
  float* psq  = (float*)(wsb + 3u * (1u << 20));        // 1 MiB
  float* y1 = (float*)(wsb + 4u * (1u << 20));          // 64 MiB
  float* y2 = (float*)(wsb + 68u * (1u << 20));         // 64 MiB

  fps_kernel<<<kNB / 2, 1024, 0, stream>>>(xyz, newxyz);
  ballq_kernel<<<(kNB * kS) / 4, 256, 0, stream>>>(xyz, newxyz, gidx);
  gemm1_kernel<<<kGemmBlocks, 256, 0, stream>>>(xyz, points, newxyz, gidx, W0, b0, y1, psum, psq);
  finalize_kernel<<<64, 256, 0, stream>>>(psum, psq, g0, be0, a1, s1, 64);
  gemm2_kernel<<<kGemmBlocks, 256, 0, stream>>>(y1, W1, b1, a1, s1, y2, psum, psq);
  finalize_kernel<<<64, 256, 0, stream>>>(psum, psq, g1, be1, a2, s2, 64);
  gemm3a_kernel<<<kGemmBlocks, 256, 0, stream>>>(y2, W2, b2, a2, s2, psum, psq);
  finalize_kernel<<<128, 256, 0, stream>>>(psum, psq, g2, be2, a3, s3, 128);
  gemm3b_kernel<<<kGemmBlocks, 256, 0, stream>>>(y2, W2, b2, a2, s2, a3, s3, newpts);
}

// Round 7
// 1345.785 us; speedup vs baseline: 6.5784x; 3.1442x over previous
//
#include <hip/hip_runtime.h>
#include <cstdint>
#include <cstddef>

namespace {

constexpr int kNB   = 8;
constexpr int kN    = 4096;
constexpr int kS    = 1024;   // NPOINT
constexpr int kK    = 32;     // NSAMPLE
constexpr int kInCh = 64;
constexpr int kC0   = 67;     // 3 + 64
constexpr int kC0P  = 68;     // padded (zero col at c'=3)
constexpr int kC1   = 64;
constexpr int kC3   = 128;
constexpr int kRows = kNB * kS * kK;  // 262144
constexpr int kTileR = 128;
constexpr int kGemmBlocks = kRows / kTileR;  // 2048

// ---------------- Farthest point sampling -----------------------------------
// Evidence through r5: the step is CU-issue-bound across 16 waves (A/B
// interleave on one CU doubled step time; 8 waves/1 wave were worse). Keep the
// proven shape (8 blocks x 1024 threads, 4 pts/lane) and cut instructions:
//  - (dist,index) packed into ONE u64 key: (float_bits<<32) | ~index.
//    dist >= 0 so float bits are monotone; ~index makes u64-max == numpy's
//    "max value, FIRST index" argmax exactly.
//  - one barrier per step (parity slots red[j&1][wid]; WAR-safe: a slot is
//    only rewritten after the next barrier, when all its readers are done).
//  - cross-wave scan = 4-level u64-max register tree over 16 partials.
// Distance arithmetic bit-identical to numpy: ((dx*dx+dy*dy)+dz*dz), RN ops,
// no FMA.
__global__ __launch_bounds__(1024) void fps_kernel(const float* __restrict__ xyz,
                                                   float* __restrict__ newxyz) {
  __shared__ float sx[kN], sy[kN], sz[kN];
  __shared__ unsigned long long red[2][16];
  const int tid = threadIdx.x;
  const int b = blockIdx.x;
  const float* xb = xyz + (size_t)b * kN * 3;
  for (int i = tid; i < kN; i += 1024) {
    sx[i] = xb[i * 3 + 0];
    sy[i] = xb[i * 3 + 1];
    sz[i] = xb[i * 3 + 2];
  }
  __syncthreads();
  float px[4], py[4], pz[4], dist[4];
#pragma unroll
  for (int t = 0; t < 4; ++t) {
    const int i = tid + 1024 * t;
    px[t] = sx[i]; py[t] = sy[i]; pz[t] = sz[i];
    dist[t] = 1e10f;
  }
  float cx = sx[0], cy = sy[0], cz = sz[0];
  float* ob = newxyz + (size_t)b * kS * 3;
  if (tid == 0) { ob[0] = cx; ob[1] = cy; ob[2] = cz; }
  const int lane = tid & 63;
  const int wid  = tid >> 6;
  for (int j = 1; j < kS; ++j) {
    unsigned long long best = 0ull;
#pragma unroll
    for (int t = 0; t < 4; ++t) {
      const float dx = __fsub_rn(px[t], cx);
      const float dy = __fsub_rn(py[t], cy);
      const float dz = __fsub_rn(pz[t], cz);
      const float d0 = __fadd_rn(__fadd_rn(__fmul_rn(dx, dx), __fmul_rn(dy, dy)),
                                 __fmul_rn(dz, dz));
      const float d = fminf(dist[t], d0);
      dist[t] = d;
      const unsigned long long key =
          ((unsigned long long)__float_as_uint(d) << 32) |
          (unsigned int)~(unsigned int)(tid + 1024 * t);
      best = key > best ? key : best;
    }
    // Wave butterfly: u64-max over 64 lanes.
#pragma unroll
    for (int off = 1; off < 64; off <<= 1) {
      const unsigned long long o = __shfl_xor(best, off, 64);
      best = o > best ? o : best;
    }
    const int p = j & 1;
    if (lane == 0) red[p][wid] = best;
    __syncthreads();   // the ONLY barrier per step
    // 4-level u64-max tree over the 16 wave partials (loads batch).
    const unsigned long long r0 = red[p][0],  r1 = red[p][1];
    const unsigned long long r2 = red[p][2],  r3 = red[p][3];
    const unsigned long long r4 = red[p][4],  r5 = red[p][5];
    const unsigned long long r6 = red[p][6],  r7 = red[p][7];
    const unsigned long long r8 = red[p][8],  r9 = red[p][9];
    const unsigned long long rA = red[p][10], rB = red[p][11];
    const unsigned long long rC = red[p][12], rD = red[p][13];
    const unsigned long long rE = red[p][14], rF = red[p][15];
    const unsigned long long a0 = r0 > r1 ? r0 : r1;
    const unsigned long long a1 = r2 > r3 ? r2 : r3;
    const unsigned long long a2 = r4 > r5 ? r4 : r5;
    const unsigned long long a3 = r6 > r7 ? r6 : r7;
    const unsigned long long a4 = r8 > r9 ? r8 : r9;
    const unsigned long long a5 = rA > rB ? rA : rB;
    const unsigned long long a6 = rC > rD ? rC : rD;
    const unsigned long long a7 = rE > rF ? rE : rF;
    const unsigned long long b0 = a0 > a1 ? a0 : a1;
    const unsigned long long b1 = a2 > a3 ? a2 : a3;
    const unsigned long long b2 = a4 > a5 ? a4 : a5;
    const unsigned long long b3 = a6 > a7 ? a6 : a7;
    const unsigned long long c0 = b0 > b1 ? b0 : b1;
    const unsigned long long c1 = b2 > b3 ? b2 : b3;
    const unsigned long long w  = c0 > c1 ? c0 : c1;
    const int fi = (int)~(unsigned int)(w & 0xffffffffull);
    cx = sx[fi]; cy = sy[fi]; cz = sz[fi];
    if (tid == 0) { ob[j * 3 + 0] = cx; ob[j * 3 + 1] = cy; ob[j * 3 + 2] = cz; }
  }
}

// ---------------- Ball query -------------------------------------------------
// One wave per query point; first-32 in-radius indices in ascending order,
// padded with the first index. Distance uses the reference's expanded form and
// the compare is done in double (python float radius*radius).
__global__ __launch_bounds__(256) void ballq_kernel(const float* __restrict__ xyz,
                                                    const float* __restrict__ newxyz,
                                                    int* __restrict__ gidx) {
  const int tid  = threadIdx.x;
  const int lane = tid & 63;
  const int gq   = blockIdx.x * 4 + (tid >> 6);
  const int b    = gq >> 10;
  const float* xb = xyz + (size_t)b * kN * 3;
  const float qx = newxyz[gq * 3 + 0];
  const float qy = newxyz[gq * 3 + 1];
  const float qz = newxyz[gq * 3 + 2];
  const float s2 = __fadd_rn(__fadd_rn(__fmul_rn(qx, qx), __fmul_rn(qy, qy)),
                             __fmul_rn(qz, qz));
  const double r2 = 0.2 * 0.2;
  int taken = 0;
  int first = 0;
  bool hasfirst = false;
  int* g = gidx + (size_t)gq * kK;
  for (int base = 0; base < kN; base += 64) {
    const int n = base + lane;
    const float fx = xb[n * 3 + 0], fy = xb[n * 3 + 1], fz = xb[n * 3 + 2];
    const float p2 = __fadd_rn(__fadd_rn(__fmul_rn(fx, fx), __fmul_rn(fy, fy)),
                               __fmul_rn(fz, fz));
    const float dt = __fadd_rn(__fadd_rn(__fmul_rn(qx, fx), __fmul_rn(qy, fy)),
                               __fmul_rn(qz, fz));
    const float d = __fadd_rn(__fadd_rn(__fmul_rn(-2.0f, dt), s2), p2);
    const bool in = !((double)d > r2);
    const unsigned long long m = __ballot(in);
    if (!hasfirst && m != 0ull) { first = base + __builtin_ctzll(m); hasfirst = true; }
    if (in) {
      const int pos = taken + (int)__popcll(m & ((1ull << lane) - 1ull));
      if (pos < kK) g[pos] = n;
    }
    taken += (int)__popcll(m);
    if (taken >= kK) break;
  }
  for (int p = taken + lane; p < kK; p += 64) g[p] = first;
}

// ---------------- GEMM core (shared pattern) ---------------------------------
// Block: 256 threads, tile 128 rows x 64 cols. Thread (tr = tid&15, tc = tid>>4)
// computes rows {tr+16i} x cols {tc*4+j}, acc[8][4].

template <int KDIM>
__device__ __forceinline__ void gemm_compute(const float xs[kTileR][kC0P],
                                             const float wl[kC1][kC0P],
                                             int tr, int tc, float acc[8][4]) {
#pragma unroll
  for (int i = 0; i < 8; ++i)
#pragma unroll
    for (int j = 0; j < 4; ++j) acc[i][j] = 0.0f;
#pragma unroll 4
  for (int c = 0; c < KDIM; c += 4) {
    const float4 wv0 = *(const float4*)&wl[tc * 4 + 0][c];
    const float4 wv1 = *(const float4*)&wl[tc * 4 + 1][c];
    const float4 wv2 = *(const float4*)&wl[tc * 4 + 2][c];
    const float4 wv3 = *(const float4*)&wl[tc * 4 + 3][c];
#pragma unroll
    for (int i = 0; i < 8; ++i) {
      const float4 xv = *(const float4*)&xs[tr + 16 * i][c];
      acc[i][0] = fmaf(xv.x, wv0.x, acc[i][0]);
      acc[i][0] = fmaf(xv.y, wv0.y, acc[i][0]);
      acc[i][0] = fmaf(xv.z, wv0.z, acc[i][0]);
      acc[i][0] = fmaf(xv.w, wv0.w, acc[i][0]);
      acc[i][1] = fmaf(xv.x, wv1.x, acc[i][1]);
      acc[i][1] = fmaf(xv.y, wv1.y, acc[i][1]);
      acc[i][1] = fmaf(xv.z, wv1.z, acc[i][1]);
      acc[i][1] = fmaf(xv.w, wv1.w, acc[i][1]);
      acc[i][2] = fmaf(xv.x, wv2.x, acc[i][2]);
      acc[i][2] = fmaf(xv.y, wv2.y, acc[i][2]);
      acc[i][2] = fmaf(xv.z, wv2.z, acc[i][2]);
      acc[i][2] = fmaf(xv.w, wv2.w, acc[i][2]);
      acc[i][3] = fmaf(xv.x, wv3.x, acc[i][3]);
      acc[i][3] = fmaf(xv.y, wv3.y, acc[i][3]);
      acc[i][3] = fmaf(xv.z, wv3.z, acc[i][3]);
      acc[i][3] = fmaf(xv.w, wv3.w, acc[i][3]);
    }
  }
}

// Epilogue: add bias, write y, and per-channel {sum, sumsq} partials.
__device__ __forceinline__ void gemm_store_stats(float acc[8][4], const float* __restrict__ bias,
                                                 float* __restrict__ y,
                                                 float* __restrict__ psum, float* __restrict__ psq,
                                                 int R0, int tr, int tc, int bid) {
  float bb[4];
#pragma unroll
  for (int j = 0; j < 4; ++j) bb[j] = bias[tc * 4 + j];
  float sum[4] = {0, 0, 0, 0}, sq[4] = {0, 0, 0, 0};
#pragma unroll
  for (int i = 0; i < 8; ++i) {
    float v[4];
#pragma unroll
    for (int j = 0; j < 4; ++j) {
      const float t = acc[i][j] + bb[j];
      v[j] = t;
      sum[j] += t;
      sq[j] = fmaf(t, t, sq[j]);
    }
    *(float4*)&y[((size_t)(R0 + tr + 16 * i)) * kC1 + tc * 4] =
        make_float4(v[0], v[1], v[2], v[3]);
  }
#pragma unroll
  for (int off = 1; off < 16; off <<= 1) {
#pragma unroll
    for (int j = 0; j < 4; ++j) {
      sum[j] += __shfl_xor(sum[j], off, 64);
      sq[j]  += __shfl_xor(sq[j], off, 64);
    }
  }
  if (tr == 0) {
    *(float4*)&psum[(size_t)bid * kC1 + tc * 4] = make_float4(sum[0], sum[1], sum[2], sum[3]);
    *(float4*)&psq[(size_t)bid * kC1 + tc * 4]  = make_float4(sq[0], sq[1], sq[2], sq[3]);
  }
}

// ---------------- Layer 1: fused gather + GEMM(K=67->68, N=64) ---------------
__global__ __launch_bounds__(256) void gemm1_kernel(
    const float* __restrict__ xyz, const float* __restrict__ points,
    const float* __restrict__ newxyz, const int* __restrict__ gidx,
    const float* __restrict__ W, const float* __restrict__ bias,
    float* __restrict__ y, float* __restrict__ psum, float* __restrict__ psq) {
  __shared__ float xs[kTileR][kC0P];
  __shared__ float wl[kC1][kC0P];
  __shared__ int   gl[kTileR];
  __shared__ float nx[4][3];
  const int tid = threadIdx.x;
  const int R0  = blockIdx.x * kTileR;
  const int b   = R0 >> 15;          // 32768 rows per batch
  const int G0  = R0 >> 5;           // global group id base (4 groups per tile)
  if (tid < kTileR) gl[tid] = gidx[R0 + tid];
  if (tid >= 128 && tid < 140) {
    const int q = (tid - 128) / 3, c = (tid - 128) % 3;
    nx[q][c] = newxyz[(size_t)(G0 + q) * 3 + c];
  }
  // Stage W reordered: c'=0..2 -> W[:,0..2], c'=3 -> 0, c'>=4 -> W[:,c'-1]
  for (int i = tid; i < kC1 * kC0P; i += 256) {
    const int o = i / kC0P, c = i % kC0P;
    float v;
    if (c < 3)       v = W[o * kC0 + c];
    else if (c == 3) v = 0.0f;
    else             v = W[o * kC0 + (c - 1)];
    wl[o][c] = v;
  }
  __syncthreads();
  // Gather-stage xs: [dx,dy,dz,0, p0..p63]
  for (int i = tid; i < kTileR * 17; i += 256) {
    const int r = i / 17, q = i % 17;
    const int n = gl[r];
    if (q == 0) {
      const float* xp = xyz + ((size_t)(b * kN + n)) * 3;
      const int sq4 = r >> 5;
      xs[r][0] = __fsub_rn(xp[0], nx[sq4][0]);
      xs[r][1] = __fsub_rn(xp[1], nx[sq4][1]);
      xs[r][2] = __fsub_rn(xp[2], nx[sq4][2]);
      xs[r][3] = 0.0f;
    } else {
      const float4 p = *(const float4*)(points + ((size_t)(b * kN + n)) * kInCh + (q - 1) * 4);
      *(float4*)&xs[r][q * 4] = p;
    }
  }
  __syncthreads();
  const int tr = tid & 15, tc = tid >> 4;
  float acc[8][4];
  gemm_compute<kC0P>(xs, wl, tr, tc, acc);
  gemm_store_stats(acc, bias, y, psum, psq, R0, tr, tc, blockIdx.x);
}

// ---------------- Layer 2: GEMM(K=64, N=64), BN1+ReLU fused on input --------
__global__ __launch_bounds__(256) void gemm2_kernel(
    const float* __restrict__ x, const float* __restrict__ W, const float* __restrict__ bias,
    const float* __restrict__ a, const float* __restrict__ sft,
    float* __restrict__ y, float* __restrict__ psum, float* __restrict__ psq) {
  __shared__ float xs[kTileR][kC0P];
  __shared__ float wl[kC1][kC0P];
  const int tid = threadIdx.x;
  const int R0  = blockIdx.x * kTileR;
  for (int i = tid; i < kTileR * 16; i += 256) {
    const int r = i >> 4, cq = i & 15;
    float4 v = *(const float4*)&x[((size_t)(R0 + r)) * kC1 + cq * 4];
    const float4 av = *(const float4*)&a[cq * 4];
    const float4 sv = *(const float4*)&sft[cq * 4];
    v.x = fmaxf(fmaf(av.x, v.x, sv.x), 0.0f);
    v.y = fmaxf(fmaf(av.y, v.y, sv.y), 0.0f);
    v.z = fmaxf(fmaf(av.z, v.z, sv.z), 0.0f);
    v.w = fmaxf(fmaf(av.w, v.w, sv.w), 0.0f);
    *(float4*)&xs[r][cq * 4] = v;
  }
  for (int i = tid; i < kC1 * 16; i += 256) {
    const int o = i >> 4, cq = i & 15;
    *(float4*)&wl[o][cq * 4] = *(const float4*)&W[(size_t)o * kC1 + cq * 4];
  }
  __syncthreads();
  const int tr = tid & 15, tc = tid >> 4;
  float acc[8][4];
  gemm_compute<kC1>(xs, wl, tr, tc, acc);
  gemm_store_stats(acc, bias, y, psum, psq, R0, tr, tc, blockIdx.x);
}

// ---------------- Layer 3 pass A: stats only (no y3 store) -------------------
__global__ __launch_bounds__(256) void gemm3a_kernel(
    const float* __restrict__ x, const float* __restrict__ W, const float* __restrict__ bias,
    const float* __restrict__ a, const float* __restrict__ sft,
    float* __restrict__ psum, float* __restrict__ psq) {
  __shared__ float xs[kTileR][kC0P];
  __shared__ float wl[kC1][kC0P];
  const int tid = threadIdx.x;
  const int R0  = blockIdx.x * kTileR;
  for (int i = tid; i < kTileR * 16; i += 256) {
    const int r = i >> 4, cq = i & 15;
    float4 v = *(const float4*)&x[((size_t)(R0 + r)) * kC1 + cq * 4];
    const float4 av = *(const float4*)&a[cq * 4];
    const float4 sv = *(const float4*)&sft[cq * 4];
    v.x = fmaxf(fmaf(av.x, v.x, sv.x), 0.0f);
    v.y = fmaxf(fmaf(av.y, v.y, sv.y), 0.0f);
    v.z = fmaxf(fmaf(av.z, v.z, sv.z), 0.0f);
    v.w = fmaxf(fmaf(av.w, v.w, sv.w), 0.0f);
    *(float4*)&xs[r][cq * 4] = v;
  }
  const int tr = tid & 15, tc = tid >> 4;
  for (int cp = 0; cp < 2; ++cp) {
    __syncthreads();
    for (int i = tid; i < kC1 * 16; i += 256) {
      const int o = i >> 4, cq = i & 15;
      *(float4*)&wl[o][cq * 4] = *(const float4*)&W[((size_t)(cp * 64 + o)) * kC1 + cq * 4];
    }
    __syncthreads();
    float acc[8][4];
    gemm_compute<kC1>(xs, wl, tr, tc, acc);
    float bb[4];
#pragma unroll
    for (int j = 0; j < 4; ++j) bb[j] = bias[cp * 64 + tc * 4 + j];
    float sum[4] = {0, 0, 0, 0}, sq[4] = {0, 0, 0, 0};
#pragma unroll
    for (int i = 0; i < 8; ++i)
#pragma unroll
      for (int j = 0; j < 4; ++j) {
        const float t = acc[i][j] + bb[j];
        sum[j] += t;
        sq[j] = fmaf(t, t, sq[j]);
      }
#pragma unroll
    for (int off = 1; off < 16; off <<= 1) {
#pragma unroll
      for (int j = 0; j < 4; ++j) {
        sum[j] += __shfl_xor(sum[j], off, 64);
        sq[j]  += __shfl_xor(sq[j], off, 64);
      }
    }
    if (tr == 0) {
      *(float4*)&psum[(size_t)blockIdx.x * kC3 + cp * 64 + tc * 4] =
          make_float4(sum[0], sum[1], sum[2], sum[3]);
      *(float4*)&psq[(size_t)blockIdx.x * kC3 + cp * 64 + tc * 4] =
          make_float4(sq[0], sq[1], sq[2], sq[3]);
    }
  }
}

// ---------------- Layer 3 pass B: recompute + BN3 + ReLU + max over k -------
__global__ __launch_bounds__(256) void gemm3b_kernel(
    const float* __restrict__ x, const float* __restrict__ W, const float* __restrict__ bias,
    const float* __restrict__ a2, const float* __restrict__ s2,
    const float* __restrict__ a3, const float* __restrict__ s3,
    float* __restrict__ outp) {
  __shared__ float xs[kTileR][kC0P];
  __shared__ float wl[kC1][kC0P];
  const int tid = threadIdx.x;
  const int R0  = blockIdx.x * kTileR;
  const int G0  = R0 >> 5;
  for (int i = tid; i < kTileR * 16; i += 256) {
    const int r = i >> 4, cq = i & 15;
    float4 v = *(const float4*)&x[((size_t)(R0 + r)) * kC1 + cq * 4];
    const float4 av = *(const float4*)&a2[cq * 4];
    const float4 sv = *(const float4*)&s2[cq * 4];
    v.x = fmaxf(fmaf(av.x, v.x, sv.x), 0.0f);
    v.y = fmaxf(fmaf(av.y, v.y, sv.y), 0.0f);
    v.z = fmaxf(fmaf(av.z, v.z, sv.z), 0.0f);
    v.w = fmaxf(fmaf(av.w, v.w, sv.w), 0.0f);
    *(float4*)&xs[r][cq * 4] = v;
  }
  const int tr = tid & 15, tc = tid >> 4;
  for (int cp = 0; cp < 2; ++cp) {
    __syncthreads();
    for (int i = tid; i < kC1 * 16; i += 256) {
      const int o = i >> 4, cq = i & 15;
      *(float4*)&wl[o][cq * 4] = *(const float4*)&W[((size_t)(cp * 64 + o)) * kC1 + cq * 4];
    }
    __syncthreads();
    float acc[8][4];
    gemm_compute<kC1>(xs, wl, tr, tc, acc);
    float bb[4], av3[4], sv3[4];
#pragma unroll
    for (int j = 0; j < 4; ++j) {
      const int col = cp * 64 + tc * 4 + j;
      bb[j]  = bias[col];
      av3[j] = a3[col];
      sv3[j] = s3[col];
    }
    float mm[4][4];
#pragma unroll
    for (int i = 0; i < 8; ++i) {
      const int s4 = i >> 1;
#pragma unroll
      for (int j = 0; j < 4; ++j) {
        const float t = acc[i][j] + bb[j];
        const float v = fmaxf(fmaf(av3[j], t, sv3[j]), 0.0f);
        mm[s4][j] = (i & 1) ? fmaxf(mm[s4][j], v) : v;
      }
    }
#pragma unroll
    for (int off = 1; off < 16; off <<= 1)
#pragma unroll
      for (int s4 = 0; s4 < 4; ++s4)
#pragma unroll
        for (int j = 0; j < 4; ++j)
          mm[s4][j] = fmaxf(mm[s4][j], __shfl_xor(mm[s4][j], off, 64));
    if (tr == 0) {
#pragma unroll
      for (int s4 = 0; s4 < 4; ++s4) {
        *(float4*)&outp[(size_t)(G0 + s4) * kC3 + cp * 64 + tc * 4] =
            make_float4(mm[s4][0], mm[s4][1], mm[s4][2], mm[s4][3]);
      }
    }
  }
}

// ---------------- BN stats finalize (parallel) -------------------------------
// One block per channel; 256 threads reduce the 2048 per-block partials.
__global__ __launch_bounds__(256) void finalize_kernel(
    const float* __restrict__ psum, const float* __restrict__ psq,
    const float* __restrict__ g, const float* __restrict__ be,
    float* __restrict__ a, float* __restrict__ s, int nch) {
  __shared__ float red[2][4];
  const int c   = blockIdx.x;
  const int tid = threadIdx.x;
  const int lane = tid & 63, wid = tid >> 6;
  float sum = 0.f, sq = 0.f;
  for (int i = tid; i < kGemmBlocks; i += 256) {
    sum += psum[(size_t)i * nch + c];
    sq  += psq[(size_t)i * nch + c];
  }
#pragma unroll
  for (int off = 1; off < 64; off <<= 1) {
    sum += __shfl_xor(sum, off, 64);
    sq  += __shfl_xor(sq, off, 64);
  }
  if (lane == 0) { red[0][wid] = sum; red[1][wid] = sq; }
  __syncthreads();
  if (tid == 0) {
    const float tsum = red[0][0] + red[0][1] + red[0][2] + red[0][3];
    const float tsq  = red[1][0] + red[1][1] + red[1][2] + red[1][3];
    const float inv = 1.0f / (float)kRows;
    const float mu  = tsum * inv;
    const float var = tsq * inv - mu * mu;
    const float rs  = 1.0f / sqrtf(var + 1e-5f);
    const float av  = g[c] * rs;
    a[c] = av;
    s[c] = be[c] - av * mu;
  }
}

}  // namespace

extern "C" void kernel_launch(void* const* d_in, const int* in_sizes, int n_in,
                              void* d_out, int out_size, void* d_ws, size_t ws_size,
                              hipStream_t stream) {
  const float* xyz    = (const float*)d_in[0];
  const float* points = (const float*)d_in[1];
  const float* W0  = (const float*)d_in[2];
  const float* b0  = (const float*)d_in[3];
  const float* g0  = (const float*)d_in[4];
  const float* be0 = (const float*)d_in[5];
  const float* W1  = (const float*)d_in[6];
  const float* b1  = (const float*)d_in[7];
  const float* g1  = (const float*)d_in[8];
  const float* be1 = (const float*)d_in[9];
  const float* W2  = (const float*)d_in[10];
  const float* b2  = (const float*)d_in[11];
  const float* g2  = (const float*)d_in[12];
  const float* be2 = (const float*)d_in[13];

  float* out      = (float*)d_out;
  float* newxyz   = out;            // 8*1024*3 = 24576 floats
  float* newpts   = out + 24576;    // 8*1024*128

  char* wsb = (char*)d_ws;
  int*   gidx = (int*)wsb;                              // 1 MiB
  float* a1 = (float*)(wsb + (1u << 20));
  float* s1 = a1 + 128;
  float* a2 = s1 + 128;
  float* s2 = a2 + 128;
  float* a3 = s2 + 128;
  float* s3 = a3 + 128;
  float* psum = (float*)(wsb + 2u * (1u << 20));        // 1 MiB
  float* psq  = (float*)(wsb + 3u * (1u << 20));        // 1 MiB
  float* y1 = (float*)(wsb + 4u * (1u << 20));          // 64 MiB
  float* y2 = (float*)(wsb + 68u * (1u << 20));         // 64 MiB

  fps_kernel<<<kNB, 1024, 0, stream>>>(xyz, newxyz);
  ballq_kernel<<<(kNB * kS) / 4, 256, 0, stream>>>(xyz, newxyz, gidx);
  gemm1_kernel<<<kGemmBlocks, 256, 0, stream>>>(xyz, points, newxyz, gidx, W0, b0, y1, psum, psq);
  finalize_kernel<<<64, 256, 0, stream>>>(psum, psq, g0, be0, a1, s1, 64);
  gemm2_kernel<<<kGemmBlocks, 256, 0, stream>>>(y1, W1, b1, a1, s1, y2, psum, psq);
  finalize_kernel<<<64, 256, 0, stream>>>(psum, psq, g1, be1, a2, s2, 64);
  gemm3a_kernel<<<kGemmBlocks, 256, 0, stream>>>(y2, W2, b2, a2, s2, psum, psq);
  finalize_kernel<<<128, 256, 0, stream>>>(psum, psq, g2, be2, a3, s3, 128);
  gemm3b_kernel<<<kGemmBlocks, 256, 0, stream>>>(y2, W2, b2, a2, s2, a3, s3, newpts);
}

// Round 8
// 1238.776 us; speedup vs baseline: 7.1467x; 1.0864x over previous
//
#include <hip/hip_runtime.h>
#include <cstdint>
#include <cstddef>

namespace {

constexpr int kNB   = 8;
constexpr int kN    = 4096;
constexpr int kS    = 1024;   // NPOINT
constexpr int kK    = 32;     // NSAMPLE
constexpr int kInCh = 64;
constexpr int kC0   = 67;     // 3 + 64
constexpr int kC0P  = 68;     // padded (zero col at c'=3)
constexpr int kC1   = 64;
constexpr int kC3   = 128;
constexpr int kRows = kNB * kS * kK;  // 262144
constexpr int kTileR = 128;
constexpr int kGemmBlocks = kRows / kTileR;  // 2048

// ---------------- Farthest point sampling -----------------------------------
// Proven shape (r6: 1.03 us/step): 8 blocks x 1024 threads, 4 pts/lane, one
// barrier/step. r7 cuts per-step instructions further:
//  - contiguous index map i = 4*tid + t  =>  min-tie-index == min-tie-LANE, so
//    the wave reduce is a cheap f32 max butterfly; exact first-occurrence index
//    recovered with one ballot+ctz+shfl.
//  - cross-wave reduce: lane-parallel (each lane loads red[lane&15], 4-level
//    16-lane xor butterfly on the u64 key) instead of 16 reads + 15-node tree.
// Key pack (value<<32)|~idx preserves numpy argmax ("max value, FIRST index")
// exactly; distances >= 0 so float bits are monotone. Distance arithmetic is
// bit-identical to numpy: ((dx*dx+dy*dy)+dz*dz), RN ops, no FMA.
__global__ __launch_bounds__(1024) void fps_kernel(const float* __restrict__ xyz,
                                                   float* __restrict__ newxyz) {
  __shared__ float sx[kN], sy[kN], sz[kN];
  __shared__ unsigned long long red[2][16];
  const int tid = threadIdx.x;
  const int b = blockIdx.x;
  const float* xb = xyz + (size_t)b * kN * 3;
  for (int i = tid; i < kN; i += 1024) {
    sx[i] = xb[i * 3 + 0];
    sy[i] = xb[i * 3 + 1];
    sz[i] = xb[i * 3 + 2];
  }
  __syncthreads();
  float px[4], py[4], pz[4], dist[4];
  const int i0 = tid * 4;
#pragma unroll
  for (int t = 0; t < 4; ++t) {
    px[t] = sx[i0 + t]; py[t] = sy[i0 + t]; pz[t] = sz[i0 + t];
    dist[t] = 1e10f;
  }
  float cx = sx[0], cy = sy[0], cz = sz[0];
  float* ob = newxyz + (size_t)b * kS * 3;
  if (tid == 0) { ob[0] = cx; ob[1] = cy; ob[2] = cz; }
  const int lane = tid & 63;
  const int wid  = tid >> 6;
  for (int j = 1; j < kS; ++j) {
    float nd[4];
#pragma unroll
    for (int t = 0; t < 4; ++t) {
      const float dx = __fsub_rn(px[t], cx);
      const float dy = __fsub_rn(py[t], cy);
      const float dz = __fsub_rn(pz[t], cz);
      const float d0 = __fadd_rn(__fadd_rn(__fmul_rn(dx, dx), __fmul_rn(dy, dy)),
                                 __fmul_rn(dz, dz));
      const float d = fminf(dist[t], d0);
      dist[t] = d;
      nd[t] = d;
    }
    // First-max over t ascending (strict '>' keeps first occurrence).
    float bv = nd[0]; int bt = 0;
    if (nd[1] > bv) { bv = nd[1]; bt = 1; }
    if (nd[2] > bv) { bv = nd[2]; bt = 2; }
    if (nd[3] > bv) { bv = nd[3]; bt = 3; }
    // Wave max: plain f32 butterfly (values are never NaN).
    float mv = bv;
#pragma unroll
    for (int off = 1; off < 64; off <<= 1) {
      const float o = __shfl_xor(mv, off, 64);
      mv = o > mv ? o : mv;
    }
    // First-occurrence within wave: min tie lane == min global index
    // (index ranges 4*tid..4*tid+3 are ordered by lane).
    const unsigned long long msk = __ballot(bv == mv);
    const int owner = (int)__builtin_ctzll(msk);
    const int bidx  = 4 * (wid * 64 + owner) + __shfl(bt, owner, 64);
    const int p = j & 1;
    if (lane == 0) {
      red[p][wid] = ((unsigned long long)__float_as_uint(mv) << 32) |
                    (unsigned int)~(unsigned int)bidx;
    }
    __syncthreads();   // the ONLY barrier per step (parity slots are WAR-safe)
    // Cross-wave: lane-parallel 16-way u64-max butterfly (each 16-lane group
    // holds all 16 partials; xor levels 1,2,4,8 converge every lane).
    unsigned long long w = red[p][lane & 15];
#pragma unroll
    for (int off = 1; off < 16; off <<= 1) {
      const unsigned long long o = __shfl_xor(w, off, 64);
      w = o > w ? o : w;
    }
    const int fi = (int)~(unsigned int)(w & 0xffffffffull);
    cx = sx[fi]; cy = sy[fi]; cz = sz[fi];
    if (tid == 0) { ob[j * 3 + 0] = cx; ob[j * 3 + 1] = cy; ob[j * 3 + 2] = cz; }
  }
}

// ---------------- Ball query -------------------------------------------------
// One wave per query point; first-32 in-radius indices in ascending order,
// padded with the first index. Distance uses the reference's expanded form and
// the compare is done in double (python float radius*radius).
__global__ __launch_bounds__(256) void ballq_kernel(const float* __restrict__ xyz,
                                                    const float* __restrict__ newxyz,
                                                    int* __restrict__ gidx) {
  const int tid  = threadIdx.x;
  const int lane = tid & 63;
  const int gq   = blockIdx.x * 4 + (tid >> 6);
  const int b    = gq >> 10;
  const float* xb = xyz + (size_t)b * kN * 3;
  const float qx = newxyz[gq * 3 + 0];
  const float qy = newxyz[gq * 3 + 1];
  const float qz = newxyz[gq * 3 + 2];
  const float s2 = __fadd_rn(__fadd_rn(__fmul_rn(qx, qx), __fmul_rn(qy, qy)),
                             __fmul_rn(qz, qz));
  const double r2 = 0.2 * 0.2;
  int taken = 0;
  int first = 0;
  bool hasfirst = false;
  int* g = gidx + (size_t)gq * kK;
  for (int base = 0; base < kN; base += 64) {
    const int n = base + lane;
    const float fx = xb[n * 3 + 0], fy = xb[n * 3 + 1], fz = xb[n * 3 + 2];
    const float p2 = __fadd_rn(__fadd_rn(__fmul_rn(fx, fx), __fmul_rn(fy, fy)),
                               __fmul_rn(fz, fz));
    const float dt = __fadd_rn(__fadd_rn(__fmul_rn(qx, fx), __fmul_rn(qy, fy)),
                               __fmul_rn(qz, fz));
    const float d = __fadd_rn(__fadd_rn(__fmul_rn(-2.0f, dt), s2), p2);
    const bool in = !((double)d > r2);
    const unsigned long long m = __ballot(in);
    if (!hasfirst && m != 0ull) { first = base + __builtin_ctzll(m); hasfirst = true; }
    if (in) {
      const int pos = taken + (int)__popcll(m & ((1ull << lane) - 1ull));
      if (pos < kK) g[pos] = n;
    }
    taken += (int)__popcll(m);
    if (taken >= kK) break;
  }
  for (int p = taken + lane; p < kK; p += 64) g[p] = first;
}

// ---------------- GEMM core (shared pattern) ---------------------------------
// Block: 256 threads, tile 128 rows x 64 cols. Thread (tr = tid&15, tc = tid>>4)
// computes rows {tr+16i} x cols {tc*4+j}, acc[8][4].

template <int KDIM>
__device__ __forceinline__ void gemm_compute(const float xs[kTileR][kC0P],
                                             const float wl[kC1][kC0P],
                                             int tr, int tc, float acc[8][4]) {
#pragma unroll
  for (int i = 0; i < 8; ++i)
#pragma unroll
    for (int j = 0; j < 4; ++j) acc[i][j] = 0.0f;
#pragma unroll 4
  for (int c = 0; c < KDIM; c += 4) {
    const float4 wv0 = *(const float4*)&wl[tc * 4 + 0][c];
    const float4 wv1 = *(const float4*)&wl[tc * 4 + 1][c];
    const float4 wv2 = *(const float4*)&wl[tc * 4 + 2][c];
    const float4 wv3 = *(const float4*)&wl[tc * 4 + 3][c];
#pragma unroll
    for (int i = 0; i < 8; ++i) {
      const float4 xv = *(const float4*)&xs[tr + 16 * i][c];
      acc[i][0] = fmaf(xv.x, wv0.x, acc[i][0]);
      acc[i][0] = fmaf(xv.y, wv0.y, acc[i][0]);
      acc[i][0] = fmaf(xv.z, wv0.z, acc[i][0]);
      acc[i][0] = fmaf(xv.w, wv0.w, acc[i][0]);
      acc[i][1] = fmaf(xv.x, wv1.x, acc[i][1]);
      acc[i][1] = fmaf(xv.y, wv1.y, acc[i][1]);
      acc[i][1] = fmaf(xv.z, wv1.z, acc[i][1]);
      acc[i][1] = fmaf(xv.w, wv1.w, acc[i][1]);
      acc[i][2] = fmaf(xv.x, wv2.x, acc[i][2]);
      acc[i][2] = fmaf(xv.y, wv2.y, acc[i][2]);
      acc[i][2] = fmaf(xv.z, wv2.z, acc[i][2]);
      acc[i][2] = fmaf(xv.w, wv2.w, acc[i][2]);
      acc[i][3] = fmaf(xv.x, wv3.x, acc[i][3]);
      acc[i][3] = fmaf(xv.y, wv3.y, acc[i][3]);
      acc[i][3] = fmaf(xv.z, wv3.z, acc[i][3]);
      acc[i][3] = fmaf(xv.w, wv3.w, acc[i][3]);
    }
  }
}

// Epilogue: add bias, write y, and per-channel {sum, sumsq} partials.
__device__ __forceinline__ void gemm_store_stats(float acc[8][4], const float* __restrict__ bias,
                                                 float* __restrict__ y,
                                                 float* __restrict__ psum, float* __restrict__ psq,
                                                 int R0, int tr, int tc, int bid) {
  float bb[4];
#pragma unroll
  for (int j = 0; j < 4; ++j) bb[j] = bias[tc * 4 + j];
  float sum[4] = {0, 0, 0, 0}, sq[4] = {0, 0, 0, 0};
#pragma unroll
  for (int i = 0; i < 8; ++i) {
    float v[4];
#pragma unroll
    for (int j = 0; j < 4; ++j) {
      const float t = acc[i][j] + bb[j];
      v[j] = t;
      sum[j] += t;
      sq[j] = fmaf(t, t, sq[j]);
    }
    *(float4*)&y[((size_t)(R0 + tr + 16 * i)) * kC1 + tc * 4] =
        make_float4(v[0], v[1], v[2], v[3]);
  }
#pragma unroll
  for (int off = 1; off < 16; off <<= 1) {
#pragma unroll
    for (int j = 0; j < 4; ++j) {
      sum[j] += __shfl_xor(sum[j], off, 64);
      sq[j]  += __shfl_xor(sq[j], off, 64);
    }
  }
  if (tr == 0) {
    *(float4*)&psum[(size_t)bid * kC1 + tc * 4] = make_float4(sum[0], sum[1], sum[2], sum[3]);
    *(float4*)&psq[(size_t)bid * kC1 + tc * 4]  = make_float4(sq[0], sq[1], sq[2], sq[3]);
  }
}

// ---------------- Layer 1: fused gather + GEMM(K=67->68, N=64) ---------------
__global__ __launch_bounds__(256) void gemm1_kernel(
    const float* __restrict__ xyz, const float* __restrict__ points,
    const float* __restrict__ newxyz, const int* __restrict__ gidx,
    const float* __restrict__ W, const float* __restrict__ bias,
    float* __restrict__ y, float* __restrict__ psum, float* __restrict__ psq) {
  __shared__ float xs[kTileR][kC0P];
  __shared__ float wl[kC1][kC0P];
  __shared__ int   gl[kTileR];
  __shared__ float nx[4][3];
  const int tid = threadIdx.x;
  const int R0  = blockIdx.x * kTileR;
  const int b   = R0 >> 15;          // 32768 rows per batch
  const int G0  = R0 >> 5;           // global group id base (4 groups per tile)
  if (tid < kTileR) gl[tid] = gidx[R0 + tid];
  if (tid >= 128 && tid < 140) {
    const int q = (tid - 128) / 3, c = (tid - 128) % 3;
    nx[q][c] = newxyz[(size_t)(G0 + q) * 3 + c];
  }
  // Stage W reordered: c'=0..2 -> W[:,0..2], c'=3 -> 0, c'>=4 -> W[:,c'-1]
  for (int i = tid; i < kC1 * kC0P; i += 256) {
    const int o = i / kC0P, c = i % kC0P;
    float v;
    if (c < 3)       v = W[o * kC0 + c];
    else if (c == 3) v = 0.0f;
    else             v = W[o * kC0 + (c - 1)];
    wl[o][c] = v;
  }
  __syncthreads();
  // Gather-stage xs: [dx,dy,dz,0, p0..p63]
  for (int i = tid; i < kTileR * 17; i += 256) {
    const int r = i / 17, q = i % 17;
    const int n = gl[r];
    if (q == 0) {
      const float* xp = xyz + ((size_t)(b * kN + n)) * 3;
      const int sq4 = r >> 5;
      xs[r][0] = __fsub_rn(xp[0], nx[sq4][0]);
      xs[r][1] = __fsub_rn(xp[1], nx[sq4][1]);
      xs[r][2] = __fsub_rn(xp[2], nx[sq4][2]);
      xs[r][3] = 0.0f;
    } else {
      const float4 p = *(const float4*)(points + ((size_t)(b * kN + n)) * kInCh + (q - 1) * 4);
      *(float4*)&xs[r][q * 4] = p;
    }
  }
  __syncthreads();
  const int tr = tid & 15, tc = tid >> 4;
  float acc[8][4];
  gemm_compute<kC0P>(xs, wl, tr, tc, acc);
  gemm_store_stats(acc, bias, y, psum, psq, R0, tr, tc, blockIdx.x);
}

// ---------------- Layer 2: GEMM(K=64, N=64), BN1+ReLU fused on input --------
__global__ __launch_bounds__(256) void gemm2_kernel(
    const float* __restrict__ x, const float* __restrict__ W, const float* __restrict__ bias,
    const float* __restrict__ a, const float* __restrict__ sft,
    float* __restrict__ y, float* __restrict__ psum, float* __restrict__ psq) {
  __shared__ float xs[kTileR][kC0P];
  __shared__ float wl[kC1][kC0P];
  const int tid = threadIdx.x;
  const int R0  = blockIdx.x * kTileR;
  for (int i = tid; i < kTileR * 16; i += 256) {
    const int r = i >> 4, cq = i & 15;
    float4 v = *(const float4*)&x[((size_t)(R0 + r)) * kC1 + cq * 4];
    const float4 av = *(const float4*)&a[cq * 4];
    const float4 sv = *(const float4*)&sft[cq * 4];
    v.x = fmaxf(fmaf(av.x, v.x, sv.x), 0.0f);
    v.y = fmaxf(fmaf(av.y, v.y, sv.y), 0.0f);
    v.z = fmaxf(fmaf(av.z, v.z, sv.z), 0.0f);
    v.w = fmaxf(fmaf(av.w, v.w, sv.w), 0.0f);
    *(float4*)&xs[r][cq * 4] = v;
  }
  for (int i = tid; i < kC1 * 16; i += 256) {
    const int o = i >> 4, cq = i & 15;
    *(float4*)&wl[o][cq * 4] = *(const float4*)&W[(size_t)o * kC1 + cq * 4];
  }
  __syncthreads();
  const int tr = tid & 15, tc = tid >> 4;
  float acc[8][4];
  gemm_compute<kC1>(xs, wl, tr, tc, acc);
  gemm_store_stats(acc, bias, y, psum, psq, R0, tr, tc, blockIdx.x);
}

// ---------------- Layer 3 pass A: stats only (no y3 store) -------------------
__global__ __launch_bounds__(256) void gemm3a_kernel(
    const float* __restrict__ x, const float* __restrict__ W, const float* __restrict__ bias,
    const float* __restrict__ a, const float* __restrict__ sft,
    float* __restrict__ psum, float* __restrict__ psq) {
  __shared__ float xs[kTileR][kC0P];
  __shared__ float wl[kC1][kC0P];
  const int tid = threadIdx.x;
  const int R0  = blockIdx.x * kTileR;
  for (int i = tid; i < kTileR * 16; i += 256) {
    const int r = i >> 4, cq = i & 15;
    float4 v = *(const float4*)&x[((size_t)(R0 + r)) * kC1 + cq * 4];
    const float4 av = *(const float4*)&a[cq * 4];
    const float4 sv = *(const float4*)&sft[cq * 4];
    v.x = fmaxf(fmaf(av.x, v.x, sv.x), 0.0f);
    v.y = fmaxf(fmaf(av.y, v.y, sv.y), 0.0f);
    v.z = fmaxf(fmaf(av.z, v.z, sv.z), 0.0f);
    v.w = fmaxf(fmaf(av.w, v.w, sv.w), 0.0f);
    *(float4*)&xs[r][cq * 4] = v;
  }
  const int tr = tid & 15, tc = tid >> 4;
  for (int cp = 0; cp < 2; ++cp) {
    __syncthreads();
    for (int i = tid; i < kC1 * 16; i += 256) {
      const int o = i >> 4, cq = i & 15;
      *(float4*)&wl[o][cq * 4] = *(const float4*)&W[((size_t)(cp * 64 + o)) * kC1 + cq * 4];
    }
    __syncthreads();
    float acc[8][4];
    gemm_compute<kC1>(xs, wl, tr, tc, acc);
    float bb[4];
#pragma unroll
    for (int j = 0; j < 4; ++j) bb[j] = bias[cp * 64 + tc * 4 + j];
    float sum[4] = {0, 0, 0, 0}, sq[4] = {0, 0, 0, 0};
#pragma unroll
    for (int i = 0; i < 8; ++i)
#pragma unroll
      for (int j = 0; j < 4; ++j) {
        const float t = acc[i][j] + bb[j];
        sum[j] += t;
        sq[j] = fmaf(t, t, sq[j]);
      }
#pragma unroll
    for (int off = 1; off < 16; off <<= 1) {
#pragma unroll
      for (int j = 0; j < 4; ++j) {
        sum[j] += __shfl_xor(sum[j], off, 64);
        sq[j]  += __shfl_xor(sq[j], off, 64);
      }
    }
    if (tr == 0) {
      *(float4*)&psum[(size_t)blockIdx.x * kC3 + cp * 64 + tc * 4] =
          make_float4(sum[0], sum[1], sum[2], sum[3]);
      *(float4*)&psq[(size_t)blockIdx.x * kC3 + cp * 64 + tc * 4] =
          make_float4(sq[0], sq[1], sq[2], sq[3]);
    }
  }
}

// ---------------- Layer 3 pass B: recompute + BN3 + ReLU + max over k -------
__global__ __launch_bounds__(256) void gemm3b_kernel(
    const float* __restrict__ x, const float* __restrict__ W, const float* __restrict__ bias,
    const float* __restrict__ a2, const float* __restrict__ s2,
    const float* __restrict__ a3, const float* __restrict__ s3,
    float* __restrict__ outp) {
  __shared__ float xs[kTileR][kC0P];
  __shared__ float wl[kC1][kC0P];
  const int tid = threadIdx.x;
  const int R0  = blockIdx.x * kTileR;
  const int G0  = R0 >> 5;
  for (int i = tid; i < kTileR * 16; i += 256) {
    const int r = i >> 4, cq = i & 15;
    float4 v = *(const float4*)&x[((size_t)(R0 + r)) * kC1 + cq * 4];
    const float4 av = *(const float4*)&a2[cq * 4];
    const float4 sv = *(const float4*)&s2[cq * 4];
    v.x = fmaxf(fmaf(av.x, v.x, sv.x), 0.0f);
    v.y = fmaxf(fmaf(av.y, v.y, sv.y), 0.0f);
    v.z = fmaxf(fmaf(av.z, v.z, sv.z), 0.0f);
    v.w = fmaxf(fmaf(av.w, v.w, sv.w), 0.0f);
    *(float4*)&xs[r][cq * 4] = v;
  }
  const int tr = tid & 15, tc = tid >> 4;
  for (int cp = 0; cp < 2; ++cp) {
    __syncthreads();
    for (int i = tid; i < kC1 * 16; i += 256) {
      const int o = i >> 4, cq = i & 15;
      *(float4*)&wl[o][cq * 4] = *(const float4*)&W[((size_t)(cp * 64 + o)) * kC1 + cq * 4];
    }
    __syncthreads();
    float acc[8][4];
    gemm_compute<kC1>(xs, wl, tr, tc, acc);
    float bb[4], av3[4], sv3[4];
#pragma unroll
    for (int j = 0; j < 4; ++j) {
      const int col = cp * 64 + tc * 4 + j;
      bb[j]  = bias[col];
      av3[j] = a3[col];
      sv3[j] = s3[col];
    }
    float mm[4][4];
#pragma unroll
    for (int i = 0; i < 8; ++i) {
      const int s4 = i >> 1;
#pragma unroll
      for (int j = 0; j < 4; ++j) {
        const float t = acc[i][j] + bb[j];
        const float v = fmaxf(fmaf(av3[j], t, sv3[j]), 0.0f);
        mm[s4][j] = (i & 1) ? fmaxf(mm[s4][j], v) : v;
      }
    }
#pragma unroll
    for (int off = 1; off < 16; off <<= 1)
#pragma unroll
      for (int s4 = 0; s4 < 4; ++s4)
#pragma unroll
        for (int j = 0; j < 4; ++j)
          mm[s4][j] = fmaxf(mm[s4][j], __shfl_xor(mm[s4][j], off, 64));
    if (tr == 0) {
#pragma unroll
      for (int s4 = 0; s4 < 4; ++s4) {
        *(float4*)&outp[(size_t)(G0 + s4) * kC3 + cp * 64 + tc * 4] =
            make_float4(mm[s4][0], mm[s4][1], mm[s4][2], mm[s4][3]);
      }
    }
  }
}

// ---------------- BN stats finalize (parallel) -------------------------------
// One block per channel; 256 threads reduce the 2048 per-block partials.
__global__ __launch_bounds__(256) void finalize_kernel(
    const float* __restrict__ psum, const float* __restrict__ psq,
    const float* __restrict__ g, const float* __restrict__ be,
    float* __restrict__ a, float* __restrict__ s, int nch) {
  __shared__ float red[2][4];
  const int c   = blockIdx.x;
  const int tid = threadIdx.x;
  const int lane = tid & 63, wid = tid >> 6;
  float sum = 0.f, sq = 0.f;
  for (int i = tid; i < kGemmBlocks; i += 256) {
    sum += psum[(size_t)i * nch + c];
    sq  += psq[(size_t)i * nch + c];
  }
#pragma unroll
  for (int off = 1; off < 64; off <<= 1) {
    sum += __shfl_xor(sum, off, 64);
    sq  += __shfl_xor(sq, off, 64);
  }
  if (lane == 0) { red[0][wid] = sum; red[1][wid] = sq; }
  __syncthreads();
  if (tid == 0) {
    const float tsum = red[0][0] + red[0][1] + red[0][2] + red[0][3];
    const float tsq  = red[1][0] + red[1][1] + red[1][2] + red[1][3];
    const float inv = 1.0f / (float)kRows;
    const float mu  = tsum * inv;
    const float var = tsq * inv - mu * mu;
    const float rs  = 1.0f / sqrtf(var + 1e-5f);
    const float av  = g[c] * rs;
    a[c] = av;
    s[c] = be[c] - av * mu;
  }
}

}  // namespace

extern "C" void kernel_launch(void* const* d_in, const int* in_sizes, int n_in,
                              void* d_out, int out_size, void* d_ws, size_t ws_size,
                              hipStream_t stream) {
  const float* xyz    = (const float*)d_in[0];
  const float* points = (const float*)d_in[1];
  const float* W0  = (const float*)d_in[2];
  const float* b0  = (const float*)d_in[3];
  const float* g0  = (const float*)d_in[4];
  const float* be0 = (const float*)d_in[5];
  const float* W1  = (const float*)d_in[6];
  const float* b1  = (const float*)d_in[7];
  const float* g1  = (const float*)d_in[8];
  const float* be1 = (const float*)d_in[9];
  const float* W2  = (const float*)d_in[10];
  const float* b2  = (const float*)d_in[11];
  const float* g2  = (const float*)d_in[12];
  const float* be2 = (const float*)d_in[13];

  float* out      = (float*)d_out;
  float* newxyz   = out;            // 8*1024*3 = 24576 floats
  float* newpts   = out + 24576;    // 8*1024*128

  char* wsb = (char*)d_ws;
  int*   gidx = (int*)wsb;                              // 1 MiB
  float* a1 = (float*)(wsb + (1u << 20));
  float* s1 = a1 + 128;
  float* a2 = s1 + 128;
  float* s2 = a2 + 128;
  float* a3 = s2 + 128;
  float* s3 = a3 + 128;
  float* psum = (float*)(wsb + 2u * (1u << 20));        // 1 MiB
  float* psq  = (float*)(wsb + 3u * (1u << 20));        // 1 MiB
  float* y1 = (float*)(wsb + 4u * (1u << 20));          // 64 MiB
  float* y2 = (float*)(wsb + 68u * (1u << 20));         // 64 MiB

  fps_kernel<<<kNB, 1024, 0, stream>>>(xyz, newxyz);
  ballq_kernel<<<(kNB * kS) / 4, 256, 0, stream>>>(xyz, newxyz, gidx);
  gemm1_kernel<<<kGemmBlocks, 256, 0, stream>>>(xyz, points, newxyz, gidx, W0, b0, y1, psum, psq);
  finalize_kernel<<<64, 256, 0, stream>>>(psum, psq, g0, be0, a1, s1, 64);
  gemm2_kernel<<<kGemmBlocks, 256, 0, stream>>>(y1, W1, b1, a1, s1, y2, psum, psq);
  finalize_kernel<<<64, 256, 0, stream>>>(psum, psq, g1, be1, a2, s2, 64);
  gemm3a_kernel<<<kGemmBlocks, 256, 0, stream>>>(y2, W2, b2, a2, s2, psum, psq);
  finalize_kernel<<<128, 256, 0, stream>>>(psum, psq, g2, be2, a3, s3, 128);
  gemm3b_kernel<<<kGemmBlocks, 256, 0, stream>>>(y2, W2, b2, a2, s2, a3, s3, newpts);
}

// Round 9
// 1052.340 us; speedup vs baseline: 8.4128x; 1.1772x over previous
//
#include <hip/hip_runtime.h>
#include <cstdint>
#include <cstddef>

namespace {

constexpr int kNB   = 8;
constexpr int kN    = 4096;
constexpr int kS    = 1024;   // NPOINT
constexpr int kK    = 32;     // NSAMPLE
constexpr int kInCh = 64;
constexpr int kC0   = 67;     // 3 + 64
constexpr int kC0P  = 68;     // padded (zero col at c'=3)
constexpr int kC1   = 64;
constexpr int kC3   = 128;
constexpr int kRows = kNB * kS * kK;  // 262144
constexpr int kTileR = 128;
constexpr int kGemmBlocks = kRows / kTileR;  // 2048

// DPP max step: invalid source lanes fall back to `old` = x (identity for max).
template <int CTRL>
__device__ __forceinline__ float dpp_max(float x) {
  const int o = __builtin_amdgcn_update_dpp(
      __float_as_int(x), __float_as_int(x), CTRL, 0xf, 0xf, false);
  const float of = __int_as_float(o);
  return of > x ? of : x;
}

// ---------------- Farthest point sampling -----------------------------------
// r8: move reductions off the DS pipe (r7 evidence: ~320 ds_swizzle/step across
// 16 waves serialize on the LDS pipe; active-CU VALUBusy ~50%).
//  - wave max via DPP row_shr 1/2/4/8 + row_bcast15/31 (VALU) + v_readlane.
//  - first-occurrence index: ballot(bv==mv) + ctz -> owner lane (SGPR), then
//    readlane(bt, owner). Zero DS ops.
//  - cross-wave: one ds_read_b32 of redv[lane&15], 4 DPP row_shr levels +
//    readlane(15); ballot -> first WAVE (contiguous index map i=4*tid+t makes
//    min tie lane/wave == min global index); one broadcast redi[owner] read.
//  - coords as float4 sp[4096]: centroid fetch is one b128 broadcast read.
// DS ops/wave/step: ~20 -> 4. Distance arithmetic bit-identical to numpy:
// ((dx*dx+dy*dy)+dz*dz), RN ops, no FMA; argmax = first occurrence.
__global__ __launch_bounds__(1024) void fps_kernel(const float* __restrict__ xyz,
                                                   float* __restrict__ newxyz) {
  __shared__ float4 sp[kN];          // 64 KiB
  __shared__ float  redv[2][16];
  __shared__ int    redi[2][16];
  const int tid = threadIdx.x;
  const int b = blockIdx.x;
  const float* xb = xyz + (size_t)b * kN * 3;
  for (int i = tid; i < kN; i += 1024) {
    sp[i] = make_float4(xb[i * 3 + 0], xb[i * 3 + 1], xb[i * 3 + 2], 0.0f);
  }
  __syncthreads();
  const int i0 = tid * 4;
  float px[4], py[4], pz[4], dist[4];
#pragma unroll
  for (int t = 0; t < 4; ++t) {
    const float4 p = sp[i0 + t];
    px[t] = p.x; py[t] = p.y; pz[t] = p.z;
    dist[t] = 1e10f;
  }
  float4 c4 = sp[0];
  float cx = c4.x, cy = c4.y, cz = c4.z;
  float* ob = newxyz + (size_t)b * kS * 3;
  if (tid == 0) { ob[0] = cx; ob[1] = cy; ob[2] = cz; }
  const int lane = tid & 63;
  const int wid  = tid >> 6;
  for (int j = 1; j < kS; ++j) {
    float nd[4];
#pragma unroll
    for (int t = 0; t < 4; ++t) {
      const float dx = __fsub_rn(px[t], cx);
      const float dy = __fsub_rn(py[t], cy);
      const float dz = __fsub_rn(pz[t], cz);
      const float d0 = __fadd_rn(__fadd_rn(__fmul_rn(dx, dx), __fmul_rn(dy, dy)),
                                 __fmul_rn(dz, dz));
      const float d = fminf(dist[t], d0);
      dist[t] = d;
      nd[t] = d;
    }
    // Per-lane max of 4 (value only).
    const float m01 = nd[0] > nd[1] ? nd[0] : nd[1];
    const float m23 = nd[2] > nd[3] ? nd[2] : nd[3];
    const float bv  = m01 > m23 ? m01 : m23;
    // Wave max via DPP (pure VALU), broadcast from lane 63.
    float m = bv;
    m = dpp_max<0x111>(m);   // row_shr:1
    m = dpp_max<0x112>(m);   // row_shr:2
    m = dpp_max<0x114>(m);   // row_shr:4
    m = dpp_max<0x118>(m);   // row_shr:8
    m = dpp_max<0x142>(m);   // row_bcast:15
    m = dpp_max<0x143>(m);   // row_bcast:31
    const float mv = __int_as_float(__builtin_amdgcn_readlane(__float_as_int(m), 63));
    // First-occurrence: min tie lane == min global index (i = 4*tid + t).
    const unsigned long long msk = __ballot(bv == mv);
    const int owner = (int)__builtin_ctzll(msk);
    const int bt = (nd[0] == bv) ? 0 : (nd[1] == bv) ? 1 : (nd[2] == bv) ? 2 : 3;
    const int bto = __builtin_amdgcn_readlane(bt, owner);
    const int bidx = (wid * 64 + owner) * 4 + bto;
    const int p = j & 1;
    if (lane == 0) { redv[p][wid] = mv; redi[p][wid] = bidx; }
    __syncthreads();   // the ONLY barrier per step (parity slots are WAR-safe)
    // Cross-wave: each lane holds partial of wave (lane&15); 4 DPP row levels.
    float v2 = redv[p][lane & 15];
    v2 = dpp_max<0x111>(v2);
    v2 = dpp_max<0x112>(v2);
    v2 = dpp_max<0x114>(v2);
    v2 = dpp_max<0x118>(v2);
    const float mv2 = __int_as_float(__builtin_amdgcn_readlane(__float_as_int(v2), 15));
    const unsigned long long msk2 = __ballot(redv[p][lane & 15] == mv2);
    const int ow = (int)__builtin_ctzll(msk2);   // first wave == first index
    const int fi = redi[p][ow];                  // uniform broadcast read
    c4 = sp[fi];                                 // one b128 broadcast read
    cx = c4.x; cy = c4.y; cz = c4.z;
    if (tid == 0) { ob[j * 3 + 0] = cx; ob[j * 3 + 1] = cy; ob[j * 3 + 2] = cz; }
  }
}

// ---------------- Ball query -------------------------------------------------
// One wave per query point; first-32 in-radius indices in ascending order,
// padded with the first index. Distance uses the reference's expanded form and
// the compare is done in double (python float radius*radius).
__global__ __launch_bounds__(256) void ballq_kernel(const float* __restrict__ xyz,
                                                    const float* __restrict__ newxyz,
                                                    int* __restrict__ gidx) {
  const int tid  = threadIdx.x;
  const int lane = tid & 63;
  const int gq   = blockIdx.x * 4 + (tid >> 6);
  const int b    = gq >> 10;
  const float* xb = xyz + (size_t)b * kN * 3;
  const float qx = newxyz[gq * 3 + 0];
  const float qy = newxyz[gq * 3 + 1];
  const float qz = newxyz[gq * 3 + 2];
  const float s2 = __fadd_rn(__fadd_rn(__fmul_rn(qx, qx), __fmul_rn(qy, qy)),
                             __fmul_rn(qz, qz));
  const double r2 = 0.2 * 0.2;
  int taken = 0;
  int first = 0;
  bool hasfirst = false;
  int* g = gidx + (size_t)gq * kK;
  for (int base = 0; base < kN; base += 64) {
    const int n = base + lane;
    const float fx = xb[n * 3 + 0], fy = xb[n * 3 + 1], fz = xb[n * 3 + 2];
    const float p2 = __fadd_rn(__fadd_rn(__fmul_rn(fx, fx), __fmul_rn(fy, fy)),
                               __fmul_rn(fz, fz));
    const float dt = __fadd_rn(__fadd_rn(__fmul_rn(qx, fx), __fmul_rn(qy, fy)),
                               __fmul_rn(qz, fz));
    const float d = __fadd_rn(__fadd_rn(__fmul_rn(-2.0f, dt), s2), p2);
    const bool in = !((double)d > r2);
    const unsigned long long m = __ballot(in);
    if (!hasfirst && m != 0ull) { first = base + __builtin_ctzll(m); hasfirst = true; }
    if (in) {
      const int pos = taken + (int)__popcll(m & ((1ull << lane) - 1ull));
      if (pos < kK) g[pos] = n;
    }
    taken += (int)__popcll(m);
    if (taken >= kK) break;
  }
  for (int p = taken + lane; p < kK; p += 64) g[p] = first;
}

// ---------------- GEMM core (shared pattern) ---------------------------------
// Block: 256 threads, tile 128 rows x 64 cols. Thread (tr = tid&15, tc = tid>>4)
// computes rows {tr+16i} x cols {tc*4+j}, acc[8][4].

template <int KDIM>
__device__ __forceinline__ void gemm_compute(const float xs[kTileR][kC0P],
                                             const float wl[kC1][kC0P],
                                             int tr, int tc, float acc[8][4]) {
#pragma unroll
  for (int i = 0; i < 8; ++i)
#pragma unroll
    for (int j = 0; j < 4; ++j) acc[i][j] = 0.0f;
#pragma unroll 4
  for (int c = 0; c < KDIM; c += 4) {
    const float4 wv0 = *(const float4*)&wl[tc * 4 + 0][c];
    const float4 wv1 = *(const float4*)&wl[tc * 4 + 1][c];
    const float4 wv2 = *(const float4*)&wl[tc * 4 + 2][c];
    const float4 wv3 = *(const float4*)&wl[tc * 4 + 3][c];
#pragma unroll
    for (int i = 0; i < 8; ++i) {
      const float4 xv = *(const float4*)&xs[tr + 16 * i][c];
      acc[i][0] = fmaf(xv.x, wv0.x, acc[i][0]);
      acc[i][0] = fmaf(xv.y, wv0.y, acc[i][0]);
      acc[i][0] = fmaf(xv.z, wv0.z, acc[i][0]);
      acc[i][0] = fmaf(xv.w, wv0.w, acc[i][0]);
      acc[i][1] = fmaf(xv.x, wv1.x, acc[i][1]);
      acc[i][1] = fmaf(xv.y, wv1.y, acc[i][1]);
      acc[i][1] = fmaf(xv.z, wv1.z, acc[i][1]);
      acc[i][1] = fmaf(xv.w, wv1.w, acc[i][1]);
      acc[i][2] = fmaf(xv.x, wv2.x, acc[i][2]);
      acc[i][2] = fmaf(xv.y, wv2.y, acc[i][2]);
      acc[i][2] = fmaf(xv.z, wv2.z, acc[i][2]);
      acc[i][2] = fmaf(xv.w, wv2.w, acc[i][2]);
      acc[i][3] = fmaf(xv.x, wv3.x, acc[i][3]);
      acc[i][3] = fmaf(xv.y, wv3.y, acc[i][3]);
      acc[i][3] = fmaf(xv.z, wv3.z, acc[i][3]);
      acc[i][3] = fmaf(xv.w, wv3.w, acc[i][3]);
    }
  }
}

// Epilogue: add bias, write y, and per-channel {sum, sumsq} partials.
__device__ __forceinline__ void gemm_store_stats(float acc[8][4], const float* __restrict__ bias,
                                                 float* __restrict__ y,
                                                 float* __restrict__ psum, float* __restrict__ psq,
                                                 int R0, int tr, int tc, int bid) {
  float bb[4];
#pragma unroll
  for (int j = 0; j < 4; ++j) bb[j] = bias[tc * 4 + j];
  float sum[4] = {0, 0, 0, 0}, sq[4] = {0, 0, 0, 0};
#pragma unroll
  for (int i = 0; i < 8; ++i) {
    float v[4];
#pragma unroll
    for (int j = 0; j < 4; ++j) {
      const float t = acc[i][j] + bb[j];
      v[j] = t;
      sum[j] += t;
      sq[j] = fmaf(t, t, sq[j]);
    }
    *(float4*)&y[((size_t)(R0 + tr + 16 * i)) * kC1 + tc * 4] =
        make_float4(v[0], v[1], v[2], v[3]);
  }
#pragma unroll
  for (int off = 1; off < 16; off <<= 1) {
#pragma unroll
    for (int j = 0; j < 4; ++j) {
      sum[j] += __shfl_xor(sum[j], off, 64);
      sq[j]  += __shfl_xor(sq[j], off, 64);
    }
  }
  if (tr == 0) {
    *(float4*)&psum[(size_t)bid * kC1 + tc * 4] = make_float4(sum[0], sum[1], sum[2], sum[3]);
    *(float4*)&psq[(size_t)bid * kC1 + tc * 4]  = make_float4(sq[0], sq[1], sq[2], sq[3]);
  }
}

// ---------------- Layer 1: fused gather + GEMM(K=67->68, N=64) ---------------
__global__ __launch_bounds__(256) void gemm1_kernel(
    const float* __restrict__ xyz, const float* __restrict__ points,
    const float* __restrict__ newxyz, const int* __restrict__ gidx,
    const float* __restrict__ W, const float* __restrict__ bias,
    float* __restrict__ y, float* __restrict__ psum, float* __restrict__ psq) {
  __shared__ float xs[kTileR][kC0P];
  __shared__ float wl[kC1][kC0P];
  __shared__ int   gl[kTileR];
  __shared__ float nx[4][3];
  const int tid = threadIdx.x;
  const int R0  = blockIdx.x * kTileR;
  const int b   = R0 >> 15;          // 32768 rows per batch
  const int G0  = R0 >> 5;           // global group id base (4 groups per tile)
  if (tid < kTileR) gl[tid] = gidx[R0 + tid];
  if (tid >= 128 && tid < 140) {
    const int q = (tid - 128) / 3, c = (tid - 128) % 3;
    nx[q][c] = newxyz[(size_t)(G0 + q) * 3 + c];
  }
  // Stage W reordered: c'=0..2 -> W[:,0..2], c'=3 -> 0, c'>=4 -> W[:,c'-1]
  for (int i = tid; i < kC1 * kC0P; i += 256) {
    const int o = i / kC0P, c = i % kC0P;
    float v;
    if (c < 3)       v = W[o * kC0 + c];
    else if (c == 3) v = 0.0f;
    else             v = W[o * kC0 + (c - 1)];
    wl[o][c] = v;
  }
  __syncthreads();
  // Gather-stage xs: [dx,dy,dz,0, p0..p63]
  for (int i = tid; i < kTileR * 17; i += 256) {
    const int r = i / 17, q = i % 17;
    const int n = gl[r];
    if (q == 0) {
      const float* xp = xyz + ((size_t)(b * kN + n)) * 3;
      const int sq4 = r >> 5;
      xs[r][0] = __fsub_rn(xp[0], nx[sq4][0]);
      xs[r][1] = __fsub_rn(xp[1], nx[sq4][1]);
      xs[r][2] = __fsub_rn(xp[2], nx[sq4][2]);
      xs[r][3] = 0.0f;
    } else {
      const float4 p = *(const float4*)(points + ((size_t)(b * kN + n)) * kInCh + (q - 1) * 4);
      *(float4*)&xs[r][q * 4] = p;
    }
  }
  __syncthreads();
  const int tr = tid & 15, tc = tid >> 4;
  float acc[8][4];
  gemm_compute<kC0P>(xs, wl, tr, tc, acc);
  gemm_store_stats(acc, bias, y, psum, psq, R0, tr, tc, blockIdx.x);
}

// ---------------- Layer 2: GEMM(K=64, N=64), BN1+ReLU fused on input --------
__global__ __launch_bounds__(256) void gemm2_kernel(
    const float* __restrict__ x, const float* __restrict__ W, const float* __restrict__ bias,
    const float* __restrict__ a, const float* __restrict__ sft,
    float* __restrict__ y, float* __restrict__ psum, float* __restrict__ psq) {
  __shared__ float xs[kTileR][kC0P];
  __shared__ float wl[kC1][kC0P];
  const int tid = threadIdx.x;
  const int R0  = blockIdx.x * kTileR;
  for (int i = tid; i < kTileR * 16; i += 256) {
    const int r = i >> 4, cq = i & 15;
    float4 v = *(const float4*)&x[((size_t)(R0 + r)) * kC1 + cq * 4];
    const float4 av = *(const float4*)&a[cq * 4];
    const float4 sv = *(const float4*)&sft[cq * 4];
    v.x = fmaxf(fmaf(av.x, v.x, sv.x), 0.0f);
    v.y = fmaxf(fmaf(av.y, v.y, sv.y), 0.0f);
    v.z = fmaxf(fmaf(av.z, v.z, sv.z), 0.0f);
    v.w = fmaxf(fmaf(av.w, v.w, sv.w), 0.0f);
    *(float4*)&xs[r][cq * 4] = v;
  }
  for (int i = tid; i < kC1 * 16; i += 256) {
    const int o = i >> 4, cq = i & 15;
    *(float4*)&wl[o][cq * 4] = *(const float4*)&W[(size_t)o * kC1 + cq * 4];
  }
  __syncthreads();
  const int tr = tid & 15, tc = tid >> 4;
  float acc[8][4];
  gemm_compute<kC1>(xs, wl, tr, tc, acc);
  gemm_store_stats(acc, bias, y, psum, psq, R0, tr, tc, blockIdx.x);
}

// ---------------- Layer 3 pass A: stats only (no y3 store) -------------------
__global__ __launch_bounds__(256) void gemm3a_kernel(
    const float* __restrict__ x, const float* __restrict__ W, const float* __restrict__ bias,
    const float* __restrict__ a, const float* __restrict__ sft,
    float* __restrict__ psum, float* __restrict__ psq) {
  __shared__ float xs[kTileR][kC0P];
  __shared__ float wl[kC1][kC0P];
  const int tid = threadIdx.x;
  const int R0  = blockIdx.x * kTileR;
  for (int i = tid; i < kTileR * 16; i += 256) {
    const int r = i >> 4, cq = i & 15;
    float4 v = *(const float4*)&x[((size_t)(R0 + r)) * kC1 + cq * 4];
    const float4 av = *(const float4*)&a[cq * 4];
    const float4 sv = *(const float4*)&sft[cq * 4];
    v.x = fmaxf(fmaf(av.x, v.x, sv.x), 0.0f);
    v.y = fmaxf(fmaf(av.y, v.y, sv.y), 0.0f);
    v.z = fmaxf(fmaf(av.z, v.z, sv.z), 0.0f);
    v.w = fmaxf(fmaf(av.w, v.w, sv.w), 0.0f);
    *(float4*)&xs[r][cq * 4] = v;
  }
  const int tr = tid & 15, tc = tid >> 4;
  for (int cp = 0; cp < 2; ++cp) {
    __syncthreads();
    for (int i = tid; i < kC1 * 16; i += 256) {
      const int o = i >> 4, cq = i & 15;
      *(float4*)&wl[o][cq * 4] = *(const float4*)&W[((size_t)(cp * 64 + o)) * kC1 + cq * 4];
    }
    __syncthreads();
    float acc[8][4];
    gemm_compute<kC1>(xs, wl, tr, tc, acc);
    float bb[4];
#pragma unroll
    for (int j = 0; j < 4; ++j) bb[j] = bias[cp * 64 + tc * 4 + j];
    float sum[4] = {0, 0, 0, 0}, sq[4] = {0, 0, 0, 0};
#pragma unroll
    for (int i = 0; i < 8; ++i)
#pragma unroll
      for (int j = 0; j < 4; ++j) {
        const float t = acc[i][j] + bb[j];
        sum[j] += t;
        sq[j] = fmaf(t, t, sq[j]);
      }
#pragma unroll
    for (int off = 1; off < 16; off <<= 1) {
#pragma unroll
      for (int j = 0; j < 4; ++j) {
        sum[j] += __shfl_xor(sum[j], off, 64);
        sq[j]  += __shfl_xor(sq[j], off, 64);
      }
    }
    if (tr == 0) {
      *(float4*)&psum[(size_t)blockIdx.x * kC3 + cp * 64 + tc * 4] =
          make_float4(sum[0], sum[1], sum[2], sum[3]);
      *(float4*)&psq[(size_t)blockIdx.x * kC3 + cp * 64 + tc * 4] =
          make_float4(sq[0], sq[1], sq[2], sq[3]);
    }
  }
}

// ---------------- Layer 3 pass B: recompute + BN3 + ReLU + max over k -------
__global__ __launch_bounds__(256) void gemm3b_kernel(
    const float* __restrict__ x, const float* __restrict__ W, const float* __restrict__ bias,
    const float* __restrict__ a2, const float* __restrict__ s2,
    const float* __restrict__ a3, const float* __restrict__ s3,
    float* __restrict__ outp) {
  __shared__ float xs[kTileR][kC0P];
  __shared__ float wl[kC1][kC0P];
  const int tid = threadIdx.x;
  const int R0  = blockIdx.x * kTileR;
  const int G0  = R0 >> 5;
  for (int i = tid; i < kTileR * 16; i += 256) {
    const int r = i >> 4, cq = i & 15;
    float4 v = *(const float4*)&x[((size_t)(R0 + r)) * kC1 + cq * 4];
    const float4 av = *(const float4*)&a2[cq * 4];
    const float4 sv = *(const float4*)&s2[cq * 4];
    v.x = fmaxf(fmaf(av.x, v.x, sv.x), 0.0f);
    v.y = fmaxf(fmaf(av.y, v.y, sv.y), 0.0f);
    v.z = fmaxf(fmaf(av.z, v.z, sv.z), 0.0f);
    v.w = fmaxf(fmaf(av.w, v.w, sv.w), 0.0f);
    *(float4*)&xs[r][cq * 4] = v;
  }
  const int tr = tid & 15, tc = tid >> 4;
  for (int cp = 0; cp < 2; ++cp) {
    __syncthreads();
    for (int i = tid; i < kC1 * 16; i += 256) {
      const int o = i >> 4, cq = i & 15;
      *(float4*)&wl[o][cq * 4] = *(const float4*)&W[((size_t)(cp * 64 + o)) * kC1 + cq * 4];
    }
    __syncthreads();
    float acc[8][4];
    gemm_compute<kC1>(xs, wl, tr, tc, acc);
    float bb[4], av3[4], sv3[4];
#pragma unroll
    for (int j = 0; j < 4; ++j) {
      const int col = cp * 64 + tc * 4 + j;
      bb[j]  = bias[col];
      av3[j] = a3[col];
      sv3[j] = s3[col];
    }
    float mm[4][4];
#pragma unroll
    for (int i = 0; i < 8; ++i) {
      const int s4 = i >> 1;
#pragma unroll
      for (int j = 0; j < 4; ++j) {
        const float t = acc[i][j] + bb[j];
        const float v = fmaxf(fmaf(av3[j], t, sv3[j]), 0.0f);
        mm[s4][j] = (i & 1) ? fmaxf(mm[s4][j], v) : v;
      }
    }
#pragma unroll
    for (int off = 1; off < 16; off <<= 1)
#pragma unroll
      for (int s4 = 0; s4 < 4; ++s4)
#pragma unroll
        for (int j = 0; j < 4; ++j)
          mm[s4][j] = fmaxf(mm[s4][j], __shfl_xor(mm[s4][j], off, 64));
    if (tr == 0) {
#pragma unroll
      for (int s4 = 0; s4 < 4; ++s4) {
        *(float4*)&outp[(size_t)(G0 + s4) * kC3 + cp * 64 + tc * 4] =
            make_float4(mm[s4][0], mm[s4][1], mm[s4][2], mm[s4][3]);
      }
    }
  }
}

// ---------------- BN stats finalize (parallel) -------------------------------
// One block per channel; 256 threads reduce the 2048 per-block partials.
__global__ __launch_bounds__(256) void finalize_kernel(
    const float* __restrict__ psum, const float* __restrict__ psq,
    const float* __restrict__ g, const float* __restrict__ be,
    float* __restrict__ a, float* __restrict__ s, int nch) {
  __shared__ float red[2][4];
  const int c   = blockIdx.x;
  const int tid = threadIdx.x;
  const int lane = tid & 63, wid = tid >> 6;
  float sum = 0.f, sq = 0.f;
  for (int i = tid; i < kGemmBlocks; i += 256) {
    sum += psum[(size_t)i * nch + c];
    sq  += psq[(size_t)i * nch + c];
  }
#pragma unroll
  for (int off = 1; off < 64; off <<= 1) {
    sum += __shfl_xor(sum, off, 64);
    sq  += __shfl_xor(sq, off, 64);
  }
  if (lane == 0) { red[0][wid] = sum; red[1][wid] = sq; }
  __syncthreads();
  if (tid == 0) {
    const float tsum = red[0][0] + red[0][1] + red[0][2] + red[0][3];
    const float tsq  = red[1][0] + red[1][1] + red[1][2] + red[1][3];
    const float inv = 1.0f / (float)kRows;
    const float mu  = tsum * inv;
    const float var = tsq * inv - mu * mu;
    const float rs  = 1.0f / sqrtf(var + 1e-5f);
    const float av  = g[c] * rs;
    a[c] = av;
    s[c] = be[c] - av * mu;
  }
}

}  // namespace

extern "C" void kernel_launch(void* const* d_in, const int* in_sizes, int n_in,
                              void* d_out, int out_size, void* d_ws, size_t ws_size,
                              hipStream_t stream) {
  const float* xyz    = (const float*)d_in[0];
  const float* points = (const float*)d_in[1];
  const float* W0  = (const float*)d_in[2];
  const float* b0  = (const float*)d_in[3];
  const float* g0  = (const float*)d_in[4];
  const float* be0 = (const float*)d_in[5];
  const float* W1  = (const float*)d_in[6];
  const float* b1  = (const float*)d_in[7];
  const float* g1  = (const float*)d_in[8];
  const float* be1 = (const float*)d_in[9];
  const float* W2  = (const float*)d_in[10];
  const float* b2  = (const float*)d_in[11];
  const float* g2  = (const float*)d_in[12];
  const float* be2 = (const float*)d_in[13];

  float* out      = (float*)d_out;
  float* newxyz   = out;            // 8*1024*3 = 24576 floats
  float* newpts   = out + 24576;    // 8*1024*128

  char* wsb = (char*)d_ws;
  int*   gidx = (int*)wsb;                              // 1 MiB
  float* a1 = (float*)(wsb + (1u << 20));
  float* s1 = a1 + 128;
  float* a2 = s1 + 128;
  float* s2 = a2 + 128;
  float* a3 = s2 + 128;
  float* s3 = a3 + 128;
  float* psum = (float*)(wsb + 2u * (1u << 20));        // 1 MiB
  float* psq  = (float*)(wsb + 3u * (1u << 20));        // 1 MiB
  float* y1 = (float*)(wsb + 4u * (1u << 20));          // 64 MiB
  float* y2 = (float*)(wsb + 68u * (1u << 20));         // 64 MiB

  fps_kernel<<<kNB, 1024, 0, stream>>>(xyz, newxyz);
  ballq_kernel<<<(kNB * kS) / 4, 256, 0, stream>>>(xyz, newxyz, gidx);
  gemm1_kernel<<<kGemmBlocks, 256, 0, stream>>>(xyz, points, newxyz, gidx, W0, b0, y1, psum, psq);
  finalize_kernel<<<64, 256, 0, stream>>>(psum, psq, g0, be0, a1, s1, 64);
  gemm2_kernel<<<kGemmBlocks, 256, 0, stream>>>(y1, W1, b1, a1, s1, y2, psum, psq);
  finalize_kernel<<<64, 256, 0, stream>>>(psum, psq, g1, be1, a2, s2, 64);
  gemm3a_kernel<<<kGemmBlocks, 256, 0, stream>>>(y2, W2, b2, a2, s2, psum, psq);
  finalize_kernel<<<128, 256, 0, stream>>>(psum, psq, g2, be2, a3, s3, 128);
  gemm3b_kernel<<<kGemmBlocks, 256, 0, stream>>>(y2, W2, b2, a2, s2, a3, s3, newpts);
}

// Round 10
// 1031.286 us; speedup vs baseline: 8.5846x; 1.0204x over previous
//
#include <hip/hip_runtime.h>
#include <cstdint>
#include <cstddef>

namespace {

constexpr int kNB   = 8;
constexpr int kN    = 4096;
constexpr int kS    = 1024;   // NPOINT
constexpr int kK    = 32;     // NSAMPLE
constexpr int kInCh = 64;
constexpr int kC0   = 67;     // 3 + 64
constexpr int kC0P  = 68;     // padded (zero col at c'=3)
constexpr int kC1   = 64;
constexpr int kC3   = 128;
constexpr int kRows = kNB * kS * kK;  // 262144
constexpr int kTileR = 128;
constexpr int kGemmBlocks = kRows / kTileR;  // 2048

typedef float v2f __attribute__((ext_vector_type(2)));

// DPP max step: invalid source lanes fall back to `old` = x (identity for max).
template <int CTRL>
__device__ __forceinline__ float dpp_max(float x) {
  const int o = __builtin_amdgcn_update_dpp(
      __float_as_int(x), __float_as_int(x), CTRL, 0xf, 0xf, false);
  const float of = __int_as_float(o);
  return of > x ? of : x;
}

// ---------------- Farthest point sampling -----------------------------------
// r9: shorten the serial per-step chain (r8 profile: ~half the 0.75us step is
// latency: barrier -> ds_read redv -> DPP -> ballot -> ds_read redi -> sp[fi]).
//  - red[p][wid] is ONE u64 {value_bits:32, idx:32}: one ds_write_b64 /
//    ds_read_b64; cross-wave DPP-max runs on the HIGH word, first tie lane
//    (<16) == first wave == smallest global index (contiguous map i=4*tid+t),
//    and the index arrives via readlane(lo, owner) -- SALU, no 2nd LDS read.
//  - packed v2f update (VOP3P v_pk_add/mul_f32): plain ops under
//    fp contract(off) are RN no-FMA, bit-identical per element; subtract is
//    p + (-c) with -c computed once per step (exact).
// Argmax = first occurrence, preserved at every level (t-order, lane-order,
// wave-order all ascending in global index).
__global__ __launch_bounds__(1024) void fps_kernel(const float* __restrict__ xyz,
                                                   float* __restrict__ newxyz) {
  __shared__ float4 sp[kN];                     // 64 KiB
  __shared__ unsigned long long red[2][16];
  const int tid = threadIdx.x;
  const int b = blockIdx.x;
  const float* xb = xyz + (size_t)b * kN * 3;
  for (int i = tid; i < kN; i += 1024) {
    sp[i] = make_float4(xb[i * 3 + 0], xb[i * 3 + 1], xb[i * 3 + 2], 0.0f);
  }
  __syncthreads();
  const int i0 = tid * 4;
  v2f pxv[2], pyv[2], pzv[2], dv[2];
#pragma unroll
  for (int h = 0; h < 2; ++h) {
    const float4 p0 = sp[i0 + 2 * h + 0];
    const float4 p1 = sp[i0 + 2 * h + 1];
    pxv[h] = (v2f){p0.x, p1.x};
    pyv[h] = (v2f){p0.y, p1.y};
    pzv[h] = (v2f){p0.z, p1.z};
    dv[h]  = (v2f){1e10f, 1e10f};
  }
  float4 c4 = sp[0];
  float cx = c4.x, cy = c4.y, cz = c4.z;
  float* ob = newxyz + (size_t)b * kS * 3;
  if (tid == 0) { ob[0] = cx; ob[1] = cy; ob[2] = cz; }
  const int lane = tid & 63;
  const int wid  = tid >> 6;
  for (int j = 1; j < kS; ++j) {
    // Packed distance update (RN, no FMA; per-element order identical to numpy).
    const float ncx = -cx, ncy = -cy, ncz = -cz;
    const v2f cxv = (v2f){ncx, ncx}, cyv = (v2f){ncy, ncy}, czv = (v2f){ncz, ncz};
#pragma unroll
    for (int h = 0; h < 2; ++h) {
#pragma clang fp contract(off)
      const v2f dx = pxv[h] + cxv;
      const v2f dy = pyv[h] + cyv;
      const v2f dz = pzv[h] + czv;
      const v2f d0 = ((dx * dx + dy * dy) + dz * dz);
      dv[h] = __builtin_elementwise_min(dv[h], d0);
    }
    const float nd0 = dv[0].x, nd1 = dv[0].y, nd2 = dv[1].x, nd3 = dv[1].y;
    // First-max over t ascending (strict '>' keeps first occurrence).
    float bv = nd0; int bt = 0;
    if (nd1 > bv) { bv = nd1; bt = 1; }
    if (nd2 > bv) { bv = nd2; bt = 2; }
    if (nd3 > bv) { bv = nd3; bt = 3; }
    // Wave max via DPP (pure VALU), broadcast from lane 63.
    float m = bv;
    m = dpp_max<0x111>(m);   // row_shr:1
    m = dpp_max<0x112>(m);   // row_shr:2
    m = dpp_max<0x114>(m);   // row_shr:4
    m = dpp_max<0x118>(m);   // row_shr:8
    m = dpp_max<0x142>(m);   // row_bcast:15
    m = dpp_max<0x143>(m);   // row_bcast:31
    const float mv = __int_as_float(__builtin_amdgcn_readlane(__float_as_int(m), 63));
    // First-occurrence: min tie lane == min global index (i = 4*tid + t).
    const unsigned long long msk = __ballot(bv == mv);
    const int owner = (int)__builtin_ctzll(msk);
    const int bto = __builtin_amdgcn_readlane(bt, owner);
    const int bidx = (wid * 64 + owner) * 4 + bto;
    const int p = j & 1;
    if (lane == 0) {
      red[p][wid] = ((unsigned long long)(unsigned int)__float_as_int(mv) << 32) |
                    (unsigned int)bidx;
    }
    __syncthreads();   // the ONLY barrier per step (parity slots are WAR-safe)
    // Cross-wave: one ds_read_b64; DPP-max on the value (hi) word; index via
    // readlane from the first tying lane (SALU -- no second LDS round-trip).
    const unsigned long long k64 = red[p][lane & 15];
    const float v2 = __int_as_float((int)(k64 >> 32));
    const int   li = (int)(unsigned int)(k64 & 0xffffffffull);
    float m2 = v2;
    m2 = dpp_max<0x111>(m2);
    m2 = dpp_max<0x112>(m2);
    m2 = dpp_max<0x114>(m2);
    m2 = dpp_max<0x118>(m2);
    const float mv2 = __int_as_float(__builtin_amdgcn_readlane(__float_as_int(m2), 15));
    const unsigned long long msk2 = __ballot(v2 == mv2);
    const int ow = (int)__builtin_ctzll(msk2);   // first lane (<16) == first wave
    const int fi = __builtin_amdgcn_readlane(li, ow);
    c4 = sp[fi];                                 // one b128 broadcast read
    cx = c4.x; cy = c4.y; cz = c4.z;
    if (tid == 0) { ob[j * 3 + 0] = cx; ob[j * 3 + 1] = cy; ob[j * 3 + 2] = cz; }
  }
}

// ---------------- Ball query -------------------------------------------------
// One wave per query point; first-32 in-radius indices in ascending order,
// padded with the first index. Distance uses the reference's expanded form and
// the compare is done in double (python float radius*radius).
__global__ __launch_bounds__(256) void ballq_kernel(const float* __restrict__ xyz,
                                                    const float* __restrict__ newxyz,
                                                    int* __restrict__ gidx) {
  const int tid  = threadIdx.x;
  const int lane = tid & 63;
  const int gq   = blockIdx.x * 4 + (tid >> 6);
  const int b    = gq >> 10;
  const float* xb = xyz + (size_t)b * kN * 3;
  const float qx = newxyz[gq * 3 + 0];
  const float qy = newxyz[gq * 3 + 1];
  const float qz = newxyz[gq * 3 + 2];
  const float s2 = __fadd_rn(__fadd_rn(__fmul_rn(qx, qx), __fmul_rn(qy, qy)),
                             __fmul_rn(qz, qz));
  const double r2 = 0.2 * 0.2;
  int taken = 0;
  int first = 0;
  bool hasfirst = false;
  int* g = gidx + (size_t)gq * kK;
  for (int base = 0; base < kN; base += 64) {
    const int n = base + lane;
    const float fx = xb[n * 3 + 0], fy = xb[n * 3 + 1], fz = xb[n * 3 + 2];
    const float p2 = __fadd_rn(__fadd_rn(__fmul_rn(fx, fx), __fmul_rn(fy, fy)),
                               __fmul_rn(fz, fz));
    const float dt = __fadd_rn(__fadd_rn(__fmul_rn(qx, fx), __fmul_rn(qy, fy)),
                               __fmul_rn(qz, fz));
    const float d = __fadd_rn(__fadd_rn(__fmul_rn(-2.0f, dt), s2), p2);
    const bool in = !((double)d > r2);
    const unsigned long long m = __ballot(in);
    if (!hasfirst && m != 0ull) { first = base + __builtin_ctzll(m); hasfirst = true; }
    if (in) {
      const int pos = taken + (int)__popcll(m & ((1ull << lane) - 1ull));
      if (pos < kK) g[pos] = n;
    }
    taken += (int)__popcll(m);
    if (taken >= kK) break;
  }
  for (int p = taken + lane; p < kK; p += 64) g[p] = first;
}

// ---------------- GEMM core (shared pattern) ---------------------------------
// Block: 256 threads, tile 128 rows x 64 cols. Thread (tr = tid&15, tc = tid>>4)
// computes rows {tr+16i} x cols {tc*4+j}, acc[8][4].

template <int KDIM>
__device__ __forceinline__ void gemm_compute(const float xs[kTileR][kC0P],
                                             const float wl[kC1][kC0P],
                                             int tr, int tc, float acc[8][4]) {
#pragma unroll
  for (int i = 0; i < 8; ++i)
#pragma unroll
    for (int j = 0; j < 4; ++j) acc[i][j] = 0.0f;
#pragma unroll 4
  for (int c = 0; c < KDIM; c += 4) {
    const float4 wv0 = *(const float4*)&wl[tc * 4 + 0][c];
    const float4 wv1 = *(const float4*)&wl[tc * 4 + 1][c];
    const float4 wv2 = *(const float4*)&wl[tc * 4 + 2][c];
    const float4 wv3 = *(const float4*)&wl[tc * 4 + 3][c];
#pragma unroll
    for (int i = 0; i < 8; ++i) {
      const float4 xv = *(const float4*)&xs[tr + 16 * i][c];
      acc[i][0] = fmaf(xv.x, wv0.x, acc[i][0]);
      acc[i][0] = fmaf(xv.y, wv0.y, acc[i][0]);
      acc[i][0] = fmaf(xv.z, wv0.z, acc[i][0]);
      acc[i][0] = fmaf(xv.w, wv0.w, acc[i][0]);
      acc[i][1] = fmaf(xv.x, wv1.x, acc[i][1]);
      acc[i][1] = fmaf(xv.y, wv1.y, acc[i][1]);
      acc[i][1] = fmaf(xv.z, wv1.z, acc[i][1]);
      acc[i][1] = fmaf(xv.w, wv1.w, acc[i][1]);
      acc[i][2] = fmaf(xv.x, wv2.x, acc[i][2]);
      acc[i][2] = fmaf(xv.y, wv2.y, acc[i][2]);
      acc[i][2] = fmaf(xv.z, wv2.z, acc[i][2]);
      acc[i][2] = fmaf(xv.w, wv2.w, acc[i][2]);
      acc[i][3] = fmaf(xv.x, wv3.x, acc[i][3]);
      acc[i][3] = fmaf(xv.y, wv3.y, acc[i][3]);
      acc[i][3] = fmaf(xv.z, wv3.z, acc[i][3]);
      acc[i][3] = fmaf(xv.w, wv3.w, acc[i][3]);
    }
  }
}

// Epilogue: add bias, write y, and per-channel {sum, sumsq} partials.
__device__ __forceinline__ void gemm_store_stats(float acc[8][4], const float* __restrict__ bias,
                                                 float* __restrict__ y,
                                                 float* __restrict__ psum, float* __restrict__ psq,
                                                 int R0, int tr, int tc, int bid) {
  float bb[4];
#pragma unroll
  for (int j = 0; j < 4; ++j) bb[j] = bias[tc * 4 + j];
  float sum[4] = {0, 0, 0, 0}, sq[4] = {0, 0, 0, 0};
#pragma unroll
  for (int i = 0; i < 8; ++i) {
    float v[4];
#pragma unroll
    for (int j = 0; j < 4; ++j) {
      const float t = acc[i][j] + bb[j];
      v[j] = t;
      sum[j] += t;
      sq[j] = fmaf(t, t, sq[j]);
    }
    *(float4*)&y[((size_t)(R0 + tr + 16 * i)) * kC1 + tc * 4] =
        make_float4(v[0], v[1], v[2], v[3]);
  }
#pragma unroll
  for (int off = 1; off < 16; off <<= 1) {
#pragma unroll
    for (int j = 0; j < 4; ++j) {
      sum[j] += __shfl_xor(sum[j], off, 64);
      sq[j]  += __shfl_xor(sq[j], off, 64);
    }
  }
  if (tr == 0) {
    *(float4*)&psum[(size_t)bid * kC1 + tc * 4] = make_float4(sum[0], sum[1], sum[2], sum[3]);
    *(float4*)&psq[(size_t)bid * kC1 + tc * 4]  = make_float4(sq[0], sq[1], sq[2], sq[3]);
  }
}

// ---------------- Layer 1: fused gather + GEMM(K=67->68, N=64) ---------------
__global__ __launch_bounds__(256) void gemm1_kernel(
    const float* __restrict__ xyz, const float* __restrict__ points,
    const float* __restrict__ newxyz, const int* __restrict__ gidx,
    const float* __restrict__ W, const float* __restrict__ bias,
    float* __restrict__ y, float* __restrict__ psum, float* __restrict__ psq) {
  __shared__ float xs[kTileR][kC0P];
  __shared__ float wl[kC1][kC0P];
  __shared__ int   gl[kTileR];
  __shared__ float nx[4][3];
  const int tid = threadIdx.x;
  const int R0  = blockIdx.x * kTileR;
  const int b   = R0 >> 15;          // 32768 rows per batch
  const int G0  = R0 >> 5;           // global group id base (4 groups per tile)
  if (tid < kTileR) gl[tid] = gidx[R0 + tid];
  if (tid >= 128 && tid < 140) {
    const int q = (tid - 128) / 3, c = (tid - 128) % 3;
    nx[q][c] = newxyz[(size_t)(G0 + q) * 3 + c];
  }
  // Stage W reordered: c'=0..2 -> W[:,0..2], c'=3 -> 0, c'>=4 -> W[:,c'-1]
  for (int i = tid; i < kC1 * kC0P; i += 256) {
    const int o = i / kC0P, c = i % kC0P;
    float v;
    if (c < 3)       v = W[o * kC0 + c];
    else if (c == 3) v = 0.0f;
    else             v = W[o * kC0 + (c - 1)];
    wl[o][c] = v;
  }
  __syncthreads();
  // Gather-stage xs: [dx,dy,dz,0, p0..p63]
  for (int i = tid; i < kTileR * 17; i += 256) {
    const int r = i / 17, q = i % 17;
    const int n = gl[r];
    if (q == 0) {
      const float* xp = xyz + ((size_t)(b * kN + n)) * 3;
      const int sq4 = r >> 5;
      xs[r][0] = __fsub_rn(xp[0], nx[sq4][0]);
      xs[r][1] = __fsub_rn(xp[1], nx[sq4][1]);
      xs[r][2] = __fsub_rn(xp[2], nx[sq4][2]);
      xs[r][3] = 0.0f;
    } else {
      const float4 p = *(const float4*)(points + ((size_t)(b * kN + n)) * kInCh + (q - 1) * 4);
      *(float4*)&xs[r][q * 4] = p;
    }
  }
  __syncthreads();
  const int tr = tid & 15, tc = tid >> 4;
  float acc[8][4];
  gemm_compute<kC0P>(xs, wl, tr, tc, acc);
  gemm_store_stats(acc, bias, y, psum, psq, R0, tr, tc, blockIdx.x);
}

// ---------------- Layer 2: GEMM(K=64, N=64), BN1+ReLU fused on input --------
__global__ __launch_bounds__(256) void gemm2_kernel(
    const float* __restrict__ x, const float* __restrict__ W, const float* __restrict__ bias,
    const float* __restrict__ a, const float* __restrict__ sft,
    float* __restrict__ y, float* __restrict__ psum, float* __restrict__ psq) {
  __shared__ float xs[kTileR][kC0P];
  __shared__ float wl[kC1][kC0P];
  const int tid = threadIdx.x;
  const int R0  = blockIdx.x * kTileR;
  for (int i = tid; i < kTileR * 16; i += 256) {
    const int r = i >> 4, cq = i & 15;
    float4 v = *(const float4*)&x[((size_t)(R0 + r)) * kC1 + cq * 4];
    const float4 av = *(const float4*)&a[cq * 4];
    const float4 sv = *(const float4*)&sft[cq * 4];
    v.x = fmaxf(fmaf(av.x, v.x, sv.x), 0.0f);
    v.y = fmaxf(fmaf(av.y, v.y, sv.y), 0.0f);
    v.z = fmaxf(fmaf(av.z, v.z, sv.z), 0.0f);
    v.w = fmaxf(fmaf(av.w, v.w, sv.w), 0.0f);
    *(float4*)&xs[r][cq * 4] = v;
  }
  for (int i = tid; i < kC1 * 16; i += 256) {
    const int o = i >> 4, cq = i & 15;
    *(float4*)&wl[o][cq * 4] = *(const float4*)&W[(size_t)o * kC1 + cq * 4];
  }
  __syncthreads();
  const int tr = tid & 15, tc = tid >> 4;
  float acc[8][4];
  gemm_compute<kC1>(xs, wl, tr, tc, acc);
  gemm_store_stats(acc, bias, y, psum, psq, R0, tr, tc, blockIdx.x);
}

// ---------------- Layer 3 pass A: stats only (no y3 store) -------------------
__global__ __launch_bounds__(256) void gemm3a_kernel(
    const float* __restrict__ x, const float* __restrict__ W, const float* __restrict__ bias,
    const float* __restrict__ a, const float* __restrict__ sft,
    float* __restrict__ psum, float* __restrict__ psq) {
  __shared__ float xs[kTileR][kC0P];
  __shared__ float wl[kC1][kC0P];
  const int tid = threadIdx.x;
  const int R0  = blockIdx.x * kTileR;
  for (int i = tid; i < kTileR * 16; i += 256) {
    const int r = i >> 4, cq = i & 15;
    float4 v = *(const float4*)&x[((size_t)(R0 + r)) * kC1 + cq * 4];
    const float4 av = *(const float4*)&a[cq * 4];
    const float4 sv = *(const float4*)&sft[cq * 4];
    v.x = fmaxf(fmaf(av.x, v.x, sv.x), 0.0f);
    v.y = fmaxf(fmaf(av.y, v.y, sv.y), 0.0f);
    v.z = fmaxf(fmaf(av.z, v.z, sv.z), 0.0f);
    v.w = fmaxf(fmaf(av.w, v.w, sv.w), 0.0f);
    *(float4*)&xs[r][cq * 4] = v;
  }
  const int tr = tid & 15, tc = tid >> 4;
  for (int cp = 0; cp < 2; ++cp) {
    __syncthreads();
    for (int i = tid; i < kC1 * 16; i += 256) {
      const int o = i >> 4, cq = i & 15;
      *(float4*)&wl[o][cq * 4] = *(const float4*)&W[((size_t)(cp * 64 + o)) * kC1 + cq * 4];
    }
    __syncthreads();
    float acc[8][4];
    gemm_compute<kC1>(xs, wl, tr, tc, acc);
    float bb[4];
#pragma unroll
    for (int j = 0; j < 4; ++j) bb[j] = bias[cp * 64 + tc * 4 + j];
    float sum[4] = {0, 0, 0, 0}, sq[4] = {0, 0, 0, 0};
#pragma unroll
    for (int i = 0; i < 8; ++i)
#pragma unroll
      for (int j = 0; j < 4; ++j) {
        const float t = acc[i][j] + bb[j];
        sum[j] += t;
        sq[j] = fmaf(t, t, sq[j]);
      }
#pragma unroll
    for (int off = 1; off < 16; off <<= 1) {
#pragma unroll
      for (int j = 0; j < 4; ++j) {
        sum[j] += __shfl_xor(sum[j], off, 64);
        sq[j]  += __shfl_xor(sq[j], off, 64);
      }
    }
    if (tr == 0) {
      *(float4*)&psum[(size_t)blockIdx.x * kC3 + cp * 64 + tc * 4] =
          make_float4(sum[0], sum[1], sum[2], sum[3]);
      *(float4*)&psq[(size_t)blockIdx.x * kC3 + cp * 64 + tc * 4] =
          make_float4(sq[0], sq[1], sq[2], sq[3]);
    }
  }
}

// ---------------- Layer 3 pass B: recompute + BN3 + ReLU + max over k -------
__global__ __launch_bounds__(256) void gemm3b_kernel(
    const float* __restrict__ x, const float* __restrict__ W, const float* __restrict__ bias,
    const float* __restrict__ a2, const float* __restrict__ s2,
    const float* __restrict__ a3, const float* __restrict__ s3,
    float* __restrict__ outp) {
  __shared__ float xs[kTileR][kC0P];
  __shared__ float wl[kC1][kC0P];
  const int tid = threadIdx.x;
  const int R0  = blockIdx.x * kTileR;
  const int G0  = R0 >> 5;
  for (int i = tid; i < kTileR * 16; i += 256) {
    const int r = i >> 4, cq = i & 15;
    float4 v = *(const float4*)&x[((size_t)(R0 + r)) * kC1 + cq * 4];
    const float4 av = *(const float4*)&a2[cq * 4];
    const float4 sv = *(const float4*)&s2[cq * 4];
    v.x = fmaxf(fmaf(av.x, v.x, sv.x), 0.0f);
    v.y = fmaxf(fmaf(av.y, v.y, sv.y), 0.0f);
    v.z = fmaxf(fmaf(av.z, v.z, sv.z), 0.0f);
    v.w = fmaxf(fmaf(av.w, v.w, sv.w), 0.0f);
    *(float4*)&xs[r][cq * 4] = v;
  }
  const int tr = tid & 15, tc = tid >> 4;
  for (int cp = 0; cp < 2; ++cp) {
    __syncthreads();
    for (int i = tid; i < kC1 * 16; i += 256) {
      const int o = i >> 4, cq = i & 15;
      *(float4*)&wl[o][cq * 4] = *(const float4*)&W[((size_t)(cp * 64 + o)) * kC1 + cq * 4];
    }
    __syncthreads();
    float acc[8][4];
    gemm_compute<kC1>(xs, wl, tr, tc, acc);
    float bb[4], av3[4], sv3[4];
#pragma unroll
    for (int j = 0; j < 4; ++j) {
      const int col = cp * 64 + tc * 4 + j;
      bb[j]  = bias[col];
      av3[j] = a3[col];
      sv3[j] = s3[col];
    }
    float mm[4][4];
#pragma unroll
    for (int i = 0; i < 8; ++i) {
      const int s4 = i >> 1;
#pragma unroll
      for (int j = 0; j < 4; ++j) {
        const float t = acc[i][j] + bb[j];
        const float v = fmaxf(fmaf(av3[j], t, sv3[j]), 0.0f);
        mm[s4][j] = (i & 1) ? fmaxf(mm[s4][j], v) : v;
      }
    }
#pragma unroll
    for (int off = 1; off < 16; off <<= 1)
#pragma unroll
      for (int s4 = 0; s4 < 4; ++s4)
#pragma unroll
        for (int j = 0; j < 4; ++j)
          mm[s4][j] = fmaxf(mm[s4][j], __shfl_xor(mm[s4][j], off, 64));
    if (tr == 0) {
#pragma unroll
      for (int s4 = 0; s4 < 4; ++s4) {
        *(float4*)&outp[(size_t)(G0 + s4) * kC3 + cp * 64 + tc * 4] =
            make_float4(mm[s4][0], mm[s4][1], mm[s4][2], mm[s4][3]);
      }
    }
  }
}

// ---------------- BN stats finalize (parallel) -------------------------------
// One block per channel; 256 threads reduce the 2048 per-block partials.
__global__ __launch_bounds__(256) void finalize_kernel(
    const float* __restrict__ psum, const float* __restrict__ psq,
    const float* __restrict__ g, const float* __restrict__ be,
    float* __restrict__ a, float* __restrict__ s, int nch) {
  __shared__ float red[2][4];
  const int c   = blockIdx.x;
  const int tid = threadIdx.x;
  const int lane = tid & 63, wid = tid >> 6;
  float sum = 0.f, sq = 0.f;
  for (int i = tid; i < kGemmBlocks; i += 256) {
    sum += psum[(size_t)i * nch + c];
    sq  += psq[(size_t)i * nch + c];
  }
#pragma unroll
  for (int off = 1; off < 64; off <<= 1) {
    sum += __shfl_xor(sum, off, 64);
    sq  += __shfl_xor(sq, off, 64);
  }
  if (lane == 0) { red[0][wid] = sum; red[1][wid] = sq; }
  __syncthreads();
  if (tid == 0) {
    const float tsum = red[0][0] + red[0][1] + red[0][2] + red[0][3];
    const float tsq  = red[1][0] + red[1][1] + red[1][2] + red[1][3];
    const float inv = 1.0f / (float)kRows;
    const float mu  = tsum * inv;
    const float var = tsq * inv - mu * mu;
    const float rs  = 1.0f / sqrtf(var + 1e-5f);
    const float av  = g[c] * rs;
    a[c] = av;
    s[c] = be[c] - av * mu;
  }
}

}  // namespace

extern "C" void kernel_launch(void* const* d_in, const int* in_sizes, int n_in,
                              void* d_out, int out_size, void* d_ws, size_t ws_size,
                              hipStream_t stream) {
  const float* xyz    = (const float*)d_in[0];
  const float* points = (const float*)d_in[1];
  const float* W0  = (const float*)d_in[2];
  const float* b0  = (const float*)d_in[3];
  const float* g0  = (const float*)d_in[4];
  const float* be0 = (const float*)d_in[5];
  const float* W1  = (const float*)d_in[6];
  const float* b1  = (const float*)d_in[7];
  const float* g1  = (const float*)d_in[8];
  const float* be1 = (const float*)d_in[9];
  const float* W2  = (const float*)d_in[10];
  const float* b2  = (const float*)d_in[11];
  const float* g2  = (const float*)d_in[12];
  const float* be2 = (const float*)d_in[13];

  float* out      = (float*)d_out;
  float* newxyz   = out;            // 8*1024*3 = 24576 floats
  float* newpts   = out + 24576;    // 8*1024*128

  char* wsb = (char*)d_ws;
  int*   gidx = (int*)wsb;                              // 1 MiB
  float* a1 = (float*)(wsb + (1u << 20));
  float* s1 = a1 + 128;
  float* a2 = s1 + 128;
  float* s2 = a2 + 128;
  float* a3 = s2 + 128;
  float* s3 = a3 + 128;
  float* psum = (float*)(wsb + 2u * (1u << 20));        // 1 MiB
  float* psq  = (float*)(wsb + 3u * (1u << 20));        // 1 MiB
  float* y1 = (float*)(wsb + 4u * (1u << 20));          // 64 MiB
  float* y2 = (float*)(wsb + 68u * (1u << 20));         // 64 MiB

  fps_kernel<<<kNB, 1024, 0, stream>>>(xyz, newxyz);
  ballq_kernel<<<(kNB * kS) / 4, 256, 0, stream>>>(xyz, newxyz, gidx);
  gemm1_kernel<<<kGemmBlocks, 256, 0, stream>>>(xyz, points, newxyz, gidx, W0, b0, y1, psum, psq);
  finalize_kernel<<<64, 256, 0, stream>>>(psum, psq, g0, be0, a1, s1, 64);
  gemm2_kernel<<<kGemmBlocks, 256, 0, stream>>>(y1, W1, b1, a1, s1, y2, psum, psq);
  finalize_kernel<<<64, 256, 0, stream>>>(psum, psq, g1, be1, a2, s2, 64);
  gemm3a_kernel<<<kGemmBlocks, 256, 0, stream>>>(y2, W2, b2, a2, s2, psum, psq);
  finalize_kernel<<<128, 256, 0, stream>>>(psum, psq, g2, be2, a3, s3, 128);
  gemm3b_kernel<<<kGemmBlocks, 256, 0, stream>>>(y2, W2, b2, a2, s2, a3, s3, newpts);
}